// Round 8
// baseline (411.250 us; speedup 1.0000x reference)
//
#include <hip/hip_runtime.h>
#include <hip/hip_bf16.h>
#include <math.h>

#define NT   65536      // total nodes (32 graphs * 2048)
#define NPGC 2048       // nodes per graph
#define NG   32         // graphs
#define NE   524288     // edges
#define EPG  16384      // edges per graph (col2 arena stride)
#define HID  128
#define K1   1024       // pool-1 keep per graph
#define K2   512        // pool-2 keep per graph

typedef short short8 __attribute__((ext_vector_type(8)));
typedef float f32x4  __attribute__((ext_vector_type(4)));

__device__ __forceinline__ float bf2f(unsigned short u) {
    union { unsigned int i; float f; } v; v.i = ((unsigned int)u) << 16; return v.f;
}
__device__ __forceinline__ unsigned short f2bf(float f) {   // round-to-nearest (packW only)
    union { float f; unsigned int i; } v; v.f = f;
    unsigned int x = v.i;
    return (unsigned short)((x + 0x7fffu + ((x >> 16) & 1u)) >> 16);
}
// fast truncation split: v ~ hi + lo, |err| <= 2^-16 |v| (4 ops)
__device__ __forceinline__ void split2(float v, unsigned short& hi, unsigned short& lo) {
    unsigned int b = __float_as_uint(v);
    hi = (unsigned short)(b >> 16);
    float rem = v - __uint_as_float(b & 0xFFFF0000u);
    lo = (unsigned short)(__float_as_uint(rem) >> 16);
}

// ---------- dtype detection: bf16 vs fp32 ----------
__global__ void k_detect(const unsigned short* __restrict__ x, int* __restrict__ flag) {
    __shared__ int cnt;
    if (threadIdx.x == 0) cnt = 0;
    __syncthreads();
    int sane = 0;
#pragma unroll
    for (int j = 0; j < 16; ++j) {
        unsigned short u = x[threadIdx.x * 16 + j];
        int e = (u >> 7) & 0xFF;
        if (e > 0x60 && e < 0xA0) sane++;
    }
    atomicAdd(&cnt, sane);
    __syncthreads();
    if (threadIdx.x == 0) *flag = (cnt > 3686) ? 1 : 0;
}

// ---------- weight conversion: (bf16|f32) -> f32 scratch ----------
struct CvtDesc { const void* src[22]; int n[22]; int off[22]; };

__global__ void k_cvt(CvtDesc d, float* __restrict__ wts, const int* __restrict__ flag) {
    int t = blockIdx.y;
    int n = d.n[t];
    bool isbf = (*flag != 0);
    const unsigned short* sb = (const unsigned short*)d.src[t];
    const float* sf = (const float*)d.src[t];
    float* o = wts + d.off[t];
    for (int i = blockIdx.x * blockDim.x + threadIdx.x; i < n; i += gridDim.x * blockDim.x)
        o[i] = isbf ? bf2f(sb[i]) : sf[i];
}

// ---------- pack SAGE weights (+ zero rowc/fill for the CSR build) ----------
__global__ void k_packW(const float* __restrict__ wts, int4 oWl, int4 oWr,
                        unsigned short* __restrict__ Wpack,
                        int* __restrict__ rowc, int* __restrict__ fill) {
    int idx = blockIdx.x * 256 + threadIdx.x;
    if (idx < NT) { rowc[idx] = 0; fill[idx] = 0; }
    if (idx >= 4 * 8 * 8 * 64 * 8) return;
    int L    = idx >> 15;
    int rem  = idx & 32767;
    int ct   = rem >> 12;
    int rem2 = rem & 4095;
    int ks   = rem2 >> 9;
    int rem3 = rem2 & 511;
    int lane = rem3 >> 3;
    int j    = rem3 & 7;
    int k   = ks * 32 + (lane >> 4) * 8 + j;
    int col = ct * 16 + (lane & 15);
    int ol = (L == 0) ? oWl.x : (L == 1) ? oWl.y : (L == 2) ? oWl.z : oWl.w;
    int orr = (L == 0) ? oWr.x : (L == 1) ? oWr.y : (L == 2) ? oWr.z : oWr.w;
    float w = (k < 128) ? wts[ol + k * 128 + col] : wts[orr + (k - 128) * 128 + col];
    unsigned short hi = f2bf(w);
    unsigned short lo = f2bf(w - bf2f(hi));
    int base = L * 65536 + (ct * 8 + ks) * 512 + lane * 8 + j;
    Wpack[base]         = hi;
    Wpack[base + 32768] = lo;
}

// ---------- edge histogram only (x is consumed in-place by layer 1) ----------
__global__ void k_hist(const int* __restrict__ dstE, int* __restrict__ rowc) {
    int e = blockIdx.x * 256 + threadIdx.x;
    if (e < NE) atomicAdd(&rowc[dstE[e]], 1);
}

// scan1 also emits initial invc (pre-pool: invc = 1/max(deg,1))
__global__ void k_scan1(const int* __restrict__ cnt, int* __restrict__ rp, int* __restrict__ bsum,
                        float* __restrict__ invc) {
    __shared__ int s[256];
    int t = threadIdx.x;
    int i = blockIdx.x * 256 + t;
    int v = cnt[i];
    invc[i] = 1.0f / fmaxf((float)v, 1.0f);
    s[t] = v;
    __syncthreads();
    for (int off = 1; off < 256; off <<= 1) {
        int a = (t >= off) ? s[t - off] : 0;
        __syncthreads();
        s[t] += a;
        __syncthreads();
    }
    rp[i] = s[t] - v;
    if (t == 255) bsum[blockIdx.x] = s[255];
}

// merged scan2+scan3
__global__ void k_scan23(int* __restrict__ rp, const int* __restrict__ bsum) {
    __shared__ int s[256];
    int t = threadIdx.x;
    s[t] = bsum[t];
    __syncthreads();
    for (int off = 1; off < 256; off <<= 1) {
        int a = (t >= off) ? s[t - off] : 0;
        __syncthreads();
        s[t] += a;
        __syncthreads();
    }
    int boffv = s[blockIdx.x] - bsum[blockIdx.x];
    int i = blockIdx.x * 256 + t;
    rp[i] += boffv;
    if (i == 0) rp[NT] = NE;
}

__global__ void k_scatter(const int* __restrict__ src, const int* __restrict__ dst,
                          const int* __restrict__ rp, int* __restrict__ fill, int* __restrict__ col) {
    int e = blockIdx.x * blockDim.x + threadIdx.x;
    if (e < NE) {
        int d = dst[e];
        int p = rp[d] + atomicAdd(&fill[d], 1);
        col[p] = src[e];
    }
}

// ---------- filtered CSR build: 1 thread/active node, block scan, ONE atomic per block ----------
__global__ void __launch_bounds__(256) k_fbuild(const int* __restrict__ act,
                                                const float* __restrict__ nm,
                                                const int* __restrict__ rp,
                                                const int* __restrict__ col,
                                                int2* __restrict__ rp2,
                                                int* __restrict__ col2,
                                                float* __restrict__ invc,
                                                int* __restrict__ ghead) {
    __shared__ int wtot[4];
    __shared__ int s_base;
    int tid = threadIdx.x;
    int lane = tid & 63, wv = tid >> 6;
    int i = blockIdx.x * 256 + tid;           // 0..NG*K1-1
    int g = i >> 10;                          // constant within block
    int n = act[i];
    int bg = rp[n], en = rp[n + 1];
    int cc = 0;
    for (int e = bg; e < en; ++e) cc += (nm[col[e]] > 0.f) ? 1 : 0;
    invc[n] = 1.0f / fmaxf((float)cc, 1.0f);

    // block-wide exclusive scan of cc
    int pre = cc;
#pragma unroll
    for (int off = 1; off < 64; off <<= 1) {
        int v = __shfl_up(pre, off, 64);
        pre += (lane >= off) ? v : 0;
    }
    if (lane == 63) wtot[wv] = pre;
    __syncthreads();
    int woff = 0;
#pragma unroll
    for (int w2 = 0; w2 < 4; ++w2) woff += (w2 < wv) ? wtot[w2] : 0;
    int ex = pre - cc + woff;
    if (tid == 0) s_base = atomicAdd(&ghead[g], wtot[0] + wtot[1] + wtot[2] + wtot[3]);
    __syncthreads();

    int p = g * EPG + s_base + ex;
    rp2[i] = make_int2(p, p + cc);
    for (int e = bg; e < en; ++e) {
        int s = col[e];
        if (nm[s] > 0.f) col2[p++] = s;
    }
}

// ---------- LDS swizzle ----------
__device__ __forceinline__ int lds_sw(int node, int k) {
    int g = k >> 3;
    int go = g ^ (node & 7);
    return node * 128 + go * 8 + (k & 7);
}

// ---------- dtype-generic row chunk load (4 feats) ----------
template<int MODE>
__device__ __forceinline__ float4 ldrow4(const void* __restrict__ h, int node, int f) {
    if constexpr (MODE == 1) {
        ushort4 v = *((const ushort4*)h + (size_t)node * 32 + (f >> 2));
        float4 o; o.x = bf2f(v.x); o.y = bf2f(v.y); o.z = bf2f(v.z); o.w = bf2f(v.w);
        return o;
    } else {
        return *((const float4*)h + (size_t)node * 32 + (f >> 2));
    }
}

// ---------- shared body: two-phase (16 KB LDS), 8-wide gather, roots issue-early/write-late ----------
template<bool HAS_TS, bool COMPACT, int MODE>
__device__ __forceinline__ void sage_body(
    const void* __restrict__ h, const float* __restrict__ ts,
    const float* __restrict__ invc,
    const int* __restrict__ rp, const int2* __restrict__ rp2,
    const int* __restrict__ col,
    const unsigned short* __restrict__ Wp,
    unsigned short* Ahi, unsigned short* Alo,
    int n0, int cb, const int* __restrict__ actb, int tid, f32x4 acc[2][2])
{
    int lane = tid & 63, w = tid >> 6;
    int lrow = lane & 15, quad = lane >> 4;
    int gnode = tid >> 5;          // 0..7 (32 threads per node)
    int f = (tid & 31) * 4;

    // ---- CSR prefetch for this thread's 4 gather nodes ----
    int gns[4], begs[4], ends[4]; float invs[4];
#pragma unroll
    for (int p = 0; p < 4; ++p) gns[p] = COMPACT ? actb[p * 8 + gnode] : n0 + p * 8 + gnode;
#pragma unroll
    for (int p = 0; p < 4; ++p) {
        if (COMPACT) { int2 be = rp2[cb + p * 8 + gnode]; begs[p] = be.x; ends[p] = be.y; }
        else         { begs[p] = rp[gns[p]]; ends[p] = rp[gns[p] + 1]; }
    }
#pragma unroll
    for (int p = 0; p < 4; ++p) invs[p] = invc[gns[p]];

    // ---- issue root-row loads NOW; values consumed only in phase B (T14 split) ----
    float4 rootv[4]; float roots[4];
#pragma unroll
    for (int i = 0; i < 4; ++i) {
        int idx = i * 256 + tid;
        int node = idx >> 5;
        int f2 = (idx & 31) * 4;
        int gn = COMPACT ? actb[node] : n0 + node;
        rootv[i] = ldrow4<MODE>(h, gn, f2);
        roots[i] = HAS_TS ? ts[gn] : 1.0f;
    }

    // ---- phase A: gather mean rows, 8 edges in flight ----
#pragma unroll
    for (int pass = 0; pass < 4; ++pass) {
        int node = pass * 8 + gnode;
        float ax = 0.f, ay = 0.f, az = 0.f, aw = 0.f;
        int beg = begs[pass], end = ends[pass];
        int ecl = end - 1;
        for (int e0 = beg; e0 < end; e0 += 8) {
            int sj[8];
#pragma unroll
            for (int j = 0; j < 8; ++j) {
                int e = (e0 + j < end) ? e0 + j : ecl;
                sj[j] = col[e];
            }
            float4 vj[8];
#pragma unroll
            for (int j = 0; j < 8; ++j)
                vj[j] = ldrow4<MODE>(h, sj[j], f);
#pragma unroll
            for (int j = 0; j < 8; ++j) {
                float cj = (e0 + j < end) ? (HAS_TS ? ts[sj[j]] : 1.0f) : 0.0f;
                ax += vj[j].x * cj;
                ay += vj[j].y * cj;
                az += vj[j].z * cj;
                aw += vj[j].w * cj;
            }
        }
        float inv = invs[pass];
        ushort4 hi4, lo4;
        split2(ax * inv, hi4.x, lo4.x);
        split2(ay * inv, hi4.y, lo4.y);
        split2(az * inv, hi4.z, lo4.z);
        split2(aw * inv, hi4.w, lo4.w);
        int a = lds_sw(node, f);
        *(ushort4*)&Ahi[a] = hi4;
        *(ushort4*)&Alo[a] = lo4;
    }
    __syncthreads();

    // ---- MFMA over Wl half (ks 0..3, from A) ----
#pragma unroll
    for (int ks = 0; ks < 4; ++ks) {
        short8 bh[2], blo[2];
#pragma unroll
        for (int c = 0; c < 2; ++c) {
            int ct = 2 * w + c;
            bh[c]  = *(const short8*)&Wp[(ct * 8 + ks) * 512 + lane * 8];
            blo[c] = *(const short8*)&Wp[32768 + (ct * 8 + ks) * 512 + lane * 8];
        }
        int kb = ks * 32 + quad * 8;
#pragma unroll
        for (int st = 0; st < 2; ++st) {
            int a = lds_sw(st * 16 + lrow, kb);
            short8 ah = *(const short8*)&Ahi[a];
            short8 al = *(const short8*)&Alo[a];
#pragma unroll
            for (int c = 0; c < 2; ++c) {
                acc[st][c] = __builtin_amdgcn_mfma_f32_16x16x32_bf16(ah, bh[c],  acc[st][c], 0, 0, 0);
                acc[st][c] = __builtin_amdgcn_mfma_f32_16x16x32_bf16(al, bh[c],  acc[st][c], 0, 0, 0);
                acc[st][c] = __builtin_amdgcn_mfma_f32_16x16x32_bf16(ah, blo[c], acc[st][c], 0, 0, 0);
            }
        }
    }
    __syncthreads();

    // ---- phase B: stage root rows from registers (loads landed long ago) ----
#pragma unroll
    for (int i = 0; i < 4; ++i) {
        int idx = i * 256 + tid;
        int node = idx >> 5;
        int f2 = (idx & 31) * 4;
        float sc = roots[i];
        ushort4 hi4, lo4;
        split2(rootv[i].x * sc, hi4.x, lo4.x);
        split2(rootv[i].y * sc, hi4.y, lo4.y);
        split2(rootv[i].z * sc, hi4.z, lo4.z);
        split2(rootv[i].w * sc, hi4.w, lo4.w);
        int a = lds_sw(node, f2);
        *(ushort4*)&Ahi[a] = hi4;
        *(ushort4*)&Alo[a] = lo4;
    }
    __syncthreads();

    // ---- MFMA over Wr half (ks 4..7, from A again) ----
#pragma unroll
    for (int ks = 4; ks < 8; ++ks) {
        short8 bh[2], blo[2];
#pragma unroll
        for (int c = 0; c < 2; ++c) {
            int ct = 2 * w + c;
            bh[c]  = *(const short8*)&Wp[(ct * 8 + ks) * 512 + lane * 8];
            blo[c] = *(const short8*)&Wp[32768 + (ct * 8 + ks) * 512 + lane * 8];
        }
        int kb = (ks - 4) * 32 + quad * 8;
#pragma unroll
        for (int st = 0; st < 2; ++st) {
            int a = lds_sw(st * 16 + lrow, kb);
            short8 ah = *(const short8*)&Ahi[a];
            short8 al = *(const short8*)&Alo[a];
#pragma unroll
            for (int c = 0; c < 2; ++c) {
                acc[st][c] = __builtin_amdgcn_mfma_f32_16x16x32_bf16(ah, bh[c],  acc[st][c], 0, 0, 0);
                acc[st][c] = __builtin_amdgcn_mfma_f32_16x16x32_bf16(al, bh[c],  acc[st][c], 0, 0, 0);
                acc[st][c] = __builtin_amdgcn_mfma_f32_16x16x32_bf16(ah, blo[c], acc[st][c], 0, 0, 0);
            }
        }
    }
}

// ---------- block -> (graph, tile) with XCD-affinity swizzle ----------
template<bool COMPACT>
__device__ __forceinline__ void map_block(int b, int& graph, int& tile) {
    if (COMPACT) { graph = (b & 7) * 4 + (b >> 8); tile = (b >> 3) & 31; }   // 1024 blocks
    else         { graph = (b & 7) * 4 + (b >> 9); tile = (b >> 3) & 63; }   // 2048 blocks
}

// ---------- layer 1: reads x directly (bf16 or f32) ----------
__global__ void __launch_bounds__(256, 8) k_sage_l1(
    const void* __restrict__ x, const int* __restrict__ flag,
    const float* __restrict__ invc,
    const int* __restrict__ rp, const int* __restrict__ col,
    const unsigned short* __restrict__ Wp, const float* __restrict__ bl,
    float* __restrict__ out)
{
    __shared__ unsigned short Ahi[32 * 128];
    __shared__ unsigned short Alo[32 * 128];
    int tid = threadIdx.x;
    int graph, tile;
    map_block<false>(blockIdx.x, graph, tile);
    int n0 = graph * NPGC + tile * 32;
    int lane = tid & 63, w = tid >> 6;
    int lrow = lane & 15, quad = lane >> 4;
    f32x4 acc[2][2] = {};

    if (*flag)
        sage_body<false, false, 1>(x, nullptr, invc, rp, nullptr, col, Wp, Ahi, Alo, n0, 0, nullptr, tid, acc);
    else
        sage_body<false, false, 0>(x, nullptr, invc, rp, nullptr, col, Wp, Ahi, Alo, n0, 0, nullptr, tid, acc);

#pragma unroll
    for (int c = 0; c < 2; ++c) {
        int colg = (2 * w + c) * 16 + lrow;
        float bias = bl[colg];
#pragma unroll
        for (int st = 0; st < 2; ++st) {
#pragma unroll
            for (int rr = 0; rr < 4; ++rr) {
                int node = n0 + st * 16 + quad * 4 + rr;
                out[(size_t)node * HID + colg] = fmaxf(acc[st][c][rr] + bias, 0.f);
            }
        }
    }
}

// ---------- layer 3: compact plain (filtered CSR) ----------
__global__ void __launch_bounds__(256, 8) k_sage_plain(
    const float* __restrict__ h, const float* __restrict__ ts,
    const float* __restrict__ invc,
    const int2* __restrict__ rp2, const int* __restrict__ col2,
    const unsigned short* __restrict__ Wp, const float* __restrict__ bl,
    float* __restrict__ out, const int* __restrict__ act)
{
    __shared__ unsigned short Ahi[32 * 128];
    __shared__ unsigned short Alo[32 * 128];
    int tid = threadIdx.x;
    int graph, tile;
    map_block<true>(blockIdx.x, graph, tile);
    int n0 = graph * NPGC + tile * 32;
    int cb = graph * K1 + tile * 32;
    const int* actb = act + cb;
    int lane = tid & 63, w = tid >> 6;
    int lrow = lane & 15, quad = lane >> 4;
    f32x4 acc[2][2] = {};

    sage_body<true, true, 0>(h, ts, invc, nullptr, rp2, col2, Wp, Ahi, Alo, n0, cb, actb, tid, acc);

#pragma unroll
    for (int c = 0; c < 2; ++c) {
        int colg = (2 * w + c) * 16 + lrow;
        float bias = bl[colg];
#pragma unroll
        for (int st = 0; st < 2; ++st) {
#pragma unroll
            for (int rr = 0; rr < 4; ++rr) {
                int node = actb[st * 16 + quad * 4 + rr];
                out[(size_t)node * HID + colg] = fmaxf(acc[st][c][rr] + bias, 0.f);
            }
        }
    }
}

// ---------- layers 2 & 4: SAGE + pool dots ----------
template<bool COMPACT>
__global__ void __launch_bounds__(256, 8) k_sage_dots(
    const float* __restrict__ h,
    const float* __restrict__ invc,
    const int* __restrict__ rp, const int2* __restrict__ rp2,
    const int* __restrict__ col,
    const unsigned short* __restrict__ Wp, const float* __restrict__ bl,
    float* __restrict__ out,
    const float* __restrict__ Prel, const float* __restrict__ Proot,
    float* __restrict__ q, float* __restrict__ r, const int* __restrict__ act)
{
    __shared__ unsigned short Ahi[32 * 128];
    __shared__ unsigned short Alo[32 * 128];
    int tid = threadIdx.x;
    int graph, tile;
    map_block<COMPACT>(blockIdx.x, graph, tile);
    int n0 = graph * NPGC + tile * 32;
    int cb = COMPACT ? (graph * K1 + tile * 32) : 0;
    const int* actb = COMPACT ? (act + cb) : nullptr;
    int lane = tid & 63, w = tid >> 6;
    int lrow = lane & 15, quad = lane >> 4;
    f32x4 acc[2][2] = {};

    // layer 4 (COMPACT): filtered CSR => all sources active => no ts needed
    sage_body<false, COMPACT, 0>(h, nullptr, invc, rp, rp2, col, Wp, Ahi, Alo, n0, cb, actb, tid, acc);

    float qp[2][4] = {}, rp_[2][4] = {};
#pragma unroll
    for (int c = 0; c < 2; ++c) {
        int colg = (2 * w + c) * 16 + lrow;
        float bias = bl[colg];
        float pq = Prel[colg], pr = Proot[colg];
#pragma unroll
        for (int st = 0; st < 2; ++st) {
#pragma unroll
            for (int rr = 0; rr < 4; ++rr) {
                int nl = st * 16 + quad * 4 + rr;
                int node = COMPACT ? actb[nl] : n0 + nl;
                float val = fmaxf(acc[st][c][rr] + bias, 0.f);
                out[(size_t)node * HID + colg] = val;
                qp[st][rr] += val * pq;
                rp_[st][rr] += val * pr;
            }
        }
    }
#pragma unroll
    for (int st = 0; st < 2; ++st)
#pragma unroll
        for (int rr = 0; rr < 4; ++rr) {
#pragma unroll
            for (int m = 1; m < 16; m <<= 1) {
                qp[st][rr]  += __shfl_xor(qp[st][rr],  m, 64);
                rp_[st][rr] += __shfl_xor(rp_[st][rr], m, 64);
            }
        }
    __syncthreads();
    float* qa = (float*)Ahi;
    if (tid < 64) qa[tid] = 0.f;
    __syncthreads();
    if (lrow == 0) {
#pragma unroll
        for (int st = 0; st < 2; ++st)
#pragma unroll
            for (int rr = 0; rr < 4; ++rr) {
                int nl = st * 16 + quad * 4 + rr;
                atomicAdd(&qa[nl], qp[st][rr]);
                atomicAdd(&qa[32 + nl], rp_[st][rr]);
            }
    }
    __syncthreads();
    if (tid < 32) {
        int node = COMPACT ? actb[tid] : n0 + tid;
        q[node] = qa[tid];
        r[node] = qa[32 + tid];
    }
}

// ---------- score = segsum(q[src]) + r + prb (full, pool 1) ----------
__global__ void k_score(const float* __restrict__ q, const float* __restrict__ r,
                        const float* __restrict__ prb,
                        const int* __restrict__ rp, const int* __restrict__ col,
                        float* __restrict__ score) {
    int n = blockIdx.x * 256 + threadIdx.x;
    int beg = rp[n], end = rp[n + 1];
    float s = 0.f;
    for (int e = beg; e < end; ++e) s += q[col[e]];
    score[n] = s + r[n] + prb[0];
}

// ---------- score over active nodes via filtered CSR (pool 2) ----------
__global__ void k_score2(const float* __restrict__ q, const float* __restrict__ r,
                         const float* __restrict__ prb,
                         const int2* __restrict__ rp2, const int* __restrict__ col2,
                         float* __restrict__ score, const int* __restrict__ act) {
    int i = blockIdx.x * 256 + threadIdx.x;
    int n = act[i];
    int2 be = rp2[i];
    float s = 0.f;
    for (int e = be.x; e < be.y; ++e) s += q[col2[e]];
    score[n] = s + r[n] + prb[0];
}

// ---------- per-graph top-k via radix select; emits compact active list ----------
template<bool NMIN>
__global__ void __launch_bounds__(256) k_topk(const float* __restrict__ score,
                                              float* __restrict__ nm,
                                              float* __restrict__ tval, int k,
                                              int* __restrict__ act) {
    __shared__ unsigned int u[NPGC];
    __shared__ int hist[256];
    __shared__ int scanb[257];
    __shared__ int wtot[4];
    __shared__ int wtot2[4];
    __shared__ unsigned int s_byte;
    __shared__ int s_kk;
    int tid = threadIdx.x;
    int lane = tid & 63, wv = tid >> 6;
    int base = blockIdx.x * NPGC;

    for (int j = tid; j < NPGC; j += 256) {
        float sc = NMIN ? ((nm[base + j] > 0.f) ? score[base + j] : -1e30f) : score[base + j];
        unsigned int v = __float_as_uint(sc);
        v = (v & 0x80000000u) ? ~v : (v | 0x80000000u);
        u[j] = v;
    }
    hist[tid] = 0;
    if (tid == 0) scanb[256] = 0;
    __syncthreads();

    unsigned int prefix = 0;
    int kk = k;
#pragma unroll
    for (int round = 0; round < 4; ++round) {
        int shift = 24 - 8 * round;
        unsigned int pmask = (round == 0) ? 0u : (0xFFFFFFFFu << (32 - 8 * round));
        for (int j = tid; j < NPGC; j += 256) {
            unsigned int v = u[j];
            if ((v & pmask) == prefix) atomicAdd(&hist[(v >> shift) & 0xFF], 1);
        }
        __syncthreads();
        int s = hist[tid];
#pragma unroll
        for (int off = 1; off < 64; off <<= 1) {
            int t = __shfl_down(s, off, 64);
            s += (lane + off < 64) ? t : 0;
        }
        if (lane == 0) wtot[wv] = s;
        __syncthreads();
        int add = 0;
#pragma unroll
        for (int w2 = 1; w2 < 4; ++w2) add += (wv + w2 < 4) ? wtot[wv + w2] : 0;
        s += add;
        scanb[tid] = s;
        __syncthreads();
        int above = scanb[tid + 1];
        if (s >= kk && above < kk) { s_byte = (unsigned int)tid; s_kk = kk - above; }
        hist[tid] = 0;
        __syncthreads();
        prefix |= (s_byte << shift);
        kk = s_kk;
    }
    unsigned int thr = prefix;

    int j0 = tid * 8;
    int cnt = 0;
#pragma unroll
    for (int j = 0; j < 8; ++j) cnt += (u[j0 + j] == thr);
    int s = cnt;
#pragma unroll
    for (int off = 1; off < 64; off <<= 1) {
        int t = __shfl_up(s, off, 64);
        s += (lane >= off) ? t : 0;
    }
    if (lane == 63) wtot[wv] = s;
    __syncthreads();
    int add = 0;
#pragma unroll
    for (int w2 = 0; w2 < 4; ++w2) add += (w2 < wv) ? wtot[w2] : 0;
    int rank = s - cnt + add;

    // keep flags (exact k kept per graph by construction of the select)
    unsigned int keepmask = 0u;
    int myrank = rank;
    int kcnt = 0;
#pragma unroll
    for (int j = 0; j < 8; ++j) {
        unsigned int v = u[j0 + j];
        bool kp;
        if (v > thr) kp = true;
        else if (v == thr) { kp = (myrank < kk); myrank++; }
        else kp = false;
        keepmask |= (kp ? 1u : 0u) << j;
        kcnt += kp ? 1 : 0;
    }
    // block-wide exclusive scan of keep counts -> compact write position
    int s2 = kcnt;
#pragma unroll
    for (int off = 1; off < 64; off <<= 1) {
        int t2 = __shfl_up(s2, off, 64);
        s2 += (lane >= off) ? t2 : 0;
    }
    if (lane == 63) wtot2[wv] = s2;
    __syncthreads();
    int pos = s2 - kcnt;
#pragma unroll
    for (int w2 = 0; w2 < 4; ++w2) pos += (w2 < wv) ? wtot2[w2] : 0;
    int* actg = act + blockIdx.x * k;
#pragma unroll
    for (int j = 0; j < 8; ++j) {
        bool kp = (keepmask >> j) & 1u;
        int n = base + j0 + j;
        nm[n]   = kp ? 1.0f : 0.0f;
        tval[n] = kp ? tanhf(score[n]) : 0.0f;
        if (kp) actg[pos++] = n;
    }
}

// ---------- readout + MLP head + log_softmax, one block per graph ----------
__global__ void k_tail(const float* __restrict__ h, const float* __restrict__ t,
                       const int* __restrict__ act,
                       const float* __restrict__ W5, const float* __restrict__ b5,
                       const float* __restrict__ W6, const float* __restrict__ b6,
                       void* __restrict__ out, const int* __restrict__ flag) {
    __shared__ float gsh[2][HID];
    __shared__ float g5[64];
    __shared__ float ls[2];
    int graph = blockIdx.x, tid = threadIdx.x;
    int f = tid & 127, sub = tid >> 7;
    const int* actg = act + graph * K2;
    float acc = 0.f;
#pragma unroll 8
    for (int i = 0; i < 256; ++i) {
        int gn = actg[sub * 256 + i];
        acc += h[(size_t)gn * HID + f] * t[gn];
    }
    gsh[sub][f] = acc;
    __syncthreads();
    if (tid < 64) {
        const float ic = 1.0f / (float)K2;
        float a5 = b5[tid];
        for (int ff = 0; ff < HID; ++ff)
            a5 += (gsh[0][ff] + gsh[1][ff]) * ic * W5[ff * 64 + tid];
        g5[tid] = fmaxf(a5, 0.f);
    }
    __syncthreads();
    if (tid < 2) {
        float l = b6[tid];
        for (int tt = 0; tt < 64; ++tt) l += g5[tt] * W6[tt * 2 + tid];
        ls[tid] = l;
    }
    __syncthreads();
    if (tid == 0) {
        float a = ls[0], b = ls[1];
        float mx = fmaxf(a, b);
        float lse = mx + logf(expf(a - mx) + expf(b - mx));
        if (*flag) {
            ((unsigned short*)out)[graph * 2 + 0] = f2bf(a - lse);
            ((unsigned short*)out)[graph * 2 + 1] = f2bf(b - lse);
        } else {
            ((float*)out)[graph * 2 + 0] = a - lse;
            ((float*)out)[graph * 2 + 1] = b - lse;
        }
    }
}

extern "C" void kernel_launch(void* const* d_in, const int* in_sizes, int n_in,
                              void* d_out, int out_size, void* d_ws, size_t ws_size,
                              hipStream_t stream) {
    const void* x    = d_in[0];
    const int*  ei   = (const int*)d_in[1];
    const int*  srcE = ei;
    const int*  dstE = ei + NE;

    char* ws = (char*)d_ws;
    float* hA    = (float*)(ws + 0);
    float* hB    = (float*)(ws + 33554432);
    float* tvec  = (float*)(ws + 67108864);
    float* invc  = (float*)(ws + 67371008);
    int*   col2  = (int*)  (ws + 67633152);   // 2 MB (per-graph arenas of EPG)
    int2*  rp2   = (int2*) (ws + 69730304);   // 256 KB
    int*   ghead = (int*)  (ws + 69992448);   // 128 B
    float* q     = (float*)(ws + 100663296);
    float* r     = (float*)(ws + 100925440);
    float* score = (float*)(ws + 101187584);
    float* nm    = (float*)(ws + 101449728);
    int*   rowc  = (int*)  (ws + 101711872);  // reused as act1 (32768 ints) after scan1
    int*   rp    = (int*)  (ws + 101974016);
    int*   bsum  = (int*)  (ws + 102236416);
    int*   fill  = (int*)  (ws + 102238464);  // reused as act2 (16384 ints) after scatter
    int*   col   = (int*)  (ws + 102500608);
    int*   flag  = (int*)  (ws + 104615936);
    float* wts   = (float*)(ws + 104616960);
    unsigned short* Wpack = (unsigned short*)(ws + 105179136);
    int*   act1  = rowc;
    int*   act2  = fill;
    (void)in_sizes; (void)n_in; (void)out_size; (void)ws_size;

    const int O_Wl1 = 0,      O_bl1 = 16384,  O_Wr1 = 16512;
    const int O_Wl2 = 32896,  O_bl2 = 49280,  O_Wr2 = 49408;
    const int O_Wl3 = 65792,  O_bl3 = 82176,  O_Wr3 = 82304;
    const int O_Wl4 = 98688,  O_bl4 = 115072, O_Wr4 = 115200;
    const int O_Pr1 = 131584, O_pb1 = 131712, O_Po1 = 131713;
    const int O_Pr2 = 131841, O_pb2 = 131969, O_Po2 = 131970;
    const int O_W5  = 132098, O_b5  = 140290, O_W6 = 140354, O_b6 = 140482;

    CvtDesc d;
    const int srcIdx[22] = {4,5,6,7,8,9,10,11,12,13,14,15,16,17,18,19,20,21,22,23,24,25};
    const int nelems[22] = {16384,128,16384, 16384,128,16384, 16384,128,16384, 16384,128,16384,
                            128,1,128, 128,1,128, 8192,64,128,2};
    const int offs[22]   = {O_Wl1,O_bl1,O_Wr1, O_Wl2,O_bl2,O_Wr2, O_Wl3,O_bl3,O_Wr3, O_Wl4,O_bl4,O_Wr4,
                            O_Pr1,O_pb1,O_Po1, O_Pr2,O_pb2,O_Po2, O_W5,O_b5,O_W6,O_b6};
    for (int i = 0; i < 22; ++i) { d.src[i] = d_in[srcIdx[i]]; d.n[i] = nelems[i]; d.off[i] = offs[i]; }

    hipMemsetAsync(ghead, 0, NG * 4, stream);

    k_detect <<<1, 256, 0, stream>>>((const unsigned short*)x, flag);
    k_cvt    <<<dim3(64, 22), 256, 0, stream>>>(d, wts, flag);
    k_packW  <<<512, 256, 0, stream>>>(wts, make_int4(O_Wl1, O_Wl2, O_Wl3, O_Wl4),
                                       make_int4(O_Wr1, O_Wr2, O_Wr3, O_Wr4), Wpack, rowc, fill);
    k_hist   <<<2048, 256, 0, stream>>>(dstE, rowc);

    k_scan1  <<<256, 256, 0, stream>>>(rowc, rp, bsum, invc);
    k_scan23 <<<256, 256, 0, stream>>>(rp, bsum);
    k_scatter<<<2048, 256, 0, stream>>>(srcE, dstE, rp, fill, col);

    // layer 1: x -> hB (reads x directly, bf16 or f32)
    k_sage_l1<<<2048, 256, 0, stream>>>(x, flag, invc, rp, col,
                                        Wpack + 0 * 65536, wts + O_bl1, hB);
    // layer 2: hB -> hA  (+ fused pool-1 dots)
    k_sage_dots<false><<<2048, 256, 0, stream>>>(hB, invc, rp, nullptr, col,
                                                 Wpack + 1 * 65536, wts + O_bl2, hA,
                                                 wts + O_Pr1, wts + O_Po1, q, r, nullptr);

    // pool 1 (k = 1024): topk emits act1; parallel filtered-CSR build + invc
    k_score<<<256, 256, 0, stream>>>(q, r, wts + O_pb1, rp, col, score);
    k_topk<false><<<32, 256, 0, stream>>>(score, nm, tvec, K1, act1);
    k_fbuild<<<NG * K1 / 256, 256, 0, stream>>>(act1, nm, rp, col, rp2, col2, invc, ghead);

    // layer 3 (compact, filtered CSR): hA (scaled by tvec) -> hB
    k_sage_plain<<<1024, 256, 0, stream>>>(hA, tvec, invc, rp2, col2,
                                           Wpack + 2 * 65536, wts + O_bl3, hB, act1);
    // layer 4 (compact, filtered CSR => no ts needed): hB -> hA (+ pool-2 dots)
    k_sage_dots<true><<<1024, 256, 0, stream>>>(hB, invc, nullptr, rp2, col2,
                                                Wpack + 3 * 65536, wts + O_bl4, hA,
                                                wts + O_Pr2, wts + O_Po2, q, r, act1);

    // pool 2 (k = 512): score over filtered CSR; emits act2
    k_score2<<<NG * K1 / 256, 256, 0, stream>>>(q, r, wts + O_pb2, rp2, col2, score, act1);
    k_topk<true><<<32, 256, 0, stream>>>(score, nm, tvec, K2, act2);

    // readout + MLP head (one block per graph; count == K2 folded in)
    k_tail<<<32, 256, 0, stream>>>(hA, tvec, act2, wts + O_W5, wts + O_b5,
                                   wts + O_W6, wts + O_b6, d_out, flag);
}

// Round 9
// 377.729 us; speedup vs baseline: 1.0887x; 1.0887x over previous
//
#include <hip/hip_runtime.h>
#include <hip/hip_bf16.h>
#include <math.h>

#define NT   65536      // total nodes (32 graphs * 2048)
#define NPGC 2048       // nodes per graph
#define NG   32         // graphs
#define NE   524288     // edges
#define EPG  16384      // edges per graph (col2 arena stride)
#define HID  128
#define K1   1024       // pool-1 keep per graph
#define K2   512        // pool-2 keep per graph

typedef short short8 __attribute__((ext_vector_type(8)));
typedef float f32x4  __attribute__((ext_vector_type(4)));

__device__ __forceinline__ float bf2f(unsigned short u) {
    union { unsigned int i; float f; } v; v.i = ((unsigned int)u) << 16; return v.f;
}
__device__ __forceinline__ unsigned short f2bf(float f) {   // round-to-nearest (packW only)
    union { float f; unsigned int i; } v; v.f = f;
    unsigned int x = v.i;
    return (unsigned short)((x + 0x7fffu + ((x >> 16) & 1u)) >> 16);
}
// fast truncation split: v ~ hi + lo, |err| <= 2^-16 |v| (4 ops)
__device__ __forceinline__ void split2(float v, unsigned short& hi, unsigned short& lo) {
    unsigned int b = __float_as_uint(v);
    hi = (unsigned short)(b >> 16);
    float rem = v - __uint_as_float(b & 0xFFFF0000u);
    lo = (unsigned short)(__float_as_uint(rem) >> 16);
}

// ---------- dtype detection: bf16 vs fp32 ----------
__global__ void k_detect(const unsigned short* __restrict__ x, int* __restrict__ flag) {
    __shared__ int cnt;
    if (threadIdx.x == 0) cnt = 0;
    __syncthreads();
    int sane = 0;
#pragma unroll
    for (int j = 0; j < 16; ++j) {
        unsigned short u = x[threadIdx.x * 16 + j];
        int e = (u >> 7) & 0xFF;
        if (e > 0x60 && e < 0xA0) sane++;
    }
    atomicAdd(&cnt, sane);
    __syncthreads();
    if (threadIdx.x == 0) *flag = (cnt > 3686) ? 1 : 0;
}

// ---------- weight conversion: (bf16|f32) -> f32 scratch ----------
struct CvtDesc { const void* src[22]; int n[22]; int off[22]; };

__global__ void k_cvt(CvtDesc d, float* __restrict__ wts, const int* __restrict__ flag) {
    int t = blockIdx.y;
    int n = d.n[t];
    bool isbf = (*flag != 0);
    const unsigned short* sb = (const unsigned short*)d.src[t];
    const float* sf = (const float*)d.src[t];
    float* o = wts + d.off[t];
    for (int i = blockIdx.x * blockDim.x + threadIdx.x; i < n; i += gridDim.x * blockDim.x)
        o[i] = isbf ? bf2f(sb[i]) : sf[i];
}

// ---------- pack SAGE weights (+ zero rowc/fill for the CSR build) ----------
__global__ void k_packW(const float* __restrict__ wts, int4 oWl, int4 oWr,
                        unsigned short* __restrict__ Wpack,
                        int* __restrict__ rowc, int* __restrict__ fill) {
    int idx = blockIdx.x * 256 + threadIdx.x;
    if (idx < NT) { rowc[idx] = 0; fill[idx] = 0; }
    if (idx >= 4 * 8 * 8 * 64 * 8) return;
    int L    = idx >> 15;
    int rem  = idx & 32767;
    int ct   = rem >> 12;
    int rem2 = rem & 4095;
    int ks   = rem2 >> 9;
    int rem3 = rem2 & 511;
    int lane = rem3 >> 3;
    int j    = rem3 & 7;
    int k   = ks * 32 + (lane >> 4) * 8 + j;
    int col = ct * 16 + (lane & 15);
    int ol = (L == 0) ? oWl.x : (L == 1) ? oWl.y : (L == 2) ? oWl.z : oWl.w;
    int orr = (L == 0) ? oWr.x : (L == 1) ? oWr.y : (L == 2) ? oWr.z : oWr.w;
    float w = (k < 128) ? wts[ol + k * 128 + col] : wts[orr + (k - 128) * 128 + col];
    unsigned short hi = f2bf(w);
    unsigned short lo = f2bf(w - bf2f(hi));
    int base = L * 65536 + (ct * 8 + ks) * 512 + lane * 8 + j;
    Wpack[base]         = hi;
    Wpack[base + 32768] = lo;
}

// ---------- edge histogram only (x is consumed in-place by layer 1) ----------
__global__ void k_hist(const int* __restrict__ dstE, int* __restrict__ rowc) {
    int e = blockIdx.x * 256 + threadIdx.x;
    if (e < NE) atomicAdd(&rowc[dstE[e]], 1);
}

// scan1 also emits initial invc (pre-pool: invc = 1/max(deg,1))
__global__ void k_scan1(const int* __restrict__ cnt, int* __restrict__ rp, int* __restrict__ bsum,
                        float* __restrict__ invc) {
    __shared__ int s[256];
    int t = threadIdx.x;
    int i = blockIdx.x * 256 + t;
    int v = cnt[i];
    invc[i] = 1.0f / fmaxf((float)v, 1.0f);
    s[t] = v;
    __syncthreads();
    for (int off = 1; off < 256; off <<= 1) {
        int a = (t >= off) ? s[t - off] : 0;
        __syncthreads();
        s[t] += a;
        __syncthreads();
    }
    rp[i] = s[t] - v;
    if (t == 255) bsum[blockIdx.x] = s[255];
}

// merged scan2+scan3
__global__ void k_scan23(int* __restrict__ rp, const int* __restrict__ bsum) {
    __shared__ int s[256];
    int t = threadIdx.x;
    s[t] = bsum[t];
    __syncthreads();
    for (int off = 1; off < 256; off <<= 1) {
        int a = (t >= off) ? s[t - off] : 0;
        __syncthreads();
        s[t] += a;
        __syncthreads();
    }
    int boffv = s[blockIdx.x] - bsum[blockIdx.x];
    int i = blockIdx.x * 256 + t;
    rp[i] += boffv;
    if (i == 0) rp[NT] = NE;
}

__global__ void k_scatter(const int* __restrict__ src, const int* __restrict__ dst,
                          const int* __restrict__ rp, int* __restrict__ fill, int* __restrict__ col) {
    int e = blockIdx.x * blockDim.x + threadIdx.x;
    if (e < NE) {
        int d = dst[e];
        int p = rp[d] + atomicAdd(&fill[d], 1);
        col[p] = src[e];
    }
}

// ---------- filtered CSR build: 1 thread/active node, block scan, ONE atomic per block ----------
__global__ void __launch_bounds__(256) k_fbuild(const int* __restrict__ act,
                                                const float* __restrict__ nm,
                                                const int* __restrict__ rp,
                                                const int* __restrict__ col,
                                                int2* __restrict__ rp2,
                                                int* __restrict__ col2,
                                                float* __restrict__ invc,
                                                int* __restrict__ ghead) {
    __shared__ int wtot[4];
    __shared__ int s_base;
    int tid = threadIdx.x;
    int lane = tid & 63, wv = tid >> 6;
    int i = blockIdx.x * 256 + tid;           // 0..NG*K1-1
    int g = i >> 10;                          // constant within block
    int n = act[i];
    int bg = rp[n], en = rp[n + 1];
    int cc = 0;
    for (int e = bg; e < en; ++e) cc += (nm[col[e]] > 0.f) ? 1 : 0;
    invc[n] = 1.0f / fmaxf((float)cc, 1.0f);

    // block-wide exclusive scan of cc
    int pre = cc;
#pragma unroll
    for (int off = 1; off < 64; off <<= 1) {
        int v = __shfl_up(pre, off, 64);
        pre += (lane >= off) ? v : 0;
    }
    if (lane == 63) wtot[wv] = pre;
    __syncthreads();
    int woff = 0;
#pragma unroll
    for (int w2 = 0; w2 < 4; ++w2) woff += (w2 < wv) ? wtot[w2] : 0;
    int ex = pre - cc + woff;
    if (tid == 0) s_base = atomicAdd(&ghead[g], wtot[0] + wtot[1] + wtot[2] + wtot[3]);
    __syncthreads();

    int p = g * EPG + s_base + ex;
    rp2[i] = make_int2(p, p + cc);
    for (int e = bg; e < en; ++e) {
        int s = col[e];
        if (nm[s] > 0.f) col2[p++] = s;
    }
}

// ---------- LDS swizzle ----------
__device__ __forceinline__ int lds_sw(int node, int k) {
    int g = k >> 3;
    int go = g ^ (node & 7);
    return node * 128 + go * 8 + (k & 7);
}

// ---------- dtype-generic row chunk load (4 feats) ----------
template<int MODE>
__device__ __forceinline__ float4 ldrow4(const void* __restrict__ h, int node, int f) {
    if constexpr (MODE == 1) {
        ushort4 v = *((const ushort4*)h + (size_t)node * 32 + (f >> 2));
        float4 o; o.x = bf2f(v.x); o.y = bf2f(v.y); o.z = bf2f(v.z); o.w = bf2f(v.w);
        return o;
    } else {
        return *((const float4*)h + (size_t)node * 32 + (f >> 2));
    }
}

// ---------- shared body: two-phase (16 KB LDS), 8-wide gather, roots issue-early/write-late ----------
template<bool HAS_TS, bool COMPACT, int MODE>
__device__ __forceinline__ void sage_body(
    const void* __restrict__ h, const float* __restrict__ ts,
    const float* __restrict__ invc,
    const int* __restrict__ rp, const int2* __restrict__ rp2,
    const int* __restrict__ col,
    const unsigned short* __restrict__ Wp,
    unsigned short* Ahi, unsigned short* Alo,
    int n0, int cb, const int* __restrict__ actb, int tid, f32x4 acc[2][2])
{
    int lane = tid & 63, w = tid >> 6;
    int lrow = lane & 15, quad = lane >> 4;
    int gnode = tid >> 5;          // 0..7 (32 threads per node)
    int f = (tid & 31) * 4;

    // ---- CSR prefetch for this thread's 4 gather nodes ----
    int gns[4], begs[4], ends[4]; float invs[4];
#pragma unroll
    for (int p = 0; p < 4; ++p) gns[p] = COMPACT ? actb[p * 8 + gnode] : n0 + p * 8 + gnode;
#pragma unroll
    for (int p = 0; p < 4; ++p) {
        if (COMPACT) { int2 be = rp2[cb + p * 8 + gnode]; begs[p] = be.x; ends[p] = be.y; }
        else         { begs[p] = rp[gns[p]]; ends[p] = rp[gns[p] + 1]; }
    }
#pragma unroll
    for (int p = 0; p < 4; ++p) invs[p] = invc[gns[p]];

    // ---- issue root-row loads NOW; values consumed only in phase B (T14 split) ----
    float4 rootv[4]; float roots[4];
#pragma unroll
    for (int i = 0; i < 4; ++i) {
        int idx = i * 256 + tid;
        int node = idx >> 5;
        int f2 = (idx & 31) * 4;
        int gn = COMPACT ? actb[node] : n0 + node;
        rootv[i] = ldrow4<MODE>(h, gn, f2);
        roots[i] = HAS_TS ? ts[gn] : 1.0f;
    }

    // ---- phase A: gather mean rows, 8 edges in flight ----
#pragma unroll
    for (int pass = 0; pass < 4; ++pass) {
        int node = pass * 8 + gnode;
        float ax = 0.f, ay = 0.f, az = 0.f, aw = 0.f;
        int beg = begs[pass], end = ends[pass];
        int ecl = end - 1;
        for (int e0 = beg; e0 < end; e0 += 8) {
            int sj[8];
#pragma unroll
            for (int j = 0; j < 8; ++j) {
                int e = (e0 + j < end) ? e0 + j : ecl;
                sj[j] = col[e];
            }
            float4 vj[8];
#pragma unroll
            for (int j = 0; j < 8; ++j)
                vj[j] = ldrow4<MODE>(h, sj[j], f);
#pragma unroll
            for (int j = 0; j < 8; ++j) {
                float cj = (e0 + j < end) ? (HAS_TS ? ts[sj[j]] : 1.0f) : 0.0f;
                ax += vj[j].x * cj;
                ay += vj[j].y * cj;
                az += vj[j].z * cj;
                aw += vj[j].w * cj;
            }
        }
        float inv = invs[pass];
        ushort4 hi4, lo4;
        split2(ax * inv, hi4.x, lo4.x);
        split2(ay * inv, hi4.y, lo4.y);
        split2(az * inv, hi4.z, lo4.z);
        split2(aw * inv, hi4.w, lo4.w);
        int a = lds_sw(node, f);
        *(ushort4*)&Ahi[a] = hi4;
        *(ushort4*)&Alo[a] = lo4;
    }
    __syncthreads();

    // ---- MFMA over Wl half (ks 0..3, from A) ----
#pragma unroll
    for (int ks = 0; ks < 4; ++ks) {
        short8 bh[2], blo[2];
#pragma unroll
        for (int c = 0; c < 2; ++c) {
            int ct = 2 * w + c;
            bh[c]  = *(const short8*)&Wp[(ct * 8 + ks) * 512 + lane * 8];
            blo[c] = *(const short8*)&Wp[32768 + (ct * 8 + ks) * 512 + lane * 8];
        }
        int kb = ks * 32 + quad * 8;
#pragma unroll
        for (int st = 0; st < 2; ++st) {
            int a = lds_sw(st * 16 + lrow, kb);
            short8 ah = *(const short8*)&Ahi[a];
            short8 al = *(const short8*)&Alo[a];
#pragma unroll
            for (int c = 0; c < 2; ++c) {
                acc[st][c] = __builtin_amdgcn_mfma_f32_16x16x32_bf16(ah, bh[c],  acc[st][c], 0, 0, 0);
                acc[st][c] = __builtin_amdgcn_mfma_f32_16x16x32_bf16(al, bh[c],  acc[st][c], 0, 0, 0);
                acc[st][c] = __builtin_amdgcn_mfma_f32_16x16x32_bf16(ah, blo[c], acc[st][c], 0, 0, 0);
            }
        }
    }
    __syncthreads();

    // ---- phase B: stage root rows from registers (loads landed long ago) ----
#pragma unroll
    for (int i = 0; i < 4; ++i) {
        int idx = i * 256 + tid;
        int node = idx >> 5;
        int f2 = (idx & 31) * 4;
        float sc = roots[i];
        ushort4 hi4, lo4;
        split2(rootv[i].x * sc, hi4.x, lo4.x);
        split2(rootv[i].y * sc, hi4.y, lo4.y);
        split2(rootv[i].z * sc, hi4.z, lo4.z);
        split2(rootv[i].w * sc, hi4.w, lo4.w);
        int a = lds_sw(node, f2);
        *(ushort4*)&Ahi[a] = hi4;
        *(ushort4*)&Alo[a] = lo4;
    }
    __syncthreads();

    // ---- MFMA over Wr half (ks 4..7, from A again) ----
#pragma unroll
    for (int ks = 4; ks < 8; ++ks) {
        short8 bh[2], blo[2];
#pragma unroll
        for (int c = 0; c < 2; ++c) {
            int ct = 2 * w + c;
            bh[c]  = *(const short8*)&Wp[(ct * 8 + ks) * 512 + lane * 8];
            blo[c] = *(const short8*)&Wp[32768 + (ct * 8 + ks) * 512 + lane * 8];
        }
        int kb = (ks - 4) * 32 + quad * 8;
#pragma unroll
        for (int st = 0; st < 2; ++st) {
            int a = lds_sw(st * 16 + lrow, kb);
            short8 ah = *(const short8*)&Ahi[a];
            short8 al = *(const short8*)&Alo[a];
#pragma unroll
            for (int c = 0; c < 2; ++c) {
                acc[st][c] = __builtin_amdgcn_mfma_f32_16x16x32_bf16(ah, bh[c],  acc[st][c], 0, 0, 0);
                acc[st][c] = __builtin_amdgcn_mfma_f32_16x16x32_bf16(al, bh[c],  acc[st][c], 0, 0, 0);
                acc[st][c] = __builtin_amdgcn_mfma_f32_16x16x32_bf16(ah, blo[c], acc[st][c], 0, 0, 0);
            }
        }
    }
}

// ---------- block -> (graph, tile) with XCD-affinity swizzle ----------
template<bool COMPACT>
__device__ __forceinline__ void map_block(int b, int& graph, int& tile) {
    if (COMPACT) { graph = (b & 7) * 4 + (b >> 8); tile = (b >> 3) & 31; }   // 1024 blocks
    else         { graph = (b & 7) * 4 + (b >> 9); tile = (b >> 3) & 63; }   // 2048 blocks
}

// ---------- layer 1: reads x directly (bf16 or f32) ----------
__global__ void __launch_bounds__(256, 6) k_sage_l1(
    const void* __restrict__ x, const int* __restrict__ flag,
    const float* __restrict__ invc,
    const int* __restrict__ rp, const int* __restrict__ col,
    const unsigned short* __restrict__ Wp, const float* __restrict__ bl,
    float* __restrict__ out)
{
    __shared__ unsigned short Ahi[32 * 128];
    __shared__ unsigned short Alo[32 * 128];
    int tid = threadIdx.x;
    int graph, tile;
    map_block<false>(blockIdx.x, graph, tile);
    int n0 = graph * NPGC + tile * 32;
    int lane = tid & 63, w = tid >> 6;
    int lrow = lane & 15, quad = lane >> 4;
    f32x4 acc[2][2] = {};

    if (*flag)
        sage_body<false, false, 1>(x, nullptr, invc, rp, nullptr, col, Wp, Ahi, Alo, n0, 0, nullptr, tid, acc);
    else
        sage_body<false, false, 0>(x, nullptr, invc, rp, nullptr, col, Wp, Ahi, Alo, n0, 0, nullptr, tid, acc);

#pragma unroll
    for (int c = 0; c < 2; ++c) {
        int colg = (2 * w + c) * 16 + lrow;
        float bias = bl[colg];
#pragma unroll
        for (int st = 0; st < 2; ++st) {
#pragma unroll
            for (int rr = 0; rr < 4; ++rr) {
                int node = n0 + st * 16 + quad * 4 + rr;
                out[(size_t)node * HID + colg] = fmaxf(acc[st][c][rr] + bias, 0.f);
            }
        }
    }
}

// ---------- layer 3: compact plain (filtered CSR) ----------
__global__ void __launch_bounds__(256, 6) k_sage_plain(
    const float* __restrict__ h, const float* __restrict__ ts,
    const float* __restrict__ invc,
    const int2* __restrict__ rp2, const int* __restrict__ col2,
    const unsigned short* __restrict__ Wp, const float* __restrict__ bl,
    float* __restrict__ out, const int* __restrict__ act)
{
    __shared__ unsigned short Ahi[32 * 128];
    __shared__ unsigned short Alo[32 * 128];
    int tid = threadIdx.x;
    int graph, tile;
    map_block<true>(blockIdx.x, graph, tile);
    int n0 = graph * NPGC + tile * 32;
    int cb = graph * K1 + tile * 32;
    const int* actb = act + cb;
    int lane = tid & 63, w = tid >> 6;
    int lrow = lane & 15, quad = lane >> 4;
    f32x4 acc[2][2] = {};

    sage_body<true, true, 0>(h, ts, invc, nullptr, rp2, col2, Wp, Ahi, Alo, n0, cb, actb, tid, acc);

#pragma unroll
    for (int c = 0; c < 2; ++c) {
        int colg = (2 * w + c) * 16 + lrow;
        float bias = bl[colg];
#pragma unroll
        for (int st = 0; st < 2; ++st) {
#pragma unroll
            for (int rr = 0; rr < 4; ++rr) {
                int node = actb[st * 16 + quad * 4 + rr];
                out[(size_t)node * HID + colg] = fmaxf(acc[st][c][rr] + bias, 0.f);
            }
        }
    }
}

// ---------- layers 2 & 4: SAGE + pool dots ----------
template<bool COMPACT>
__global__ void __launch_bounds__(256, 6) k_sage_dots(
    const float* __restrict__ h,
    const float* __restrict__ invc,
    const int* __restrict__ rp, const int2* __restrict__ rp2,
    const int* __restrict__ col,
    const unsigned short* __restrict__ Wp, const float* __restrict__ bl,
    float* __restrict__ out,
    const float* __restrict__ Prel, const float* __restrict__ Proot,
    float* __restrict__ q, float* __restrict__ r, const int* __restrict__ act)
{
    __shared__ unsigned short Ahi[32 * 128];
    __shared__ unsigned short Alo[32 * 128];
    int tid = threadIdx.x;
    int graph, tile;
    map_block<COMPACT>(blockIdx.x, graph, tile);
    int n0 = graph * NPGC + tile * 32;
    int cb = COMPACT ? (graph * K1 + tile * 32) : 0;
    const int* actb = COMPACT ? (act + cb) : nullptr;
    int lane = tid & 63, w = tid >> 6;
    int lrow = lane & 15, quad = lane >> 4;
    f32x4 acc[2][2] = {};

    // layer 4 (COMPACT): filtered CSR => all sources active => no ts needed
    sage_body<false, COMPACT, 0>(h, nullptr, invc, rp, rp2, col, Wp, Ahi, Alo, n0, cb, actb, tid, acc);

    float qp[2][4] = {}, rp_[2][4] = {};
#pragma unroll
    for (int c = 0; c < 2; ++c) {
        int colg = (2 * w + c) * 16 + lrow;
        float bias = bl[colg];
        float pq = Prel[colg], pr = Proot[colg];
#pragma unroll
        for (int st = 0; st < 2; ++st) {
#pragma unroll
            for (int rr = 0; rr < 4; ++rr) {
                int nl = st * 16 + quad * 4 + rr;
                int node = COMPACT ? actb[nl] : n0 + nl;
                float val = fmaxf(acc[st][c][rr] + bias, 0.f);
                out[(size_t)node * HID + colg] = val;
                qp[st][rr] += val * pq;
                rp_[st][rr] += val * pr;
            }
        }
    }
#pragma unroll
    for (int st = 0; st < 2; ++st)
#pragma unroll
        for (int rr = 0; rr < 4; ++rr) {
#pragma unroll
            for (int m = 1; m < 16; m <<= 1) {
                qp[st][rr]  += __shfl_xor(qp[st][rr],  m, 64);
                rp_[st][rr] += __shfl_xor(rp_[st][rr], m, 64);
            }
        }
    __syncthreads();
    float* qa = (float*)Ahi;
    if (tid < 64) qa[tid] = 0.f;
    __syncthreads();
    if (lrow == 0) {
#pragma unroll
        for (int st = 0; st < 2; ++st)
#pragma unroll
            for (int rr = 0; rr < 4; ++rr) {
                int nl = st * 16 + quad * 4 + rr;
                atomicAdd(&qa[nl], qp[st][rr]);
                atomicAdd(&qa[32 + nl], rp_[st][rr]);
            }
    }
    __syncthreads();
    if (tid < 32) {
        int node = COMPACT ? actb[tid] : n0 + tid;
        q[node] = qa[tid];
        r[node] = qa[32 + tid];
    }
}

// ---------- score = segsum(q[src]) + r + prb (full, pool 1) ----------
__global__ void k_score(const float* __restrict__ q, const float* __restrict__ r,
                        const float* __restrict__ prb,
                        const int* __restrict__ rp, const int* __restrict__ col,
                        float* __restrict__ score) {
    int n = blockIdx.x * 256 + threadIdx.x;
    int beg = rp[n], end = rp[n + 1];
    float s = 0.f;
    for (int e = beg; e < end; ++e) s += q[col[e]];
    score[n] = s + r[n] + prb[0];
}

// ---------- score over active nodes via filtered CSR (pool 2) ----------
__global__ void k_score2(const float* __restrict__ q, const float* __restrict__ r,
                         const float* __restrict__ prb,
                         const int2* __restrict__ rp2, const int* __restrict__ col2,
                         float* __restrict__ score, const int* __restrict__ act) {
    int i = blockIdx.x * 256 + threadIdx.x;
    int n = act[i];
    int2 be = rp2[i];
    float s = 0.f;
    for (int e = be.x; e < be.y; ++e) s += q[col2[e]];
    score[n] = s + r[n] + prb[0];
}

// ---------- per-graph top-k via radix select; emits compact active list ----------
template<bool NMIN>
__global__ void __launch_bounds__(256) k_topk(const float* __restrict__ score,
                                              float* __restrict__ nm,
                                              float* __restrict__ tval, int k,
                                              int* __restrict__ act) {
    __shared__ unsigned int u[NPGC];
    __shared__ int hist[256];
    __shared__ int scanb[257];
    __shared__ int wtot[4];
    __shared__ int wtot2[4];
    __shared__ unsigned int s_byte;
    __shared__ int s_kk;
    int tid = threadIdx.x;
    int lane = tid & 63, wv = tid >> 6;
    int base = blockIdx.x * NPGC;

    for (int j = tid; j < NPGC; j += 256) {
        float sc = NMIN ? ((nm[base + j] > 0.f) ? score[base + j] : -1e30f) : score[base + j];
        unsigned int v = __float_as_uint(sc);
        v = (v & 0x80000000u) ? ~v : (v | 0x80000000u);
        u[j] = v;
    }
    hist[tid] = 0;
    if (tid == 0) scanb[256] = 0;
    __syncthreads();

    unsigned int prefix = 0;
    int kk = k;
#pragma unroll
    for (int round = 0; round < 4; ++round) {
        int shift = 24 - 8 * round;
        unsigned int pmask = (round == 0) ? 0u : (0xFFFFFFFFu << (32 - 8 * round));
        for (int j = tid; j < NPGC; j += 256) {
            unsigned int v = u[j];
            if ((v & pmask) == prefix) atomicAdd(&hist[(v >> shift) & 0xFF], 1);
        }
        __syncthreads();
        int s = hist[tid];
#pragma unroll
        for (int off = 1; off < 64; off <<= 1) {
            int t = __shfl_down(s, off, 64);
            s += (lane + off < 64) ? t : 0;
        }
        if (lane == 0) wtot[wv] = s;
        __syncthreads();
        int add = 0;
#pragma unroll
        for (int w2 = 1; w2 < 4; ++w2) add += (wv + w2 < 4) ? wtot[wv + w2] : 0;
        s += add;
        scanb[tid] = s;
        __syncthreads();
        int above = scanb[tid + 1];
        if (s >= kk && above < kk) { s_byte = (unsigned int)tid; s_kk = kk - above; }
        hist[tid] = 0;
        __syncthreads();
        prefix |= (s_byte << shift);
        kk = s_kk;
    }
    unsigned int thr = prefix;

    int j0 = tid * 8;
    int cnt = 0;
#pragma unroll
    for (int j = 0; j < 8; ++j) cnt += (u[j0 + j] == thr);
    int s = cnt;
#pragma unroll
    for (int off = 1; off < 64; off <<= 1) {
        int t = __shfl_up(s, off, 64);
        s += (lane >= off) ? t : 0;
    }
    if (lane == 63) wtot[wv] = s;
    __syncthreads();
    int add = 0;
#pragma unroll
    for (int w2 = 0; w2 < 4; ++w2) add += (w2 < wv) ? wtot[w2] : 0;
    int rank = s - cnt + add;

    // keep flags (exact k kept per graph by construction of the select)
    unsigned int keepmask = 0u;
    int myrank = rank;
    int kcnt = 0;
#pragma unroll
    for (int j = 0; j < 8; ++j) {
        unsigned int v = u[j0 + j];
        bool kp;
        if (v > thr) kp = true;
        else if (v == thr) { kp = (myrank < kk); myrank++; }
        else kp = false;
        keepmask |= (kp ? 1u : 0u) << j;
        kcnt += kp ? 1 : 0;
    }
    // block-wide exclusive scan of keep counts -> compact write position
    int s2 = kcnt;
#pragma unroll
    for (int off = 1; off < 64; off <<= 1) {
        int t2 = __shfl_up(s2, off, 64);
        s2 += (lane >= off) ? t2 : 0;
    }
    if (lane == 63) wtot2[wv] = s2;
    __syncthreads();
    int pos = s2 - kcnt;
#pragma unroll
    for (int w2 = 0; w2 < 4; ++w2) pos += (w2 < wv) ? wtot2[w2] : 0;
    int* actg = act + blockIdx.x * k;
#pragma unroll
    for (int j = 0; j < 8; ++j) {
        bool kp = (keepmask >> j) & 1u;
        int n = base + j0 + j;
        nm[n]   = kp ? 1.0f : 0.0f;
        tval[n] = kp ? tanhf(score[n]) : 0.0f;
        if (kp) actg[pos++] = n;
    }
}

// ---------- readout + MLP head + log_softmax, one block per graph ----------
__global__ void k_tail(const float* __restrict__ h, const float* __restrict__ t,
                       const int* __restrict__ act,
                       const float* __restrict__ W5, const float* __restrict__ b5,
                       const float* __restrict__ W6, const float* __restrict__ b6,
                       void* __restrict__ out, const int* __restrict__ flag) {
    __shared__ float gsh[2][HID];
    __shared__ float g5[64];
    __shared__ float ls[2];
    int graph = blockIdx.x, tid = threadIdx.x;
    int f = tid & 127, sub = tid >> 7;
    const int* actg = act + graph * K2;
    float acc = 0.f;
#pragma unroll 8
    for (int i = 0; i < 256; ++i) {
        int gn = actg[sub * 256 + i];
        acc += h[(size_t)gn * HID + f] * t[gn];
    }
    gsh[sub][f] = acc;
    __syncthreads();
    if (tid < 64) {
        const float ic = 1.0f / (float)K2;
        float a5 = b5[tid];
        for (int ff = 0; ff < HID; ++ff)
            a5 += (gsh[0][ff] + gsh[1][ff]) * ic * W5[ff * 64 + tid];
        g5[tid] = fmaxf(a5, 0.f);
    }
    __syncthreads();
    if (tid < 2) {
        float l = b6[tid];
        for (int tt = 0; tt < 64; ++tt) l += g5[tt] * W6[tt * 2 + tid];
        ls[tid] = l;
    }
    __syncthreads();
    if (tid == 0) {
        float a = ls[0], b = ls[1];
        float mx = fmaxf(a, b);
        float lse = mx + logf(expf(a - mx) + expf(b - mx));
        if (*flag) {
            ((unsigned short*)out)[graph * 2 + 0] = f2bf(a - lse);
            ((unsigned short*)out)[graph * 2 + 1] = f2bf(b - lse);
        } else {
            ((float*)out)[graph * 2 + 0] = a - lse;
            ((float*)out)[graph * 2 + 1] = b - lse;
        }
    }
}

extern "C" void kernel_launch(void* const* d_in, const int* in_sizes, int n_in,
                              void* d_out, int out_size, void* d_ws, size_t ws_size,
                              hipStream_t stream) {
    const void* x    = d_in[0];
    const int*  ei   = (const int*)d_in[1];
    const int*  srcE = ei;
    const int*  dstE = ei + NE;

    char* ws = (char*)d_ws;
    float* hA    = (float*)(ws + 0);
    float* hB    = (float*)(ws + 33554432);
    float* tvec  = (float*)(ws + 67108864);
    float* invc  = (float*)(ws + 67371008);
    int*   col2  = (int*)  (ws + 67633152);   // 2 MB (per-graph arenas of EPG)
    int2*  rp2   = (int2*) (ws + 69730304);   // 256 KB
    int*   ghead = (int*)  (ws + 69992448);   // 128 B
    float* q     = (float*)(ws + 100663296);
    float* r     = (float*)(ws + 100925440);
    float* score = (float*)(ws + 101187584);
    float* nm    = (float*)(ws + 101449728);
    int*   rowc  = (int*)  (ws + 101711872);  // reused as act1 (32768 ints) after scan1
    int*   rp    = (int*)  (ws + 101974016);
    int*   bsum  = (int*)  (ws + 102236416);
    int*   fill  = (int*)  (ws + 102238464);  // reused as act2 (16384 ints) after scatter
    int*   col   = (int*)  (ws + 102500608);
    int*   flag  = (int*)  (ws + 104615936);
    float* wts   = (float*)(ws + 104616960);
    unsigned short* Wpack = (unsigned short*)(ws + 105179136);
    int*   act1  = rowc;
    int*   act2  = fill;
    (void)in_sizes; (void)n_in; (void)out_size; (void)ws_size;

    const int O_Wl1 = 0,      O_bl1 = 16384,  O_Wr1 = 16512;
    const int O_Wl2 = 32896,  O_bl2 = 49280,  O_Wr2 = 49408;
    const int O_Wl3 = 65792,  O_bl3 = 82176,  O_Wr3 = 82304;
    const int O_Wl4 = 98688,  O_bl4 = 115072, O_Wr4 = 115200;
    const int O_Pr1 = 131584, O_pb1 = 131712, O_Po1 = 131713;
    const int O_Pr2 = 131841, O_pb2 = 131969, O_Po2 = 131970;
    const int O_W5  = 132098, O_b5  = 140290, O_W6 = 140354, O_b6 = 140482;

    CvtDesc d;
    const int srcIdx[22] = {4,5,6,7,8,9,10,11,12,13,14,15,16,17,18,19,20,21,22,23,24,25};
    const int nelems[22] = {16384,128,16384, 16384,128,16384, 16384,128,16384, 16384,128,16384,
                            128,1,128, 128,1,128, 8192,64,128,2};
    const int offs[22]   = {O_Wl1,O_bl1,O_Wr1, O_Wl2,O_bl2,O_Wr2, O_Wl3,O_bl3,O_Wr3, O_Wl4,O_bl4,O_Wr4,
                            O_Pr1,O_pb1,O_Po1, O_Pr2,O_pb2,O_Po2, O_W5,O_b5,O_W6,O_b6};
    for (int i = 0; i < 22; ++i) { d.src[i] = d_in[srcIdx[i]]; d.n[i] = nelems[i]; d.off[i] = offs[i]; }

    hipMemsetAsync(ghead, 0, NG * 4, stream);

    k_detect <<<1, 256, 0, stream>>>((const unsigned short*)x, flag);
    k_cvt    <<<dim3(64, 22), 256, 0, stream>>>(d, wts, flag);
    k_packW  <<<512, 256, 0, stream>>>(wts, make_int4(O_Wl1, O_Wl2, O_Wl3, O_Wl4),
                                       make_int4(O_Wr1, O_Wr2, O_Wr3, O_Wr4), Wpack, rowc, fill);
    k_hist   <<<2048, 256, 0, stream>>>(dstE, rowc);

    k_scan1  <<<256, 256, 0, stream>>>(rowc, rp, bsum, invc);
    k_scan23 <<<256, 256, 0, stream>>>(rp, bsum);
    k_scatter<<<2048, 256, 0, stream>>>(srcE, dstE, rp, fill, col);

    // layer 1: x -> hB (reads x directly, bf16 or f32)
    k_sage_l1<<<2048, 256, 0, stream>>>(x, flag, invc, rp, col,
                                        Wpack + 0 * 65536, wts + O_bl1, hB);
    // layer 2: hB -> hA  (+ fused pool-1 dots)
    k_sage_dots<false><<<2048, 256, 0, stream>>>(hB, invc, rp, nullptr, col,
                                                 Wpack + 1 * 65536, wts + O_bl2, hA,
                                                 wts + O_Pr1, wts + O_Po1, q, r, nullptr);

    // pool 1 (k = 1024): topk emits act1; parallel filtered-CSR build + invc
    k_score<<<256, 256, 0, stream>>>(q, r, wts + O_pb1, rp, col, score);
    k_topk<false><<<32, 256, 0, stream>>>(score, nm, tvec, K1, act1);
    k_fbuild<<<NG * K1 / 256, 256, 0, stream>>>(act1, nm, rp, col, rp2, col2, invc, ghead);

    // layer 3 (compact, filtered CSR): hA (scaled by tvec) -> hB
    k_sage_plain<<<1024, 256, 0, stream>>>(hA, tvec, invc, rp2, col2,
                                           Wpack + 2 * 65536, wts + O_bl3, hB, act1);
    // layer 4 (compact, filtered CSR => no ts needed): hB -> hA (+ pool-2 dots)
    k_sage_dots<true><<<1024, 256, 0, stream>>>(hB, invc, nullptr, rp2, col2,
                                                Wpack + 3 * 65536, wts + O_bl4, hA,
                                                wts + O_Pr2, wts + O_Po2, q, r, act1);

    // pool 2 (k = 512): score over filtered CSR; emits act2
    k_score2<<<NG * K1 / 256, 256, 0, stream>>>(q, r, wts + O_pb2, rp2, col2, score, act1);
    k_topk<true><<<32, 256, 0, stream>>>(score, nm, tvec, K2, act2);

    // readout + MLP head (one block per graph; count == K2 folded in)
    k_tail<<<32, 256, 0, stream>>>(hA, tvec, act2, wts + O_W5, wts + O_b5,
                                   wts + O_W6, wts + O_b6, d_out, flag);
}

// Round 10
// 376.124 us; speedup vs baseline: 1.0934x; 1.0043x over previous
//
#include <hip/hip_runtime.h>
#include <hip/hip_bf16.h>
#include <math.h>

#define NT   65536      // total nodes (32 graphs * 2048)
#define NPGC 2048       // nodes per graph
#define NG   32         // graphs
#define NE   524288     // edges
#define EPG  16384      // edges per graph (col2 arena stride)
#define HID  128
#define K1   1024       // pool-1 keep per graph
#define K2   512        // pool-2 keep per graph

typedef short short8 __attribute__((ext_vector_type(8)));
typedef float f32x4  __attribute__((ext_vector_type(4)));

__device__ __forceinline__ float bf2f(unsigned short u) {
    union { unsigned int i; float f; } v; v.i = ((unsigned int)u) << 16; return v.f;
}
__device__ __forceinline__ unsigned short f2bf(float f) {   // round-to-nearest (packW only)
    union { float f; unsigned int i; } v; v.f = f;
    unsigned int x = v.i;
    return (unsigned short)((x + 0x7fffu + ((x >> 16) & 1u)) >> 16);
}
// fast truncation split: v ~ hi + lo, |err| <= 2^-16 |v| (4 ops)
__device__ __forceinline__ void split2(float v, unsigned short& hi, unsigned short& lo) {
    unsigned int b = __float_as_uint(v);
    hi = (unsigned short)(b >> 16);
    float rem = v - __uint_as_float(b & 0xFFFF0000u);
    lo = (unsigned short)(__float_as_uint(rem) >> 16);
}

// ---------- dtype detection: bf16 vs fp32 ----------
__global__ void k_detect(const unsigned short* __restrict__ x, int* __restrict__ flag) {
    __shared__ int cnt;
    if (threadIdx.x == 0) cnt = 0;
    __syncthreads();
    int sane = 0;
#pragma unroll
    for (int j = 0; j < 16; ++j) {
        unsigned short u = x[threadIdx.x * 16 + j];
        int e = (u >> 7) & 0xFF;
        if (e > 0x60 && e < 0xA0) sane++;
    }
    atomicAdd(&cnt, sane);
    __syncthreads();
    if (threadIdx.x == 0) *flag = (cnt > 3686) ? 1 : 0;
}

// ---------- weight conversion: (bf16|f32) -> f32 scratch ----------
struct CvtDesc { const void* src[22]; int n[22]; int off[22]; };

__global__ void k_cvt(CvtDesc d, float* __restrict__ wts, const int* __restrict__ flag) {
    int t = blockIdx.y;
    int n = d.n[t];
    bool isbf = (*flag != 0);
    const unsigned short* sb = (const unsigned short*)d.src[t];
    const float* sf = (const float*)d.src[t];
    float* o = wts + d.off[t];
    for (int i = blockIdx.x * blockDim.x + threadIdx.x; i < n; i += gridDim.x * blockDim.x)
        o[i] = isbf ? bf2f(sb[i]) : sf[i];
}

// ---------- pack SAGE weights (+ zero rowc/fill for the CSR build) ----------
__global__ void k_packW(const float* __restrict__ wts, int4 oWl, int4 oWr,
                        unsigned short* __restrict__ Wpack,
                        int* __restrict__ rowc, int* __restrict__ fill) {
    int idx = blockIdx.x * 256 + threadIdx.x;
    if (idx < NT) { rowc[idx] = 0; fill[idx] = 0; }
    if (idx >= 4 * 8 * 8 * 64 * 8) return;
    int L    = idx >> 15;
    int rem  = idx & 32767;
    int ct   = rem >> 12;
    int rem2 = rem & 4095;
    int ks   = rem2 >> 9;
    int rem3 = rem2 & 511;
    int lane = rem3 >> 3;
    int j    = rem3 & 7;
    int k   = ks * 32 + (lane >> 4) * 8 + j;
    int col = ct * 16 + (lane & 15);
    int ol = (L == 0) ? oWl.x : (L == 1) ? oWl.y : (L == 2) ? oWl.z : oWl.w;
    int orr = (L == 0) ? oWr.x : (L == 1) ? oWr.y : (L == 2) ? oWr.z : oWr.w;
    float w = (k < 128) ? wts[ol + k * 128 + col] : wts[orr + (k - 128) * 128 + col];
    unsigned short hi = f2bf(w);
    unsigned short lo = f2bf(w - bf2f(hi));
    int base = L * 65536 + (ct * 8 + ks) * 512 + lane * 8 + j;
    Wpack[base]         = hi;
    Wpack[base + 32768] = lo;
}

// ---------- edge histogram only (x is consumed in-place by layer 1) ----------
__global__ void k_hist(const int* __restrict__ dstE, int* __restrict__ rowc) {
    int e = blockIdx.x * 256 + threadIdx.x;
    if (e < NE) atomicAdd(&rowc[dstE[e]], 1);
}

// scan1 also emits initial invc (pre-pool: invc = 1/max(deg,1))
__global__ void k_scan1(const int* __restrict__ cnt, int* __restrict__ rp, int* __restrict__ bsum,
                        float* __restrict__ invc) {
    __shared__ int s[256];
    int t = threadIdx.x;
    int i = blockIdx.x * 256 + t;
    int v = cnt[i];
    invc[i] = 1.0f / fmaxf((float)v, 1.0f);
    s[t] = v;
    __syncthreads();
    for (int off = 1; off < 256; off <<= 1) {
        int a = (t >= off) ? s[t - off] : 0;
        __syncthreads();
        s[t] += a;
        __syncthreads();
    }
    rp[i] = s[t] - v;
    if (t == 255) bsum[blockIdx.x] = s[255];
}

// merged scan2+scan3
__global__ void k_scan23(int* __restrict__ rp, const int* __restrict__ bsum) {
    __shared__ int s[256];
    int t = threadIdx.x;
    s[t] = bsum[t];
    __syncthreads();
    for (int off = 1; off < 256; off <<= 1) {
        int a = (t >= off) ? s[t - off] : 0;
        __syncthreads();
        s[t] += a;
        __syncthreads();
    }
    int boffv = s[blockIdx.x] - bsum[blockIdx.x];
    int i = blockIdx.x * 256 + t;
    rp[i] += boffv;
    if (i == 0) rp[NT] = NE;
}

__global__ void k_scatter(const int* __restrict__ src, const int* __restrict__ dst,
                          const int* __restrict__ rp, int* __restrict__ fill, int* __restrict__ col) {
    int e = blockIdx.x * blockDim.x + threadIdx.x;
    if (e < NE) {
        int d = dst[e];
        int p = rp[d] + atomicAdd(&fill[d], 1);
        col[p] = src[e];
    }
}

// ---------- filtered CSR build: 1 thread/active node, block scan, ONE atomic per block ----------
__global__ void __launch_bounds__(256) k_fbuild(const int* __restrict__ act,
                                                const float* __restrict__ nm,
                                                const int* __restrict__ rp,
                                                const int* __restrict__ col,
                                                int2* __restrict__ rp2,
                                                int* __restrict__ col2,
                                                float* __restrict__ invc,
                                                int* __restrict__ ghead) {
    __shared__ int wtot[4];
    __shared__ int s_base;
    int tid = threadIdx.x;
    int lane = tid & 63, wv = tid >> 6;
    int i = blockIdx.x * 256 + tid;           // 0..NG*K1-1
    int g = i >> 10;                          // constant within block
    int n = act[i];
    int bg = rp[n], en = rp[n + 1];
    int cc = 0;
    for (int e = bg; e < en; ++e) cc += (nm[col[e]] > 0.f) ? 1 : 0;
    invc[n] = 1.0f / fmaxf((float)cc, 1.0f);

    // block-wide exclusive scan of cc
    int pre = cc;
#pragma unroll
    for (int off = 1; off < 64; off <<= 1) {
        int v = __shfl_up(pre, off, 64);
        pre += (lane >= off) ? v : 0;
    }
    if (lane == 63) wtot[wv] = pre;
    __syncthreads();
    int woff = 0;
#pragma unroll
    for (int w2 = 0; w2 < 4; ++w2) woff += (w2 < wv) ? wtot[w2] : 0;
    int ex = pre - cc + woff;
    if (tid == 0) s_base = atomicAdd(&ghead[g], wtot[0] + wtot[1] + wtot[2] + wtot[3]);
    __syncthreads();

    int p = g * EPG + s_base + ex;
    rp2[i] = make_int2(p, p + cc);
    for (int e = bg; e < en; ++e) {
        int s = col[e];
        if (nm[s] > 0.f) col2[p++] = s;
    }
}

// ---------- LDS swizzle ----------
__device__ __forceinline__ int lds_sw(int node, int k) {
    int g = k >> 3;
    int go = g ^ (node & 7);
    return node * 128 + go * 8 + (k & 7);
}

// ---------- dtype-generic row chunk load (4 feats) ----------
template<int MODE>
__device__ __forceinline__ float4 ldrow4(const void* __restrict__ h, int node, int f) {
    if constexpr (MODE == 1) {
        ushort4 v = *((const ushort4*)h + (size_t)node * 32 + (f >> 2));
        float4 o; o.x = bf2f(v.x); o.y = bf2f(v.y); o.z = bf2f(v.z); o.w = bf2f(v.w);
        return o;
    } else {
        return *((const float4*)h + (size_t)node * 32 + (f >> 2));
    }
}

// ---------- shared body: two-phase (16 KB LDS), 8-wide gather, CSR prefetched (R7 form) ----------
template<bool HAS_TS, bool COMPACT, int MODE>
__device__ __forceinline__ void sage_body(
    const void* __restrict__ h, const float* __restrict__ ts,
    const float* __restrict__ invc,
    const int* __restrict__ rp, const int2* __restrict__ rp2,
    const int* __restrict__ col,
    const unsigned short* __restrict__ Wp,
    unsigned short* Ahi, unsigned short* Alo,
    int n0, int cb, const int* __restrict__ actb, int tid, f32x4 acc[2][2])
{
    int lane = tid & 63, w = tid >> 6;
    int lrow = lane & 15, quad = lane >> 4;
    int gnode = tid >> 5;          // 0..7 (32 threads per node)
    int f = (tid & 31) * 4;

    // ---- CSR prefetch for this thread's 4 gather nodes ----
    int gns[4], begs[4], ends[4]; float invs[4];
#pragma unroll
    for (int p = 0; p < 4; ++p) gns[p] = COMPACT ? actb[p * 8 + gnode] : n0 + p * 8 + gnode;
#pragma unroll
    for (int p = 0; p < 4; ++p) {
        if (COMPACT) { int2 be = rp2[cb + p * 8 + gnode]; begs[p] = be.x; ends[p] = be.y; }
        else         { begs[p] = rp[gns[p]]; ends[p] = rp[gns[p] + 1]; }
    }
#pragma unroll
    for (int p = 0; p < 4; ++p) invs[p] = invc[gns[p]];

    // ---- phase A: gather mean rows, 8 edges in flight ----
#pragma unroll
    for (int pass = 0; pass < 4; ++pass) {
        int node = pass * 8 + gnode;
        float ax = 0.f, ay = 0.f, az = 0.f, aw = 0.f;
        int beg = begs[pass], end = ends[pass];
        int ecl = end - 1;
        for (int e0 = beg; e0 < end; e0 += 8) {
            int sj[8];
#pragma unroll
            for (int j = 0; j < 8; ++j) {
                int e = (e0 + j < end) ? e0 + j : ecl;
                sj[j] = col[e];
            }
            float4 vj[8];
#pragma unroll
            for (int j = 0; j < 8; ++j)
                vj[j] = ldrow4<MODE>(h, sj[j], f);
#pragma unroll
            for (int j = 0; j < 8; ++j) {
                float cj = (e0 + j < end) ? (HAS_TS ? ts[sj[j]] : 1.0f) : 0.0f;
                ax += vj[j].x * cj;
                ay += vj[j].y * cj;
                az += vj[j].z * cj;
                aw += vj[j].w * cj;
            }
        }
        float inv = invs[pass];
        ushort4 hi4, lo4;
        split2(ax * inv, hi4.x, lo4.x);
        split2(ay * inv, hi4.y, lo4.y);
        split2(az * inv, hi4.z, lo4.z);
        split2(aw * inv, hi4.w, lo4.w);
        int a = lds_sw(node, f);
        *(ushort4*)&Ahi[a] = hi4;
        *(ushort4*)&Alo[a] = lo4;
    }
    __syncthreads();

    // ---- MFMA over Wl half (ks 0..3, from A) ----
#pragma unroll
    for (int ks = 0; ks < 4; ++ks) {
        short8 bh[2], blo[2];
#pragma unroll
        for (int c = 0; c < 2; ++c) {
            int ct = 2 * w + c;
            bh[c]  = *(const short8*)&Wp[(ct * 8 + ks) * 512 + lane * 8];
            blo[c] = *(const short8*)&Wp[32768 + (ct * 8 + ks) * 512 + lane * 8];
        }
        int kb = ks * 32 + quad * 8;
#pragma unroll
        for (int st = 0; st < 2; ++st) {
            int a = lds_sw(st * 16 + lrow, kb);
            short8 ah = *(const short8*)&Ahi[a];
            short8 al = *(const short8*)&Alo[a];
#pragma unroll
            for (int c = 0; c < 2; ++c) {
                acc[st][c] = __builtin_amdgcn_mfma_f32_16x16x32_bf16(ah, bh[c],  acc[st][c], 0, 0, 0);
                acc[st][c] = __builtin_amdgcn_mfma_f32_16x16x32_bf16(al, bh[c],  acc[st][c], 0, 0, 0);
                acc[st][c] = __builtin_amdgcn_mfma_f32_16x16x32_bf16(ah, blo[c], acc[st][c], 0, 0, 0);
            }
        }
    }
    __syncthreads();

    // ---- phase B: stage root rows into the SAME buffer (coalesced) ----
#pragma unroll
    for (int i = 0; i < 4; ++i) {
        int idx = i * 256 + tid;
        int node = idx >> 5;
        int f2 = (idx & 31) * 4;
        int gn = COMPACT ? actb[node] : n0 + node;
        float4 v = ldrow4<MODE>(h, gn, f2);
        float sc = HAS_TS ? ts[gn] : 1.0f;
        ushort4 hi4, lo4;
        split2(v.x * sc, hi4.x, lo4.x);
        split2(v.y * sc, hi4.y, lo4.y);
        split2(v.z * sc, hi4.z, lo4.z);
        split2(v.w * sc, hi4.w, lo4.w);
        int a = lds_sw(node, f2);
        *(ushort4*)&Ahi[a] = hi4;
        *(ushort4*)&Alo[a] = lo4;
    }
    __syncthreads();

    // ---- MFMA over Wr half (ks 4..7, from A again) ----
#pragma unroll
    for (int ks = 4; ks < 8; ++ks) {
        short8 bh[2], blo[2];
#pragma unroll
        for (int c = 0; c < 2; ++c) {
            int ct = 2 * w + c;
            bh[c]  = *(const short8*)&Wp[(ct * 8 + ks) * 512 + lane * 8];
            blo[c] = *(const short8*)&Wp[32768 + (ct * 8 + ks) * 512 + lane * 8];
        }
        int kb = (ks - 4) * 32 + quad * 8;
#pragma unroll
        for (int st = 0; st < 2; ++st) {
            int a = lds_sw(st * 16 + lrow, kb);
            short8 ah = *(const short8*)&Ahi[a];
            short8 al = *(const short8*)&Alo[a];
#pragma unroll
            for (int c = 0; c < 2; ++c) {
                acc[st][c] = __builtin_amdgcn_mfma_f32_16x16x32_bf16(ah, bh[c],  acc[st][c], 0, 0, 0);
                acc[st][c] = __builtin_amdgcn_mfma_f32_16x16x32_bf16(al, bh[c],  acc[st][c], 0, 0, 0);
                acc[st][c] = __builtin_amdgcn_mfma_f32_16x16x32_bf16(ah, blo[c], acc[st][c], 0, 0, 0);
            }
        }
    }
}

// ---------- block -> (graph, tile) with XCD-affinity swizzle ----------
template<bool COMPACT>
__device__ __forceinline__ void map_block(int b, int& graph, int& tile) {
    if (COMPACT) { graph = (b & 7) * 4 + (b >> 8); tile = (b >> 3) & 31; }   // 1024 blocks
    else         { graph = (b & 7) * 4 + (b >> 9); tile = (b >> 3) & 63; }   // 2048 blocks
}

// ---------- layer 1: reads x directly (bf16 or f32) ----------
__global__ void __launch_bounds__(256, 8) k_sage_l1(
    const void* __restrict__ x, const int* __restrict__ flag,
    const float* __restrict__ invc,
    const int* __restrict__ rp, const int* __restrict__ col,
    const unsigned short* __restrict__ Wp, const float* __restrict__ bl,
    float* __restrict__ out)
{
    __shared__ unsigned short Ahi[32 * 128];
    __shared__ unsigned short Alo[32 * 128];
    int tid = threadIdx.x;
    int graph, tile;
    map_block<false>(blockIdx.x, graph, tile);
    int n0 = graph * NPGC + tile * 32;
    int lane = tid & 63, w = tid >> 6;
    int lrow = lane & 15, quad = lane >> 4;
    f32x4 acc[2][2] = {};

    if (*flag)
        sage_body<false, false, 1>(x, nullptr, invc, rp, nullptr, col, Wp, Ahi, Alo, n0, 0, nullptr, tid, acc);
    else
        sage_body<false, false, 0>(x, nullptr, invc, rp, nullptr, col, Wp, Ahi, Alo, n0, 0, nullptr, tid, acc);

#pragma unroll
    for (int c = 0; c < 2; ++c) {
        int colg = (2 * w + c) * 16 + lrow;
        float bias = bl[colg];
#pragma unroll
        for (int st = 0; st < 2; ++st) {
#pragma unroll
            for (int rr = 0; rr < 4; ++rr) {
                int node = n0 + st * 16 + quad * 4 + rr;
                out[(size_t)node * HID + colg] = fmaxf(acc[st][c][rr] + bias, 0.f);
            }
        }
    }
}

// ---------- layer 3: compact plain (filtered CSR) ----------
__global__ void __launch_bounds__(256, 8) k_sage_plain(
    const float* __restrict__ h, const float* __restrict__ ts,
    const float* __restrict__ invc,
    const int2* __restrict__ rp2, const int* __restrict__ col2,
    const unsigned short* __restrict__ Wp, const float* __restrict__ bl,
    float* __restrict__ out, const int* __restrict__ act)
{
    __shared__ unsigned short Ahi[32 * 128];
    __shared__ unsigned short Alo[32 * 128];
    int tid = threadIdx.x;
    int graph, tile;
    map_block<true>(blockIdx.x, graph, tile);
    int n0 = graph * NPGC + tile * 32;
    int cb = graph * K1 + tile * 32;
    const int* actb = act + cb;
    int lane = tid & 63, w = tid >> 6;
    int lrow = lane & 15, quad = lane >> 4;
    f32x4 acc[2][2] = {};

    sage_body<true, true, 0>(h, ts, invc, nullptr, rp2, col2, Wp, Ahi, Alo, n0, cb, actb, tid, acc);

#pragma unroll
    for (int c = 0; c < 2; ++c) {
        int colg = (2 * w + c) * 16 + lrow;
        float bias = bl[colg];
#pragma unroll
        for (int st = 0; st < 2; ++st) {
#pragma unroll
            for (int rr = 0; rr < 4; ++rr) {
                int node = actb[st * 16 + quad * 4 + rr];
                out[(size_t)node * HID + colg] = fmaxf(acc[st][c][rr] + bias, 0.f);
            }
        }
    }
}

// ---------- layers 2 & 4: SAGE + pool dots ----------
template<bool COMPACT>
__global__ void __launch_bounds__(256, 8) k_sage_dots(
    const float* __restrict__ h,
    const float* __restrict__ invc,
    const int* __restrict__ rp, const int2* __restrict__ rp2,
    const int* __restrict__ col,
    const unsigned short* __restrict__ Wp, const float* __restrict__ bl,
    float* __restrict__ out,
    const float* __restrict__ Prel, const float* __restrict__ Proot,
    float* __restrict__ q, float* __restrict__ r, const int* __restrict__ act)
{
    __shared__ unsigned short Ahi[32 * 128];
    __shared__ unsigned short Alo[32 * 128];
    int tid = threadIdx.x;
    int graph, tile;
    map_block<COMPACT>(blockIdx.x, graph, tile);
    int n0 = graph * NPGC + tile * 32;
    int cb = COMPACT ? (graph * K1 + tile * 32) : 0;
    const int* actb = COMPACT ? (act + cb) : nullptr;
    int lane = tid & 63, w = tid >> 6;
    int lrow = lane & 15, quad = lane >> 4;
    f32x4 acc[2][2] = {};

    // layer 4 (COMPACT): filtered CSR => all sources active => no ts needed
    sage_body<false, COMPACT, 0>(h, nullptr, invc, rp, rp2, col, Wp, Ahi, Alo, n0, cb, actb, tid, acc);

    float qp[2][4] = {}, rp_[2][4] = {};
#pragma unroll
    for (int c = 0; c < 2; ++c) {
        int colg = (2 * w + c) * 16 + lrow;
        float bias = bl[colg];
        float pq = Prel[colg], pr = Proot[colg];
#pragma unroll
        for (int st = 0; st < 2; ++st) {
#pragma unroll
            for (int rr = 0; rr < 4; ++rr) {
                int nl = st * 16 + quad * 4 + rr;
                int node = COMPACT ? actb[nl] : n0 + nl;
                float val = fmaxf(acc[st][c][rr] + bias, 0.f);
                out[(size_t)node * HID + colg] = val;
                qp[st][rr] += val * pq;
                rp_[st][rr] += val * pr;
            }
        }
    }
#pragma unroll
    for (int st = 0; st < 2; ++st)
#pragma unroll
        for (int rr = 0; rr < 4; ++rr) {
#pragma unroll
            for (int m = 1; m < 16; m <<= 1) {
                qp[st][rr]  += __shfl_xor(qp[st][rr],  m, 64);
                rp_[st][rr] += __shfl_xor(rp_[st][rr], m, 64);
            }
        }
    __syncthreads();
    float* qa = (float*)Ahi;
    if (tid < 64) qa[tid] = 0.f;
    __syncthreads();
    if (lrow == 0) {
#pragma unroll
        for (int st = 0; st < 2; ++st)
#pragma unroll
            for (int rr = 0; rr < 4; ++rr) {
                int nl = st * 16 + quad * 4 + rr;
                atomicAdd(&qa[nl], qp[st][rr]);
                atomicAdd(&qa[32 + nl], rp_[st][rr]);
            }
    }
    __syncthreads();
    if (tid < 32) {
        int node = COMPACT ? actb[tid] : n0 + tid;
        q[node] = qa[tid];
        r[node] = qa[32 + tid];
    }
}

// ---------- score = segsum(q[src]) + r + prb (full, pool 1) ----------
__global__ void k_score(const float* __restrict__ q, const float* __restrict__ r,
                        const float* __restrict__ prb,
                        const int* __restrict__ rp, const int* __restrict__ col,
                        float* __restrict__ score) {
    int n = blockIdx.x * 256 + threadIdx.x;
    int beg = rp[n], end = rp[n + 1];
    float s = 0.f;
    for (int e = beg; e < end; ++e) s += q[col[e]];
    score[n] = s + r[n] + prb[0];
}

// ---------- score over active nodes via filtered CSR (pool 2) ----------
__global__ void k_score2(const float* __restrict__ q, const float* __restrict__ r,
                         const float* __restrict__ prb,
                         const int2* __restrict__ rp2, const int* __restrict__ col2,
                         float* __restrict__ score, const int* __restrict__ act) {
    int i = blockIdx.x * 256 + threadIdx.x;
    int n = act[i];
    int2 be = rp2[i];
    float s = 0.f;
    for (int e = be.x; e < be.y; ++e) s += q[col2[e]];
    score[n] = s + r[n] + prb[0];
}

// ---------- per-graph top-k via radix select; emits compact active list ----------
template<bool NMIN>
__global__ void __launch_bounds__(256) k_topk(const float* __restrict__ score,
                                              float* __restrict__ nm,
                                              float* __restrict__ tval, int k,
                                              int* __restrict__ act) {
    __shared__ unsigned int u[NPGC];
    __shared__ int hist[256];
    __shared__ int scanb[257];
    __shared__ int wtot[4];
    __shared__ int wtot2[4];
    __shared__ unsigned int s_byte;
    __shared__ int s_kk;
    int tid = threadIdx.x;
    int lane = tid & 63, wv = tid >> 6;
    int base = blockIdx.x * NPGC;

    for (int j = tid; j < NPGC; j += 256) {
        float sc = NMIN ? ((nm[base + j] > 0.f) ? score[base + j] : -1e30f) : score[base + j];
        unsigned int v = __float_as_uint(sc);
        v = (v & 0x80000000u) ? ~v : (v | 0x80000000u);
        u[j] = v;
    }
    hist[tid] = 0;
    if (tid == 0) scanb[256] = 0;
    __syncthreads();

    unsigned int prefix = 0;
    int kk = k;
#pragma unroll
    for (int round = 0; round < 4; ++round) {
        int shift = 24 - 8 * round;
        unsigned int pmask = (round == 0) ? 0u : (0xFFFFFFFFu << (32 - 8 * round));
        for (int j = tid; j < NPGC; j += 256) {
            unsigned int v = u[j];
            if ((v & pmask) == prefix) atomicAdd(&hist[(v >> shift) & 0xFF], 1);
        }
        __syncthreads();
        int s = hist[tid];
#pragma unroll
        for (int off = 1; off < 64; off <<= 1) {
            int t = __shfl_down(s, off, 64);
            s += (lane + off < 64) ? t : 0;
        }
        if (lane == 0) wtot[wv] = s;
        __syncthreads();
        int add = 0;
#pragma unroll
        for (int w2 = 1; w2 < 4; ++w2) add += (wv + w2 < 4) ? wtot[wv + w2] : 0;
        s += add;
        scanb[tid] = s;
        __syncthreads();
        int above = scanb[tid + 1];
        if (s >= kk && above < kk) { s_byte = (unsigned int)tid; s_kk = kk - above; }
        hist[tid] = 0;
        __syncthreads();
        prefix |= (s_byte << shift);
        kk = s_kk;
    }
    unsigned int thr = prefix;

    int j0 = tid * 8;
    int cnt = 0;
#pragma unroll
    for (int j = 0; j < 8; ++j) cnt += (u[j0 + j] == thr);
    int s = cnt;
#pragma unroll
    for (int off = 1; off < 64; off <<= 1) {
        int t = __shfl_up(s, off, 64);
        s += (lane >= off) ? t : 0;
    }
    if (lane == 63) wtot[wv] = s;
    __syncthreads();
    int add = 0;
#pragma unroll
    for (int w2 = 0; w2 < 4; ++w2) add += (w2 < wv) ? wtot[w2] : 0;
    int rank = s - cnt + add;

    // keep flags (exact k kept per graph by construction of the select)
    unsigned int keepmask = 0u;
    int myrank = rank;
    int kcnt = 0;
#pragma unroll
    for (int j = 0; j < 8; ++j) {
        unsigned int v = u[j0 + j];
        bool kp;
        if (v > thr) kp = true;
        else if (v == thr) { kp = (myrank < kk); myrank++; }
        else kp = false;
        keepmask |= (kp ? 1u : 0u) << j;
        kcnt += kp ? 1 : 0;
    }
    // block-wide exclusive scan of keep counts -> compact write position
    int s2 = kcnt;
#pragma unroll
    for (int off = 1; off < 64; off <<= 1) {
        int t2 = __shfl_up(s2, off, 64);
        s2 += (lane >= off) ? t2 : 0;
    }
    if (lane == 63) wtot2[wv] = s2;
    __syncthreads();
    int pos = s2 - kcnt;
#pragma unroll
    for (int w2 = 0; w2 < 4; ++w2) pos += (w2 < wv) ? wtot2[w2] : 0;
    int* actg = act + blockIdx.x * k;
#pragma unroll
    for (int j = 0; j < 8; ++j) {
        bool kp = (keepmask >> j) & 1u;
        int n = base + j0 + j;
        nm[n]   = kp ? 1.0f : 0.0f;
        tval[n] = kp ? tanhf(score[n]) : 0.0f;
        if (kp) actg[pos++] = n;
    }
}

// ---------- readout + MLP head + log_softmax, one block per graph ----------
__global__ void k_tail(const float* __restrict__ h, const float* __restrict__ t,
                       const int* __restrict__ act,
                       const float* __restrict__ W5, const float* __restrict__ b5,
                       const float* __restrict__ W6, const float* __restrict__ b6,
                       void* __restrict__ out, const int* __restrict__ flag) {
    __shared__ float gsh[2][HID];
    __shared__ float g5[64];
    __shared__ float ls[2];
    int graph = blockIdx.x, tid = threadIdx.x;
    int f = tid & 127, sub = tid >> 7;
    const int* actg = act + graph * K2;
    float acc = 0.f;
#pragma unroll 8
    for (int i = 0; i < 256; ++i) {
        int gn = actg[sub * 256 + i];
        acc += h[(size_t)gn * HID + f] * t[gn];
    }
    gsh[sub][f] = acc;
    __syncthreads();
    if (tid < 64) {
        const float ic = 1.0f / (float)K2;
        float a5 = b5[tid];
        for (int ff = 0; ff < HID; ++ff)
            a5 += (gsh[0][ff] + gsh[1][ff]) * ic * W5[ff * 64 + tid];
        g5[tid] = fmaxf(a5, 0.f);
    }
    __syncthreads();
    if (tid < 2) {
        float l = b6[tid];
        for (int tt = 0; tt < 64; ++tt) l += g5[tt] * W6[tt * 2 + tid];
        ls[tid] = l;
    }
    __syncthreads();
    if (tid == 0) {
        float a = ls[0], b = ls[1];
        float mx = fmaxf(a, b);
        float lse = mx + logf(expf(a - mx) + expf(b - mx));
        if (*flag) {
            ((unsigned short*)out)[graph * 2 + 0] = f2bf(a - lse);
            ((unsigned short*)out)[graph * 2 + 1] = f2bf(b - lse);
        } else {
            ((float*)out)[graph * 2 + 0] = a - lse;
            ((float*)out)[graph * 2 + 1] = b - lse;
        }
    }
}

extern "C" void kernel_launch(void* const* d_in, const int* in_sizes, int n_in,
                              void* d_out, int out_size, void* d_ws, size_t ws_size,
                              hipStream_t stream) {
    const void* x    = d_in[0];
    const int*  ei   = (const int*)d_in[1];
    const int*  srcE = ei;
    const int*  dstE = ei + NE;

    char* ws = (char*)d_ws;
    float* hA    = (float*)(ws + 0);
    float* hB    = (float*)(ws + 33554432);
    float* tvec  = (float*)(ws + 67108864);
    float* invc  = (float*)(ws + 67371008);
    int*   col2  = (int*)  (ws + 67633152);   // 2 MB (per-graph arenas of EPG)
    int2*  rp2   = (int2*) (ws + 69730304);   // 256 KB
    int*   ghead = (int*)  (ws + 69992448);   // 128 B
    float* q     = (float*)(ws + 100663296);
    float* r     = (float*)(ws + 100925440);
    float* score = (float*)(ws + 101187584);
    float* nm    = (float*)(ws + 101449728);
    int*   rowc  = (int*)  (ws + 101711872);  // reused as act1 (32768 ints) after scan1
    int*   rp    = (int*)  (ws + 101974016);
    int*   bsum  = (int*)  (ws + 102236416);
    int*   fill  = (int*)  (ws + 102238464);  // reused as act2 (16384 ints) after scatter
    int*   col   = (int*)  (ws + 102500608);
    int*   flag  = (int*)  (ws + 104615936);
    float* wts   = (float*)(ws + 104616960);
    unsigned short* Wpack = (unsigned short*)(ws + 105179136);
    int*   act1  = rowc;
    int*   act2  = fill;
    (void)in_sizes; (void)n_in; (void)out_size; (void)ws_size;

    const int O_Wl1 = 0,      O_bl1 = 16384,  O_Wr1 = 16512;
    const int O_Wl2 = 32896,  O_bl2 = 49280,  O_Wr2 = 49408;
    const int O_Wl3 = 65792,  O_bl3 = 82176,  O_Wr3 = 82304;
    const int O_Wl4 = 98688,  O_bl4 = 115072, O_Wr4 = 115200;
    const int O_Pr1 = 131584, O_pb1 = 131712, O_Po1 = 131713;
    const int O_Pr2 = 131841, O_pb2 = 131969, O_Po2 = 131970;
    const int O_W5  = 132098, O_b5  = 140290, O_W6 = 140354, O_b6 = 140482;

    CvtDesc d;
    const int srcIdx[22] = {4,5,6,7,8,9,10,11,12,13,14,15,16,17,18,19,20,21,22,23,24,25};
    const int nelems[22] = {16384,128,16384, 16384,128,16384, 16384,128,16384, 16384,128,16384,
                            128,1,128, 128,1,128, 8192,64,128,2};
    const int offs[22]   = {O_Wl1,O_bl1,O_Wr1, O_Wl2,O_bl2,O_Wr2, O_Wl3,O_bl3,O_Wr3, O_Wl4,O_bl4,O_Wr4,
                            O_Pr1,O_pb1,O_Po1, O_Pr2,O_pb2,O_Po2, O_W5,O_b5,O_W6,O_b6};
    for (int i = 0; i < 22; ++i) { d.src[i] = d_in[srcIdx[i]]; d.n[i] = nelems[i]; d.off[i] = offs[i]; }

    hipMemsetAsync(ghead, 0, NG * 4, stream);

    k_detect <<<1, 256, 0, stream>>>((const unsigned short*)x, flag);
    k_cvt    <<<dim3(64, 22), 256, 0, stream>>>(d, wts, flag);
    k_packW  <<<512, 256, 0, stream>>>(wts, make_int4(O_Wl1, O_Wl2, O_Wl3, O_Wl4),
                                       make_int4(O_Wr1, O_Wr2, O_Wr3, O_Wr4), Wpack, rowc, fill);
    k_hist   <<<2048, 256, 0, stream>>>(dstE, rowc);

    k_scan1  <<<256, 256, 0, stream>>>(rowc, rp, bsum, invc);
    k_scan23 <<<256, 256, 0, stream>>>(rp, bsum);
    k_scatter<<<2048, 256, 0, stream>>>(srcE, dstE, rp, fill, col);

    // layer 1: x -> hB (reads x directly, bf16 or f32)
    k_sage_l1<<<2048, 256, 0, stream>>>(x, flag, invc, rp, col,
                                        Wpack + 0 * 65536, wts + O_bl1, hB);
    // layer 2: hB -> hA  (+ fused pool-1 dots)
    k_sage_dots<false><<<2048, 256, 0, stream>>>(hB, invc, rp, nullptr, col,
                                                 Wpack + 1 * 65536, wts + O_bl2, hA,
                                                 wts + O_Pr1, wts + O_Po1, q, r, nullptr);

    // pool 1 (k = 1024): topk emits act1; parallel filtered-CSR build + invc
    k_score<<<256, 256, 0, stream>>>(q, r, wts + O_pb1, rp, col, score);
    k_topk<false><<<32, 256, 0, stream>>>(score, nm, tvec, K1, act1);
    k_fbuild<<<NG * K1 / 256, 256, 0, stream>>>(act1, nm, rp, col, rp2, col2, invc, ghead);

    // layer 3 (compact, filtered CSR): hA (scaled by tvec) -> hB
    k_sage_plain<<<1024, 256, 0, stream>>>(hA, tvec, invc, rp2, col2,
                                           Wpack + 2 * 65536, wts + O_bl3, hB, act1);
    // layer 4 (compact, filtered CSR => no ts needed): hB -> hA (+ pool-2 dots)
    k_sage_dots<true><<<1024, 256, 0, stream>>>(hB, invc, nullptr, rp2, col2,
                                                Wpack + 3 * 65536, wts + O_bl4, hA,
                                                wts + O_Pr2, wts + O_Po2, q, r, act1);

    // pool 2 (k = 512): score over filtered CSR; emits act2
    k_score2<<<NG * K1 / 256, 256, 0, stream>>>(q, r, wts + O_pb2, rp2, col2, score, act1);
    k_topk<true><<<32, 256, 0, stream>>>(score, nm, tvec, K2, act2);

    // readout + MLP head (one block per graph; count == K2 folded in)
    k_tail<<<32, 256, 0, stream>>>(hA, tvec, act2, wts + O_W5, wts + O_b5,
                                   wts + O_W6, wts + O_b6, d_out, flag);
}

// Round 11
// 370.831 us; speedup vs baseline: 1.1090x; 1.0143x over previous
//
#include <hip/hip_runtime.h>
#include <hip/hip_bf16.h>
#include <math.h>

#define NT   65536      // total nodes (32 graphs * 2048)
#define NPGC 2048       // nodes per graph
#define NG   32         // graphs
#define NE   524288     // edges
#define EPG  16384      // edges per graph (col2 arena stride)
#define HID  128
#define K1   1024       // pool-1 keep per graph
#define K2   512        // pool-2 keep per graph

typedef short short8 __attribute__((ext_vector_type(8)));
typedef float f32x4  __attribute__((ext_vector_type(4)));

__device__ __forceinline__ float bf2f(unsigned short u) {
    union { unsigned int i; float f; } v; v.i = ((unsigned int)u) << 16; return v.f;
}
__device__ __forceinline__ unsigned short f2bf(float f) {   // round-to-nearest (packW only)
    union { float f; unsigned int i; } v; v.f = f;
    unsigned int x = v.i;
    return (unsigned short)((x + 0x7fffu + ((x >> 16) & 1u)) >> 16);
}
// fast truncation split: v ~ hi + lo, |err| <= 2^-16 |v| (4 ops)
__device__ __forceinline__ void split2(float v, unsigned short& hi, unsigned short& lo) {
    unsigned int b = __float_as_uint(v);
    hi = (unsigned short)(b >> 16);
    float rem = v - __uint_as_float(b & 0xFFFF0000u);
    lo = (unsigned short)(__float_as_uint(rem) >> 16);
}

// ---------- dtype detection: bf16 vs fp32 ----------
__global__ void k_detect(const unsigned short* __restrict__ x, int* __restrict__ flag) {
    __shared__ int cnt;
    if (threadIdx.x == 0) cnt = 0;
    __syncthreads();
    int sane = 0;
#pragma unroll
    for (int j = 0; j < 16; ++j) {
        unsigned short u = x[threadIdx.x * 16 + j];
        int e = (u >> 7) & 0xFF;
        if (e > 0x60 && e < 0xA0) sane++;
    }
    atomicAdd(&cnt, sane);
    __syncthreads();
    if (threadIdx.x == 0) *flag = (cnt > 3686) ? 1 : 0;
}

// ---------- weight conversion: (bf16|f32) -> f32 scratch ----------
struct CvtDesc { const void* src[22]; int n[22]; int off[22]; };

__global__ void k_cvt(CvtDesc d, float* __restrict__ wts, const int* __restrict__ flag) {
    int t = blockIdx.y;
    int n = d.n[t];
    bool isbf = (*flag != 0);
    const unsigned short* sb = (const unsigned short*)d.src[t];
    const float* sf = (const float*)d.src[t];
    float* o = wts + d.off[t];
    for (int i = blockIdx.x * blockDim.x + threadIdx.x; i < n; i += gridDim.x * blockDim.x)
        o[i] = isbf ? bf2f(sb[i]) : sf[i];
}

// ---------- pack SAGE weights (+ zero rowc/fill for the CSR build) ----------
__global__ void k_packW(const float* __restrict__ wts, int4 oWl, int4 oWr,
                        unsigned short* __restrict__ Wpack,
                        int* __restrict__ rowc, int* __restrict__ fill) {
    int idx = blockIdx.x * 256 + threadIdx.x;
    if (idx < NT) { rowc[idx] = 0; fill[idx] = 0; }
    if (idx >= 4 * 8 * 8 * 64 * 8) return;
    int L    = idx >> 15;
    int rem  = idx & 32767;
    int ct   = rem >> 12;
    int rem2 = rem & 4095;
    int ks   = rem2 >> 9;
    int rem3 = rem2 & 511;
    int lane = rem3 >> 3;
    int j    = rem3 & 7;
    int k   = ks * 32 + (lane >> 4) * 8 + j;
    int col = ct * 16 + (lane & 15);
    int ol = (L == 0) ? oWl.x : (L == 1) ? oWl.y : (L == 2) ? oWl.z : oWl.w;
    int orr = (L == 0) ? oWr.x : (L == 1) ? oWr.y : (L == 2) ? oWr.z : oWr.w;
    float w = (k < 128) ? wts[ol + k * 128 + col] : wts[orr + (k - 128) * 128 + col];
    unsigned short hi = f2bf(w);
    unsigned short lo = f2bf(w - bf2f(hi));
    int base = L * 65536 + (ct * 8 + ks) * 512 + lane * 8 + j;
    Wpack[base]         = hi;
    Wpack[base + 32768] = lo;
}

// ---------- edge histogram only (x is consumed in-place by layer 1) ----------
__global__ void k_hist(const int* __restrict__ dstE, int* __restrict__ rowc) {
    int e = blockIdx.x * 256 + threadIdx.x;
    if (e < NE) atomicAdd(&rowc[dstE[e]], 1);
}

// scan1 also emits initial invc (pre-pool: invc = 1/max(deg,1))
__global__ void k_scan1(const int* __restrict__ cnt, int* __restrict__ rp, int* __restrict__ bsum,
                        float* __restrict__ invc) {
    __shared__ int s[256];
    int t = threadIdx.x;
    int i = blockIdx.x * 256 + t;
    int v = cnt[i];
    invc[i] = 1.0f / fmaxf((float)v, 1.0f);
    s[t] = v;
    __syncthreads();
    for (int off = 1; off < 256; off <<= 1) {
        int a = (t >= off) ? s[t - off] : 0;
        __syncthreads();
        s[t] += a;
        __syncthreads();
    }
    rp[i] = s[t] - v;
    if (t == 255) bsum[blockIdx.x] = s[255];
}

// merged scan2+scan3
__global__ void k_scan23(int* __restrict__ rp, const int* __restrict__ bsum) {
    __shared__ int s[256];
    int t = threadIdx.x;
    s[t] = bsum[t];
    __syncthreads();
    for (int off = 1; off < 256; off <<= 1) {
        int a = (t >= off) ? s[t - off] : 0;
        __syncthreads();
        s[t] += a;
        __syncthreads();
    }
    int boffv = s[blockIdx.x] - bsum[blockIdx.x];
    int i = blockIdx.x * 256 + t;
    rp[i] += boffv;
    if (i == 0) rp[NT] = NE;
}

__global__ void k_scatter(const int* __restrict__ src, const int* __restrict__ dst,
                          const int* __restrict__ rp, int* __restrict__ fill, int* __restrict__ col) {
    int e = blockIdx.x * blockDim.x + threadIdx.x;
    if (e < NE) {
        int d = dst[e];
        int p = rp[d] + atomicAdd(&fill[d], 1);
        col[p] = src[e];
    }
}

// ---------- filtered CSR build: 1 thread/active node, block scan, ONE atomic per block ----------
__global__ void __launch_bounds__(256) k_fbuild(const int* __restrict__ act,
                                                const float* __restrict__ nm,
                                                const int* __restrict__ rp,
                                                const int* __restrict__ col,
                                                int2* __restrict__ rp2,
                                                int* __restrict__ col2,
                                                float* __restrict__ invc,
                                                int* __restrict__ ghead) {
    __shared__ int wtot[4];
    __shared__ int s_base;
    int tid = threadIdx.x;
    int lane = tid & 63, wv = tid >> 6;
    int i = blockIdx.x * 256 + tid;           // 0..NG*K1-1
    int g = i >> 10;                          // constant within block
    int n = act[i];
    int bg = rp[n], en = rp[n + 1];
    int cc = 0;
    for (int e = bg; e < en; ++e) cc += (nm[col[e]] > 0.f) ? 1 : 0;
    invc[n] = 1.0f / fmaxf((float)cc, 1.0f);

    // block-wide exclusive scan of cc
    int pre = cc;
#pragma unroll
    for (int off = 1; off < 64; off <<= 1) {
        int v = __shfl_up(pre, off, 64);
        pre += (lane >= off) ? v : 0;
    }
    if (lane == 63) wtot[wv] = pre;
    __syncthreads();
    int woff = 0;
#pragma unroll
    for (int w2 = 0; w2 < 4; ++w2) woff += (w2 < wv) ? wtot[w2] : 0;
    int ex = pre - cc + woff;
    if (tid == 0) s_base = atomicAdd(&ghead[g], wtot[0] + wtot[1] + wtot[2] + wtot[3]);
    __syncthreads();

    int p = g * EPG + s_base + ex;
    rp2[i] = make_int2(p, p + cc);
    for (int e = bg; e < en; ++e) {
        int s = col[e];
        if (nm[s] > 0.f) col2[p++] = s;
    }
}

// ---------- LDS swizzle ----------
__device__ __forceinline__ int lds_sw(int node, int k) {
    int g = k >> 3;
    int go = g ^ (node & 7);
    return node * 128 + go * 8 + (k & 7);
}

// ---------- dtype-generic row chunk load (4 feats) ----------
template<int MODE>
__device__ __forceinline__ float4 ldrow4(const void* __restrict__ h, int node, int f) {
    if constexpr (MODE == 1) {
        ushort4 v = *((const ushort4*)h + (size_t)node * 32 + (f >> 2));
        float4 o; o.x = bf2f(v.x); o.y = bf2f(v.y); o.z = bf2f(v.z); o.w = bf2f(v.w);
        return o;
    } else {
        return *((const float4*)h + (size_t)node * 32 + (f >> 2));
    }
}

// ---------- shared body: two-phase (16 KB LDS), 8-wide gather, CSR prefetched (R7 form) ----------
template<bool HAS_TS, bool COMPACT, int MODE>
__device__ __forceinline__ void sage_body(
    const void* __restrict__ h, const float* __restrict__ ts,
    const float* __restrict__ invc,
    const int* __restrict__ rp, const int2* __restrict__ rp2,
    const int* __restrict__ col,
    const unsigned short* __restrict__ Wp,
    unsigned short* Ahi, unsigned short* Alo,
    int n0, int cb, const int* __restrict__ actb, int tid, f32x4 acc[2][2])
{
    int lane = tid & 63, w = tid >> 6;
    int lrow = lane & 15, quad = lane >> 4;
    int gnode = tid >> 5;          // 0..7 (32 threads per node)
    int f = (tid & 31) * 4;

    // ---- CSR prefetch for this thread's 4 gather nodes ----
    int gns[4], begs[4], ends[4]; float invs[4];
#pragma unroll
    for (int p = 0; p < 4; ++p) gns[p] = COMPACT ? actb[p * 8 + gnode] : n0 + p * 8 + gnode;
#pragma unroll
    for (int p = 0; p < 4; ++p) {
        if (COMPACT) { int2 be = rp2[cb + p * 8 + gnode]; begs[p] = be.x; ends[p] = be.y; }
        else         { begs[p] = rp[gns[p]]; ends[p] = rp[gns[p] + 1]; }
    }
#pragma unroll
    for (int p = 0; p < 4; ++p) invs[p] = invc[gns[p]];

    // ---- phase A: gather mean rows, 8 edges in flight ----
#pragma unroll
    for (int pass = 0; pass < 4; ++pass) {
        int node = pass * 8 + gnode;
        float ax = 0.f, ay = 0.f, az = 0.f, aw = 0.f;
        int beg = begs[pass], end = ends[pass];
        int ecl = end - 1;
        for (int e0 = beg; e0 < end; e0 += 8) {
            int sj[8];
#pragma unroll
            for (int j = 0; j < 8; ++j) {
                int e = (e0 + j < end) ? e0 + j : ecl;
                sj[j] = col[e];
            }
            float4 vj[8];
#pragma unroll
            for (int j = 0; j < 8; ++j)
                vj[j] = ldrow4<MODE>(h, sj[j], f);
#pragma unroll
            for (int j = 0; j < 8; ++j) {
                float cj = (e0 + j < end) ? (HAS_TS ? ts[sj[j]] : 1.0f) : 0.0f;
                ax += vj[j].x * cj;
                ay += vj[j].y * cj;
                az += vj[j].z * cj;
                aw += vj[j].w * cj;
            }
        }
        float inv = invs[pass];
        ushort4 hi4, lo4;
        split2(ax * inv, hi4.x, lo4.x);
        split2(ay * inv, hi4.y, lo4.y);
        split2(az * inv, hi4.z, lo4.z);
        split2(aw * inv, hi4.w, lo4.w);
        int a = lds_sw(node, f);
        *(ushort4*)&Ahi[a] = hi4;
        *(ushort4*)&Alo[a] = lo4;
    }
    __syncthreads();

    // ---- MFMA over Wl half (ks 0..3, from A) ----
#pragma unroll
    for (int ks = 0; ks < 4; ++ks) {
        short8 bh[2], blo[2];
#pragma unroll
        for (int c = 0; c < 2; ++c) {
            int ct = 2 * w + c;
            bh[c]  = *(const short8*)&Wp[(ct * 8 + ks) * 512 + lane * 8];
            blo[c] = *(const short8*)&Wp[32768 + (ct * 8 + ks) * 512 + lane * 8];
        }
        int kb = ks * 32 + quad * 8;
#pragma unroll
        for (int st = 0; st < 2; ++st) {
            int a = lds_sw(st * 16 + lrow, kb);
            short8 ah = *(const short8*)&Ahi[a];
            short8 al = *(const short8*)&Alo[a];
#pragma unroll
            for (int c = 0; c < 2; ++c) {
                acc[st][c] = __builtin_amdgcn_mfma_f32_16x16x32_bf16(ah, bh[c],  acc[st][c], 0, 0, 0);
                acc[st][c] = __builtin_amdgcn_mfma_f32_16x16x32_bf16(al, bh[c],  acc[st][c], 0, 0, 0);
                acc[st][c] = __builtin_amdgcn_mfma_f32_16x16x32_bf16(ah, blo[c], acc[st][c], 0, 0, 0);
            }
        }
    }
    __syncthreads();

    // ---- phase B: stage root rows into the SAME buffer (coalesced) ----
#pragma unroll
    for (int i = 0; i < 4; ++i) {
        int idx = i * 256 + tid;
        int node = idx >> 5;
        int f2 = (idx & 31) * 4;
        int gn = COMPACT ? actb[node] : n0 + node;
        float4 v = ldrow4<MODE>(h, gn, f2);
        float sc = HAS_TS ? ts[gn] : 1.0f;
        ushort4 hi4, lo4;
        split2(v.x * sc, hi4.x, lo4.x);
        split2(v.y * sc, hi4.y, lo4.y);
        split2(v.z * sc, hi4.z, lo4.z);
        split2(v.w * sc, hi4.w, lo4.w);
        int a = lds_sw(node, f2);
        *(ushort4*)&Ahi[a] = hi4;
        *(ushort4*)&Alo[a] = lo4;
    }
    __syncthreads();

    // ---- MFMA over Wr half (ks 4..7, from A again) ----
#pragma unroll
    for (int ks = 4; ks < 8; ++ks) {
        short8 bh[2], blo[2];
#pragma unroll
        for (int c = 0; c < 2; ++c) {
            int ct = 2 * w + c;
            bh[c]  = *(const short8*)&Wp[(ct * 8 + ks) * 512 + lane * 8];
            blo[c] = *(const short8*)&Wp[32768 + (ct * 8 + ks) * 512 + lane * 8];
        }
        int kb = (ks - 4) * 32 + quad * 8;
#pragma unroll
        for (int st = 0; st < 2; ++st) {
            int a = lds_sw(st * 16 + lrow, kb);
            short8 ah = *(const short8*)&Ahi[a];
            short8 al = *(const short8*)&Alo[a];
#pragma unroll
            for (int c = 0; c < 2; ++c) {
                acc[st][c] = __builtin_amdgcn_mfma_f32_16x16x32_bf16(ah, bh[c],  acc[st][c], 0, 0, 0);
                acc[st][c] = __builtin_amdgcn_mfma_f32_16x16x32_bf16(al, bh[c],  acc[st][c], 0, 0, 0);
                acc[st][c] = __builtin_amdgcn_mfma_f32_16x16x32_bf16(ah, blo[c], acc[st][c], 0, 0, 0);
            }
        }
    }
}

// ---------- block -> (graph, tile) with XCD-affinity swizzle ----------
template<bool COMPACT>
__device__ __forceinline__ void map_block(int b, int& graph, int& tile) {
    if (COMPACT) { graph = (b & 7) * 4 + (b >> 8); tile = (b >> 3) & 31; }   // 1024 blocks
    else         { graph = (b & 7) * 4 + (b >> 9); tile = (b >> 3) & 63; }   // 2048 blocks
}

// ---------- layer 1: reads x directly (bf16 or f32) ----------
__global__ void __launch_bounds__(256, 7) k_sage_l1(
    const void* __restrict__ x, const int* __restrict__ flag,
    const float* __restrict__ invc,
    const int* __restrict__ rp, const int* __restrict__ col,
    const unsigned short* __restrict__ Wp, const float* __restrict__ bl,
    float* __restrict__ out)
{
    __shared__ unsigned short Ahi[32 * 128];
    __shared__ unsigned short Alo[32 * 128];
    int tid = threadIdx.x;
    int graph, tile;
    map_block<false>(blockIdx.x, graph, tile);
    int n0 = graph * NPGC + tile * 32;
    int lane = tid & 63, w = tid >> 6;
    int lrow = lane & 15, quad = lane >> 4;
    f32x4 acc[2][2] = {};

    if (*flag)
        sage_body<false, false, 1>(x, nullptr, invc, rp, nullptr, col, Wp, Ahi, Alo, n0, 0, nullptr, tid, acc);
    else
        sage_body<false, false, 0>(x, nullptr, invc, rp, nullptr, col, Wp, Ahi, Alo, n0, 0, nullptr, tid, acc);

#pragma unroll
    for (int c = 0; c < 2; ++c) {
        int colg = (2 * w + c) * 16 + lrow;
        float bias = bl[colg];
#pragma unroll
        for (int st = 0; st < 2; ++st) {
#pragma unroll
            for (int rr = 0; rr < 4; ++rr) {
                int node = n0 + st * 16 + quad * 4 + rr;
                out[(size_t)node * HID + colg] = fmaxf(acc[st][c][rr] + bias, 0.f);
            }
        }
    }
}

// ---------- layer 3: compact plain (filtered CSR) ----------
__global__ void __launch_bounds__(256, 7) k_sage_plain(
    const float* __restrict__ h, const float* __restrict__ ts,
    const float* __restrict__ invc,
    const int2* __restrict__ rp2, const int* __restrict__ col2,
    const unsigned short* __restrict__ Wp, const float* __restrict__ bl,
    float* __restrict__ out, const int* __restrict__ act)
{
    __shared__ unsigned short Ahi[32 * 128];
    __shared__ unsigned short Alo[32 * 128];
    int tid = threadIdx.x;
    int graph, tile;
    map_block<true>(blockIdx.x, graph, tile);
    int n0 = graph * NPGC + tile * 32;
    int cb = graph * K1 + tile * 32;
    const int* actb = act + cb;
    int lane = tid & 63, w = tid >> 6;
    int lrow = lane & 15, quad = lane >> 4;
    f32x4 acc[2][2] = {};

    sage_body<true, true, 0>(h, ts, invc, nullptr, rp2, col2, Wp, Ahi, Alo, n0, cb, actb, tid, acc);

#pragma unroll
    for (int c = 0; c < 2; ++c) {
        int colg = (2 * w + c) * 16 + lrow;
        float bias = bl[colg];
#pragma unroll
        for (int st = 0; st < 2; ++st) {
#pragma unroll
            for (int rr = 0; rr < 4; ++rr) {
                int node = actb[st * 16 + quad * 4 + rr];
                out[(size_t)node * HID + colg] = fmaxf(acc[st][c][rr] + bias, 0.f);
            }
        }
    }
}

// ---------- layers 2 & 4: SAGE + pool dots ----------
template<bool COMPACT>
__global__ void __launch_bounds__(256, 7) k_sage_dots(
    const float* __restrict__ h,
    const float* __restrict__ invc,
    const int* __restrict__ rp, const int2* __restrict__ rp2,
    const int* __restrict__ col,
    const unsigned short* __restrict__ Wp, const float* __restrict__ bl,
    float* __restrict__ out,
    const float* __restrict__ Prel, const float* __restrict__ Proot,
    float* __restrict__ q, float* __restrict__ r, const int* __restrict__ act)
{
    __shared__ unsigned short Ahi[32 * 128];
    __shared__ unsigned short Alo[32 * 128];
    int tid = threadIdx.x;
    int graph, tile;
    map_block<COMPACT>(blockIdx.x, graph, tile);
    int n0 = graph * NPGC + tile * 32;
    int cb = COMPACT ? (graph * K1 + tile * 32) : 0;
    const int* actb = COMPACT ? (act + cb) : nullptr;
    int lane = tid & 63, w = tid >> 6;
    int lrow = lane & 15, quad = lane >> 4;
    f32x4 acc[2][2] = {};

    // layer 4 (COMPACT): filtered CSR => all sources active => no ts needed
    sage_body<false, COMPACT, 0>(h, nullptr, invc, rp, rp2, col, Wp, Ahi, Alo, n0, cb, actb, tid, acc);

    float qp[2][4] = {}, rp_[2][4] = {};
#pragma unroll
    for (int c = 0; c < 2; ++c) {
        int colg = (2 * w + c) * 16 + lrow;
        float bias = bl[colg];
        float pq = Prel[colg], pr = Proot[colg];
#pragma unroll
        for (int st = 0; st < 2; ++st) {
#pragma unroll
            for (int rr = 0; rr < 4; ++rr) {
                int nl = st * 16 + quad * 4 + rr;
                int node = COMPACT ? actb[nl] : n0 + nl;
                float val = fmaxf(acc[st][c][rr] + bias, 0.f);
                out[(size_t)node * HID + colg] = val;
                qp[st][rr] += val * pq;
                rp_[st][rr] += val * pr;
            }
        }
    }
#pragma unroll
    for (int st = 0; st < 2; ++st)
#pragma unroll
        for (int rr = 0; rr < 4; ++rr) {
#pragma unroll
            for (int m = 1; m < 16; m <<= 1) {
                qp[st][rr]  += __shfl_xor(qp[st][rr],  m, 64);
                rp_[st][rr] += __shfl_xor(rp_[st][rr], m, 64);
            }
        }
    __syncthreads();
    float* qa = (float*)Ahi;
    if (tid < 64) qa[tid] = 0.f;
    __syncthreads();
    if (lrow == 0) {
#pragma unroll
        for (int st = 0; st < 2; ++st)
#pragma unroll
            for (int rr = 0; rr < 4; ++rr) {
                int nl = st * 16 + quad * 4 + rr;
                atomicAdd(&qa[nl], qp[st][rr]);
                atomicAdd(&qa[32 + nl], rp_[st][rr]);
            }
    }
    __syncthreads();
    if (tid < 32) {
        int node = COMPACT ? actb[tid] : n0 + tid;
        q[node] = qa[tid];
        r[node] = qa[32 + tid];
    }
}

// ---------- score = segsum(q[src]) + r + prb (full, pool 1) ----------
__global__ void k_score(const float* __restrict__ q, const float* __restrict__ r,
                        const float* __restrict__ prb,
                        const int* __restrict__ rp, const int* __restrict__ col,
                        float* __restrict__ score) {
    int n = blockIdx.x * 256 + threadIdx.x;
    int beg = rp[n], end = rp[n + 1];
    float s = 0.f;
    for (int e = beg; e < end; ++e) s += q[col[e]];
    score[n] = s + r[n] + prb[0];
}

// ---------- score over active nodes via filtered CSR (pool 2) ----------
__global__ void k_score2(const float* __restrict__ q, const float* __restrict__ r,
                         const float* __restrict__ prb,
                         const int2* __restrict__ rp2, const int* __restrict__ col2,
                         float* __restrict__ score, const int* __restrict__ act) {
    int i = blockIdx.x * 256 + threadIdx.x;
    int n = act[i];
    int2 be = rp2[i];
    float s = 0.f;
    for (int e = be.x; e < be.y; ++e) s += q[col2[e]];
    score[n] = s + r[n] + prb[0];
}

// ---------- per-graph top-k via radix select; emits compact active list ----------
template<bool NMIN>
__global__ void __launch_bounds__(256) k_topk(const float* __restrict__ score,
                                              float* __restrict__ nm,
                                              float* __restrict__ tval, int k,
                                              int* __restrict__ act) {
    __shared__ unsigned int u[NPGC];
    __shared__ int hist[256];
    __shared__ int scanb[257];
    __shared__ int wtot[4];
    __shared__ int wtot2[4];
    __shared__ unsigned int s_byte;
    __shared__ int s_kk;
    int tid = threadIdx.x;
    int lane = tid & 63, wv = tid >> 6;
    int base = blockIdx.x * NPGC;

    for (int j = tid; j < NPGC; j += 256) {
        float sc = NMIN ? ((nm[base + j] > 0.f) ? score[base + j] : -1e30f) : score[base + j];
        unsigned int v = __float_as_uint(sc);
        v = (v & 0x80000000u) ? ~v : (v | 0x80000000u);
        u[j] = v;
    }
    hist[tid] = 0;
    if (tid == 0) scanb[256] = 0;
    __syncthreads();

    unsigned int prefix = 0;
    int kk = k;
#pragma unroll
    for (int round = 0; round < 4; ++round) {
        int shift = 24 - 8 * round;
        unsigned int pmask = (round == 0) ? 0u : (0xFFFFFFFFu << (32 - 8 * round));
        for (int j = tid; j < NPGC; j += 256) {
            unsigned int v = u[j];
            if ((v & pmask) == prefix) atomicAdd(&hist[(v >> shift) & 0xFF], 1);
        }
        __syncthreads();
        int s = hist[tid];
#pragma unroll
        for (int off = 1; off < 64; off <<= 1) {
            int t = __shfl_down(s, off, 64);
            s += (lane + off < 64) ? t : 0;
        }
        if (lane == 0) wtot[wv] = s;
        __syncthreads();
        int add = 0;
#pragma unroll
        for (int w2 = 1; w2 < 4; ++w2) add += (wv + w2 < 4) ? wtot[wv + w2] : 0;
        s += add;
        scanb[tid] = s;
        __syncthreads();
        int above = scanb[tid + 1];
        if (s >= kk && above < kk) { s_byte = (unsigned int)tid; s_kk = kk - above; }
        hist[tid] = 0;
        __syncthreads();
        prefix |= (s_byte << shift);
        kk = s_kk;
    }
    unsigned int thr = prefix;

    int j0 = tid * 8;
    int cnt = 0;
#pragma unroll
    for (int j = 0; j < 8; ++j) cnt += (u[j0 + j] == thr);
    int s = cnt;
#pragma unroll
    for (int off = 1; off < 64; off <<= 1) {
        int t = __shfl_up(s, off, 64);
        s += (lane >= off) ? t : 0;
    }
    if (lane == 63) wtot[wv] = s;
    __syncthreads();
    int add = 0;
#pragma unroll
    for (int w2 = 0; w2 < 4; ++w2) add += (w2 < wv) ? wtot[w2] : 0;
    int rank = s - cnt + add;

    // keep flags (exact k kept per graph by construction of the select)
    unsigned int keepmask = 0u;
    int myrank = rank;
    int kcnt = 0;
#pragma unroll
    for (int j = 0; j < 8; ++j) {
        unsigned int v = u[j0 + j];
        bool kp;
        if (v > thr) kp = true;
        else if (v == thr) { kp = (myrank < kk); myrank++; }
        else kp = false;
        keepmask |= (kp ? 1u : 0u) << j;
        kcnt += kp ? 1 : 0;
    }
    // block-wide exclusive scan of keep counts -> compact write position
    int s2 = kcnt;
#pragma unroll
    for (int off = 1; off < 64; off <<= 1) {
        int t2 = __shfl_up(s2, off, 64);
        s2 += (lane >= off) ? t2 : 0;
    }
    if (lane == 63) wtot2[wv] = s2;
    __syncthreads();
    int pos = s2 - kcnt;
#pragma unroll
    for (int w2 = 0; w2 < 4; ++w2) pos += (w2 < wv) ? wtot2[w2] : 0;
    int* actg = act + blockIdx.x * k;
#pragma unroll
    for (int j = 0; j < 8; ++j) {
        bool kp = (keepmask >> j) & 1u;
        int n = base + j0 + j;
        nm[n]   = kp ? 1.0f : 0.0f;
        tval[n] = kp ? tanhf(score[n]) : 0.0f;
        if (kp) actg[pos++] = n;
    }
}

// ---------- readout + MLP head + log_softmax, one block per graph ----------
__global__ void k_tail(const float* __restrict__ h, const float* __restrict__ t,
                       const int* __restrict__ act,
                       const float* __restrict__ W5, const float* __restrict__ b5,
                       const float* __restrict__ W6, const float* __restrict__ b6,
                       void* __restrict__ out, const int* __restrict__ flag) {
    __shared__ float gsh[2][HID];
    __shared__ float g5[64];
    __shared__ float ls[2];
    int graph = blockIdx.x, tid = threadIdx.x;
    int f = tid & 127, sub = tid >> 7;
    const int* actg = act + graph * K2;
    float acc = 0.f;
#pragma unroll 8
    for (int i = 0; i < 256; ++i) {
        int gn = actg[sub * 256 + i];
        acc += h[(size_t)gn * HID + f] * t[gn];
    }
    gsh[sub][f] = acc;
    __syncthreads();
    if (tid < 64) {
        const float ic = 1.0f / (float)K2;
        float a5 = b5[tid];
        for (int ff = 0; ff < HID; ++ff)
            a5 += (gsh[0][ff] + gsh[1][ff]) * ic * W5[ff * 64 + tid];
        g5[tid] = fmaxf(a5, 0.f);
    }
    __syncthreads();
    if (tid < 2) {
        float l = b6[tid];
        for (int tt = 0; tt < 64; ++tt) l += g5[tt] * W6[tt * 2 + tid];
        ls[tid] = l;
    }
    __syncthreads();
    if (tid == 0) {
        float a = ls[0], b = ls[1];
        float mx = fmaxf(a, b);
        float lse = mx + logf(expf(a - mx) + expf(b - mx));
        if (*flag) {
            ((unsigned short*)out)[graph * 2 + 0] = f2bf(a - lse);
            ((unsigned short*)out)[graph * 2 + 1] = f2bf(b - lse);
        } else {
            ((float*)out)[graph * 2 + 0] = a - lse;
            ((float*)out)[graph * 2 + 1] = b - lse;
        }
    }
}

extern "C" void kernel_launch(void* const* d_in, const int* in_sizes, int n_in,
                              void* d_out, int out_size, void* d_ws, size_t ws_size,
                              hipStream_t stream) {
    const void* x    = d_in[0];
    const int*  ei   = (const int*)d_in[1];
    const int*  srcE = ei;
    const int*  dstE = ei + NE;

    char* ws = (char*)d_ws;
    float* hA    = (float*)(ws + 0);
    float* hB    = (float*)(ws + 33554432);
    float* tvec  = (float*)(ws + 67108864);
    float* invc  = (float*)(ws + 67371008);
    int*   col2  = (int*)  (ws + 67633152);   // 2 MB (per-graph arenas of EPG)
    int2*  rp2   = (int2*) (ws + 69730304);   // 256 KB
    int*   ghead = (int*)  (ws + 69992448);   // 128 B
    float* q     = (float*)(ws + 100663296);
    float* r     = (float*)(ws + 100925440);
    float* score = (float*)(ws + 101187584);
    float* nm    = (float*)(ws + 101449728);
    int*   rowc  = (int*)  (ws + 101711872);  // reused as act1 (32768 ints) after scan1
    int*   rp    = (int*)  (ws + 101974016);
    int*   bsum  = (int*)  (ws + 102236416);
    int*   fill  = (int*)  (ws + 102238464);  // reused as act2 (16384 ints) after scatter
    int*   col   = (int*)  (ws + 102500608);
    int*   flag  = (int*)  (ws + 104615936);
    float* wts   = (float*)(ws + 104616960);
    unsigned short* Wpack = (unsigned short*)(ws + 105179136);
    int*   act1  = rowc;
    int*   act2  = fill;
    (void)in_sizes; (void)n_in; (void)out_size; (void)ws_size;

    const int O_Wl1 = 0,      O_bl1 = 16384,  O_Wr1 = 16512;
    const int O_Wl2 = 32896,  O_bl2 = 49280,  O_Wr2 = 49408;
    const int O_Wl3 = 65792,  O_bl3 = 82176,  O_Wr3 = 82304;
    const int O_Wl4 = 98688,  O_bl4 = 115072, O_Wr4 = 115200;
    const int O_Pr1 = 131584, O_pb1 = 131712, O_Po1 = 131713;
    const int O_Pr2 = 131841, O_pb2 = 131969, O_Po2 = 131970;
    const int O_W5  = 132098, O_b5  = 140290, O_W6 = 140354, O_b6 = 140482;

    CvtDesc d;
    const int srcIdx[22] = {4,5,6,7,8,9,10,11,12,13,14,15,16,17,18,19,20,21,22,23,24,25};
    const int nelems[22] = {16384,128,16384, 16384,128,16384, 16384,128,16384, 16384,128,16384,
                            128,1,128, 128,1,128, 8192,64,128,2};
    const int offs[22]   = {O_Wl1,O_bl1,O_Wr1, O_Wl2,O_bl2,O_Wr2, O_Wl3,O_bl3,O_Wr3, O_Wl4,O_bl4,O_Wr4,
                            O_Pr1,O_pb1,O_Po1, O_Pr2,O_pb2,O_Po2, O_W5,O_b5,O_W6,O_b6};
    for (int i = 0; i < 22; ++i) { d.src[i] = d_in[srcIdx[i]]; d.n[i] = nelems[i]; d.off[i] = offs[i]; }

    hipMemsetAsync(ghead, 0, NG * 4, stream);

    k_detect <<<1, 256, 0, stream>>>((const unsigned short*)x, flag);
    k_cvt    <<<dim3(64, 22), 256, 0, stream>>>(d, wts, flag);
    k_packW  <<<512, 256, 0, stream>>>(wts, make_int4(O_Wl1, O_Wl2, O_Wl3, O_Wl4),
                                       make_int4(O_Wr1, O_Wr2, O_Wr3, O_Wr4), Wpack, rowc, fill);
    k_hist   <<<2048, 256, 0, stream>>>(dstE, rowc);

    k_scan1  <<<256, 256, 0, stream>>>(rowc, rp, bsum, invc);
    k_scan23 <<<256, 256, 0, stream>>>(rp, bsum);
    k_scatter<<<2048, 256, 0, stream>>>(srcE, dstE, rp, fill, col);

    // layer 1: x -> hB (reads x directly, bf16 or f32)
    k_sage_l1<<<2048, 256, 0, stream>>>(x, flag, invc, rp, col,
                                        Wpack + 0 * 65536, wts + O_bl1, hB);
    // layer 2: hB -> hA  (+ fused pool-1 dots)
    k_sage_dots<false><<<2048, 256, 0, stream>>>(hB, invc, rp, nullptr, col,
                                                 Wpack + 1 * 65536, wts + O_bl2, hA,
                                                 wts + O_Pr1, wts + O_Po1, q, r, nullptr);

    // pool 1 (k = 1024): topk emits act1; parallel filtered-CSR build + invc
    k_score<<<256, 256, 0, stream>>>(q, r, wts + O_pb1, rp, col, score);
    k_topk<false><<<32, 256, 0, stream>>>(score, nm, tvec, K1, act1);
    k_fbuild<<<NG * K1 / 256, 256, 0, stream>>>(act1, nm, rp, col, rp2, col2, invc, ghead);

    // layer 3 (compact, filtered CSR): hA (scaled by tvec) -> hB
    k_sage_plain<<<1024, 256, 0, stream>>>(hA, tvec, invc, rp2, col2,
                                           Wpack + 2 * 65536, wts + O_bl3, hB, act1);
    // layer 4 (compact, filtered CSR => no ts needed): hB -> hA (+ pool-2 dots)
    k_sage_dots<true><<<1024, 256, 0, stream>>>(hB, invc, nullptr, rp2, col2,
                                                Wpack + 3 * 65536, wts + O_bl4, hA,
                                                wts + O_Pr2, wts + O_Po2, q, r, act1);

    // pool 2 (k = 512): score over filtered CSR; emits act2
    k_score2<<<NG * K1 / 256, 256, 0, stream>>>(q, r, wts + O_pb2, rp2, col2, score, act1);
    k_topk<true><<<32, 256, 0, stream>>>(score, nm, tvec, K2, act2);

    // readout + MLP head (one block per graph; count == K2 folded in)
    k_tail<<<32, 256, 0, stream>>>(hA, tvec, act2, wts + O_W5, wts + O_b5,
                                   wts + O_W6, wts + O_b6, d_out, flag);
}

// Round 12
// 367.385 us; speedup vs baseline: 1.1194x; 1.0094x over previous
//
#include <hip/hip_runtime.h>
#include <hip/hip_bf16.h>
#include <math.h>

#define NT   65536      // total nodes (32 graphs * 2048)
#define NPGC 2048       // nodes per graph
#define NG   32         // graphs
#define NE   524288     // edges
#define EPG  16384      // edges per graph (col2 arena stride)
#define HID  128
#define K1   1024       // pool-1 keep per graph
#define K2   512        // pool-2 keep per graph

typedef short short8 __attribute__((ext_vector_type(8)));
typedef float f32x4  __attribute__((ext_vector_type(4)));

__device__ __forceinline__ float bf2f(unsigned short u) {
    union { unsigned int i; float f; } v; v.i = ((unsigned int)u) << 16; return v.f;
}
__device__ __forceinline__ unsigned short f2bf(float f) {   // round-to-nearest (packW only)
    union { float f; unsigned int i; } v; v.f = f;
    unsigned int x = v.i;
    return (unsigned short)((x + 0x7fffu + ((x >> 16) & 1u)) >> 16);
}
// fast truncation split: v ~ hi + lo, |err| <= 2^-16 |v| (4 ops)
__device__ __forceinline__ void split2(float v, unsigned short& hi, unsigned short& lo) {
    unsigned int b = __float_as_uint(v);
    hi = (unsigned short)(b >> 16);
    float rem = v - __uint_as_float(b & 0xFFFF0000u);
    lo = (unsigned short)(__float_as_uint(rem) >> 16);
}

// ---------- dtype detection: bf16 vs fp32 ----------
__global__ void k_detect(const unsigned short* __restrict__ x, int* __restrict__ flag) {
    __shared__ int cnt;
    if (threadIdx.x == 0) cnt = 0;
    __syncthreads();
    int sane = 0;
#pragma unroll
    for (int j = 0; j < 16; ++j) {
        unsigned short u = x[threadIdx.x * 16 + j];
        int e = (u >> 7) & 0xFF;
        if (e > 0x60 && e < 0xA0) sane++;
    }
    atomicAdd(&cnt, sane);
    __syncthreads();
    if (threadIdx.x == 0) *flag = (cnt > 3686) ? 1 : 0;
}

// ---------- weight conversion: (bf16|f32) -> f32 scratch ----------
struct CvtDesc { const void* src[22]; int n[22]; int off[22]; };

__global__ void k_cvt(CvtDesc d, float* __restrict__ wts, const int* __restrict__ flag) {
    int t = blockIdx.y;
    int n = d.n[t];
    bool isbf = (*flag != 0);
    const unsigned short* sb = (const unsigned short*)d.src[t];
    const float* sf = (const float*)d.src[t];
    float* o = wts + d.off[t];
    for (int i = blockIdx.x * blockDim.x + threadIdx.x; i < n; i += gridDim.x * blockDim.x)
        o[i] = isbf ? bf2f(sb[i]) : sf[i];
}

// ---------- pack SAGE weights (+ zero rowc/fill for the CSR build) ----------
__global__ void k_packW(const float* __restrict__ wts, int4 oWl, int4 oWr,
                        unsigned short* __restrict__ Wpack,
                        int* __restrict__ rowc, int* __restrict__ fill) {
    int idx = blockIdx.x * 256 + threadIdx.x;
    if (idx < NT) { rowc[idx] = 0; fill[idx] = 0; }
    if (idx >= 4 * 8 * 8 * 64 * 8) return;
    int L    = idx >> 15;
    int rem  = idx & 32767;
    int ct   = rem >> 12;
    int rem2 = rem & 4095;
    int ks   = rem2 >> 9;
    int rem3 = rem2 & 511;
    int lane = rem3 >> 3;
    int j    = rem3 & 7;
    int k   = ks * 32 + (lane >> 4) * 8 + j;
    int col = ct * 16 + (lane & 15);
    int ol = (L == 0) ? oWl.x : (L == 1) ? oWl.y : (L == 2) ? oWl.z : oWl.w;
    int orr = (L == 0) ? oWr.x : (L == 1) ? oWr.y : (L == 2) ? oWr.z : oWr.w;
    float w = (k < 128) ? wts[ol + k * 128 + col] : wts[orr + (k - 128) * 128 + col];
    unsigned short hi = f2bf(w);
    unsigned short lo = f2bf(w - bf2f(hi));
    int base = L * 65536 + (ct * 8 + ks) * 512 + lane * 8 + j;
    Wpack[base]         = hi;
    Wpack[base + 32768] = lo;
}

// ---------- edge histogram only (x is consumed in-place by layer 1) ----------
__global__ void k_hist(const int* __restrict__ dstE, int* __restrict__ rowc) {
    int e = blockIdx.x * 256 + threadIdx.x;
    if (e < NE) atomicAdd(&rowc[dstE[e]], 1);
}

// scan1 also emits initial invc (pre-pool: invc = 1/max(deg,1))
__global__ void k_scan1(const int* __restrict__ cnt, int* __restrict__ rp, int* __restrict__ bsum,
                        float* __restrict__ invc) {
    __shared__ int s[256];
    int t = threadIdx.x;
    int i = blockIdx.x * 256 + t;
    int v = cnt[i];
    invc[i] = 1.0f / fmaxf((float)v, 1.0f);
    s[t] = v;
    __syncthreads();
    for (int off = 1; off < 256; off <<= 1) {
        int a = (t >= off) ? s[t - off] : 0;
        __syncthreads();
        s[t] += a;
        __syncthreads();
    }
    rp[i] = s[t] - v;
    if (t == 255) bsum[blockIdx.x] = s[255];
}

// merged scan2+scan3
__global__ void k_scan23(int* __restrict__ rp, const int* __restrict__ bsum) {
    __shared__ int s[256];
    int t = threadIdx.x;
    s[t] = bsum[t];
    __syncthreads();
    for (int off = 1; off < 256; off <<= 1) {
        int a = (t >= off) ? s[t - off] : 0;
        __syncthreads();
        s[t] += a;
        __syncthreads();
    }
    int boffv = s[blockIdx.x] - bsum[blockIdx.x];
    int i = blockIdx.x * 256 + t;
    rp[i] += boffv;
    if (i == 0) rp[NT] = NE;
}

__global__ void k_scatter(const int* __restrict__ src, const int* __restrict__ dst,
                          const int* __restrict__ rp, int* __restrict__ fill, int* __restrict__ col) {
    int e = blockIdx.x * blockDim.x + threadIdx.x;
    if (e < NE) {
        int d = dst[e];
        int p = rp[d] + atomicAdd(&fill[d], 1);
        col[p] = src[e];
    }
}

// ---------- filtered CSR build: 1 thread/active node, block scan, ONE atomic per block ----------
__global__ void __launch_bounds__(256) k_fbuild(const int* __restrict__ act,
                                                const float* __restrict__ nm,
                                                const int* __restrict__ rp,
                                                const int* __restrict__ col,
                                                int2* __restrict__ rp2,
                                                int* __restrict__ col2,
                                                float* __restrict__ invc,
                                                int* __restrict__ ghead) {
    __shared__ int wtot[4];
    __shared__ int s_base;
    int tid = threadIdx.x;
    int lane = tid & 63, wv = tid >> 6;
    int i = blockIdx.x * 256 + tid;           // 0..NG*K1-1
    int g = i >> 10;                          // constant within block
    int n = act[i];
    int bg = rp[n], en = rp[n + 1];
    int cc = 0;
    for (int e = bg; e < en; ++e) cc += (nm[col[e]] > 0.f) ? 1 : 0;
    invc[n] = 1.0f / fmaxf((float)cc, 1.0f);

    // block-wide exclusive scan of cc
    int pre = cc;
#pragma unroll
    for (int off = 1; off < 64; off <<= 1) {
        int v = __shfl_up(pre, off, 64);
        pre += (lane >= off) ? v : 0;
    }
    if (lane == 63) wtot[wv] = pre;
    __syncthreads();
    int woff = 0;
#pragma unroll
    for (int w2 = 0; w2 < 4; ++w2) woff += (w2 < wv) ? wtot[w2] : 0;
    int ex = pre - cc + woff;
    if (tid == 0) s_base = atomicAdd(&ghead[g], wtot[0] + wtot[1] + wtot[2] + wtot[3]);
    __syncthreads();

    int p = g * EPG + s_base + ex;
    rp2[i] = make_int2(p, p + cc);
    for (int e = bg; e < en; ++e) {
        int s = col[e];
        if (nm[s] > 0.f) col2[p++] = s;
    }
}

// ---------- LDS swizzle ----------
__device__ __forceinline__ int lds_sw(int node, int k) {
    int g = k >> 3;
    int go = g ^ (node & 7);
    return node * 128 + go * 8 + (k & 7);
}

// ---------- dtype-generic row chunk load (4 feats) ----------
template<int MODE>
__device__ __forceinline__ float4 ldrow4(const void* __restrict__ h, int node, int f) {
    if constexpr (MODE == 1) {
        ushort4 v = *((const ushort4*)h + (size_t)node * 32 + (f >> 2));
        float4 o; o.x = bf2f(v.x); o.y = bf2f(v.y); o.z = bf2f(v.z); o.w = bf2f(v.w);
        return o;
    } else {
        return *((const float4*)h + (size_t)node * 32 + (f >> 2));
    }
}

// ---------- shared body: two-phase (16 KB LDS), 8-wide gather, CSR prefetched (R7 form) ----------
template<bool HAS_TS, bool COMPACT, int MODE>
__device__ __forceinline__ void sage_body(
    const void* __restrict__ h, const float* __restrict__ ts,
    const float* __restrict__ invc,
    const int* __restrict__ rp, const int2* __restrict__ rp2,
    const int* __restrict__ col,
    const unsigned short* __restrict__ Wp,
    unsigned short* Ahi, unsigned short* Alo,
    int n0, int cb, const int* __restrict__ actb, int tid, f32x4 acc[2][2])
{
    int lane = tid & 63, w = tid >> 6;
    int lrow = lane & 15, quad = lane >> 4;
    int gnode = tid >> 5;          // 0..7 (32 threads per node)
    int f = (tid & 31) * 4;

    // ---- CSR prefetch for this thread's 4 gather nodes ----
    int gns[4], begs[4], ends[4]; float invs[4];
#pragma unroll
    for (int p = 0; p < 4; ++p) gns[p] = COMPACT ? actb[p * 8 + gnode] : n0 + p * 8 + gnode;
#pragma unroll
    for (int p = 0; p < 4; ++p) {
        if (COMPACT) { int2 be = rp2[cb + p * 8 + gnode]; begs[p] = be.x; ends[p] = be.y; }
        else         { begs[p] = rp[gns[p]]; ends[p] = rp[gns[p] + 1]; }
    }
#pragma unroll
    for (int p = 0; p < 4; ++p) invs[p] = invc[gns[p]];

    // ---- phase A: gather mean rows, 8 edges in flight ----
#pragma unroll
    for (int pass = 0; pass < 4; ++pass) {
        int node = pass * 8 + gnode;
        float ax = 0.f, ay = 0.f, az = 0.f, aw = 0.f;
        int beg = begs[pass], end = ends[pass];
        int ecl = end - 1;
        for (int e0 = beg; e0 < end; e0 += 8) {
            int sj[8];
#pragma unroll
            for (int j = 0; j < 8; ++j) {
                int e = (e0 + j < end) ? e0 + j : ecl;
                sj[j] = col[e];
            }
            float4 vj[8];
#pragma unroll
            for (int j = 0; j < 8; ++j)
                vj[j] = ldrow4<MODE>(h, sj[j], f);
#pragma unroll
            for (int j = 0; j < 8; ++j) {
                float cj = (e0 + j < end) ? (HAS_TS ? ts[sj[j]] : 1.0f) : 0.0f;
                ax += vj[j].x * cj;
                ay += vj[j].y * cj;
                az += vj[j].z * cj;
                aw += vj[j].w * cj;
            }
        }
        float inv = invs[pass];
        ushort4 hi4, lo4;
        split2(ax * inv, hi4.x, lo4.x);
        split2(ay * inv, hi4.y, lo4.y);
        split2(az * inv, hi4.z, lo4.z);
        split2(aw * inv, hi4.w, lo4.w);
        int a = lds_sw(node, f);
        *(ushort4*)&Ahi[a] = hi4;
        *(ushort4*)&Alo[a] = lo4;
    }
    __syncthreads();

    // ---- MFMA over Wl half (ks 0..3, from A) ----
#pragma unroll
    for (int ks = 0; ks < 4; ++ks) {
        short8 bh[2], blo[2];
#pragma unroll
        for (int c = 0; c < 2; ++c) {
            int ct = 2 * w + c;
            bh[c]  = *(const short8*)&Wp[(ct * 8 + ks) * 512 + lane * 8];
            blo[c] = *(const short8*)&Wp[32768 + (ct * 8 + ks) * 512 + lane * 8];
        }
        int kb = ks * 32 + quad * 8;
#pragma unroll
        for (int st = 0; st < 2; ++st) {
            int a = lds_sw(st * 16 + lrow, kb);
            short8 ah = *(const short8*)&Ahi[a];
            short8 al = *(const short8*)&Alo[a];
#pragma unroll
            for (int c = 0; c < 2; ++c) {
                acc[st][c] = __builtin_amdgcn_mfma_f32_16x16x32_bf16(ah, bh[c],  acc[st][c], 0, 0, 0);
                acc[st][c] = __builtin_amdgcn_mfma_f32_16x16x32_bf16(al, bh[c],  acc[st][c], 0, 0, 0);
                acc[st][c] = __builtin_amdgcn_mfma_f32_16x16x32_bf16(ah, blo[c], acc[st][c], 0, 0, 0);
            }
        }
    }
    __syncthreads();

    // ---- phase B: stage root rows into the SAME buffer (coalesced) ----
#pragma unroll
    for (int i = 0; i < 4; ++i) {
        int idx = i * 256 + tid;
        int node = idx >> 5;
        int f2 = (idx & 31) * 4;
        int gn = COMPACT ? actb[node] : n0 + node;
        float4 v = ldrow4<MODE>(h, gn, f2);
        float sc = HAS_TS ? ts[gn] : 1.0f;
        ushort4 hi4, lo4;
        split2(v.x * sc, hi4.x, lo4.x);
        split2(v.y * sc, hi4.y, lo4.y);
        split2(v.z * sc, hi4.z, lo4.z);
        split2(v.w * sc, hi4.w, lo4.w);
        int a = lds_sw(node, f2);
        *(ushort4*)&Ahi[a] = hi4;
        *(ushort4*)&Alo[a] = lo4;
    }
    __syncthreads();

    // ---- MFMA over Wr half (ks 4..7, from A again) ----
#pragma unroll
    for (int ks = 4; ks < 8; ++ks) {
        short8 bh[2], blo[2];
#pragma unroll
        for (int c = 0; c < 2; ++c) {
            int ct = 2 * w + c;
            bh[c]  = *(const short8*)&Wp[(ct * 8 + ks) * 512 + lane * 8];
            blo[c] = *(const short8*)&Wp[32768 + (ct * 8 + ks) * 512 + lane * 8];
        }
        int kb = (ks - 4) * 32 + quad * 8;
#pragma unroll
        for (int st = 0; st < 2; ++st) {
            int a = lds_sw(st * 16 + lrow, kb);
            short8 ah = *(const short8*)&Ahi[a];
            short8 al = *(const short8*)&Alo[a];
#pragma unroll
            for (int c = 0; c < 2; ++c) {
                acc[st][c] = __builtin_amdgcn_mfma_f32_16x16x32_bf16(ah, bh[c],  acc[st][c], 0, 0, 0);
                acc[st][c] = __builtin_amdgcn_mfma_f32_16x16x32_bf16(al, bh[c],  acc[st][c], 0, 0, 0);
                acc[st][c] = __builtin_amdgcn_mfma_f32_16x16x32_bf16(ah, blo[c], acc[st][c], 0, 0, 0);
            }
        }
    }
}

// ---------- block -> (graph, tile) with XCD-affinity swizzle ----------
template<bool COMPACT>
__device__ __forceinline__ void map_block(int b, int& graph, int& tile) {
    if (COMPACT) { graph = (b & 7) * 4 + (b >> 8); tile = (b >> 3) & 31; }   // 1024 blocks
    else         { graph = (b & 7) * 4 + (b >> 9); tile = (b >> 3) & 63; }   // 2048 blocks
}

// ---------- layer 1: reads x directly (bf16 or f32) ----------
__global__ void k_sage_l1(
    const void* __restrict__ x, const int* __restrict__ flag,
    const float* __restrict__ invc,
    const int* __restrict__ rp, const int* __restrict__ col,
    const unsigned short* __restrict__ Wp, const float* __restrict__ bl,
    float* __restrict__ out)
{
    __shared__ unsigned short Ahi[32 * 128];
    __shared__ unsigned short Alo[32 * 128];
    int tid = threadIdx.x;
    int graph, tile;
    map_block<false>(blockIdx.x, graph, tile);
    int n0 = graph * NPGC + tile * 32;
    int lane = tid & 63, w = tid >> 6;
    int lrow = lane & 15, quad = lane >> 4;
    f32x4 acc[2][2] = {};

    if (*flag)
        sage_body<false, false, 1>(x, nullptr, invc, rp, nullptr, col, Wp, Ahi, Alo, n0, 0, nullptr, tid, acc);
    else
        sage_body<false, false, 0>(x, nullptr, invc, rp, nullptr, col, Wp, Ahi, Alo, n0, 0, nullptr, tid, acc);

#pragma unroll
    for (int c = 0; c < 2; ++c) {
        int colg = (2 * w + c) * 16 + lrow;
        float bias = bl[colg];
#pragma unroll
        for (int st = 0; st < 2; ++st) {
#pragma unroll
            for (int rr = 0; rr < 4; ++rr) {
                int node = n0 + st * 16 + quad * 4 + rr;
                out[(size_t)node * HID + colg] = fmaxf(acc[st][c][rr] + bias, 0.f);
            }
        }
    }
}

// ---------- layer 3: compact plain (filtered CSR) ----------
__global__ void k_sage_plain(
    const float* __restrict__ h, const float* __restrict__ ts,
    const float* __restrict__ invc,
    const int2* __restrict__ rp2, const int* __restrict__ col2,
    const unsigned short* __restrict__ Wp, const float* __restrict__ bl,
    float* __restrict__ out, const int* __restrict__ act)
{
    __shared__ unsigned short Ahi[32 * 128];
    __shared__ unsigned short Alo[32 * 128];
    int tid = threadIdx.x;
    int graph, tile;
    map_block<true>(blockIdx.x, graph, tile);
    int n0 = graph * NPGC + tile * 32;
    int cb = graph * K1 + tile * 32;
    const int* actb = act + cb;
    int lane = tid & 63, w = tid >> 6;
    int lrow = lane & 15, quad = lane >> 4;
    f32x4 acc[2][2] = {};

    sage_body<true, true, 0>(h, ts, invc, nullptr, rp2, col2, Wp, Ahi, Alo, n0, cb, actb, tid, acc);

#pragma unroll
    for (int c = 0; c < 2; ++c) {
        int colg = (2 * w + c) * 16 + lrow;
        float bias = bl[colg];
#pragma unroll
        for (int st = 0; st < 2; ++st) {
#pragma unroll
            for (int rr = 0; rr < 4; ++rr) {
                int node = actb[st * 16 + quad * 4 + rr];
                out[(size_t)node * HID + colg] = fmaxf(acc[st][c][rr] + bias, 0.f);
            }
        }
    }
}

// ---------- layers 2 & 4: SAGE + pool dots ----------
template<bool COMPACT>
__global__ void k_sage_dots(
    const float* __restrict__ h,
    const float* __restrict__ invc,
    const int* __restrict__ rp, const int2* __restrict__ rp2,
    const int* __restrict__ col,
    const unsigned short* __restrict__ Wp, const float* __restrict__ bl,
    float* __restrict__ out,
    const float* __restrict__ Prel, const float* __restrict__ Proot,
    float* __restrict__ q, float* __restrict__ r, const int* __restrict__ act)
{
    __shared__ unsigned short Ahi[32 * 128];
    __shared__ unsigned short Alo[32 * 128];
    int tid = threadIdx.x;
    int graph, tile;
    map_block<COMPACT>(blockIdx.x, graph, tile);
    int n0 = graph * NPGC + tile * 32;
    int cb = COMPACT ? (graph * K1 + tile * 32) : 0;
    const int* actb = COMPACT ? (act + cb) : nullptr;
    int lane = tid & 63, w = tid >> 6;
    int lrow = lane & 15, quad = lane >> 4;
    f32x4 acc[2][2] = {};

    // layer 4 (COMPACT): filtered CSR => all sources active => no ts needed
    sage_body<false, COMPACT, 0>(h, nullptr, invc, rp, rp2, col, Wp, Ahi, Alo, n0, cb, actb, tid, acc);

    float qp[2][4] = {}, rp_[2][4] = {};
#pragma unroll
    for (int c = 0; c < 2; ++c) {
        int colg = (2 * w + c) * 16 + lrow;
        float bias = bl[colg];
        float pq = Prel[colg], pr = Proot[colg];
#pragma unroll
        for (int st = 0; st < 2; ++st) {
#pragma unroll
            for (int rr = 0; rr < 4; ++rr) {
                int nl = st * 16 + quad * 4 + rr;
                int node = COMPACT ? actb[nl] : n0 + nl;
                float val = fmaxf(acc[st][c][rr] + bias, 0.f);
                out[(size_t)node * HID + colg] = val;
                qp[st][rr] += val * pq;
                rp_[st][rr] += val * pr;
            }
        }
    }
#pragma unroll
    for (int st = 0; st < 2; ++st)
#pragma unroll
        for (int rr = 0; rr < 4; ++rr) {
#pragma unroll
            for (int m = 1; m < 16; m <<= 1) {
                qp[st][rr]  += __shfl_xor(qp[st][rr],  m, 64);
                rp_[st][rr] += __shfl_xor(rp_[st][rr], m, 64);
            }
        }
    __syncthreads();
    float* qa = (float*)Ahi;
    if (tid < 64) qa[tid] = 0.f;
    __syncthreads();
    if (lrow == 0) {
#pragma unroll
        for (int st = 0; st < 2; ++st)
#pragma unroll
            for (int rr = 0; rr < 4; ++rr) {
                int nl = st * 16 + quad * 4 + rr;
                atomicAdd(&qa[nl], qp[st][rr]);
                atomicAdd(&qa[32 + nl], rp_[st][rr]);
            }
    }
    __syncthreads();
    if (tid < 32) {
        int node = COMPACT ? actb[tid] : n0 + tid;
        q[node] = qa[tid];
        r[node] = qa[32 + tid];
    }
}

// ---------- score = segsum(q[src]) + r + prb (full, pool 1) ----------
__global__ void k_score(const float* __restrict__ q, const float* __restrict__ r,
                        const float* __restrict__ prb,
                        const int* __restrict__ rp, const int* __restrict__ col,
                        float* __restrict__ score) {
    int n = blockIdx.x * 256 + threadIdx.x;
    int beg = rp[n], end = rp[n + 1];
    float s = 0.f;
    for (int e = beg; e < end; ++e) s += q[col[e]];
    score[n] = s + r[n] + prb[0];
}

// ---------- score over active nodes via filtered CSR (pool 2) ----------
__global__ void k_score2(const float* __restrict__ q, const float* __restrict__ r,
                         const float* __restrict__ prb,
                         const int2* __restrict__ rp2, const int* __restrict__ col2,
                         float* __restrict__ score, const int* __restrict__ act) {
    int i = blockIdx.x * 256 + threadIdx.x;
    int n = act[i];
    int2 be = rp2[i];
    float s = 0.f;
    for (int e = be.x; e < be.y; ++e) s += q[col2[e]];
    score[n] = s + r[n] + prb[0];
}

// ---------- per-graph top-k via radix select; emits compact active list ----------
template<bool NMIN>
__global__ void __launch_bounds__(256) k_topk(const float* __restrict__ score,
                                              float* __restrict__ nm,
                                              float* __restrict__ tval, int k,
                                              int* __restrict__ act) {
    __shared__ unsigned int u[NPGC];
    __shared__ int hist[256];
    __shared__ int scanb[257];
    __shared__ int wtot[4];
    __shared__ int wtot2[4];
    __shared__ unsigned int s_byte;
    __shared__ int s_kk;
    int tid = threadIdx.x;
    int lane = tid & 63, wv = tid >> 6;
    int base = blockIdx.x * NPGC;

    for (int j = tid; j < NPGC; j += 256) {
        float sc = NMIN ? ((nm[base + j] > 0.f) ? score[base + j] : -1e30f) : score[base + j];
        unsigned int v = __float_as_uint(sc);
        v = (v & 0x80000000u) ? ~v : (v | 0x80000000u);
        u[j] = v;
    }
    hist[tid] = 0;
    if (tid == 0) scanb[256] = 0;
    __syncthreads();

    unsigned int prefix = 0;
    int kk = k;
#pragma unroll
    for (int round = 0; round < 4; ++round) {
        int shift = 24 - 8 * round;
        unsigned int pmask = (round == 0) ? 0u : (0xFFFFFFFFu << (32 - 8 * round));
        for (int j = tid; j < NPGC; j += 256) {
            unsigned int v = u[j];
            if ((v & pmask) == prefix) atomicAdd(&hist[(v >> shift) & 0xFF], 1);
        }
        __syncthreads();
        int s = hist[tid];
#pragma unroll
        for (int off = 1; off < 64; off <<= 1) {
            int t = __shfl_down(s, off, 64);
            s += (lane + off < 64) ? t : 0;
        }
        if (lane == 0) wtot[wv] = s;
        __syncthreads();
        int add = 0;
#pragma unroll
        for (int w2 = 1; w2 < 4; ++w2) add += (wv + w2 < 4) ? wtot[wv + w2] : 0;
        s += add;
        scanb[tid] = s;
        __syncthreads();
        int above = scanb[tid + 1];
        if (s >= kk && above < kk) { s_byte = (unsigned int)tid; s_kk = kk - above; }
        hist[tid] = 0;
        __syncthreads();
        prefix |= (s_byte << shift);
        kk = s_kk;
    }
    unsigned int thr = prefix;

    int j0 = tid * 8;
    int cnt = 0;
#pragma unroll
    for (int j = 0; j < 8; ++j) cnt += (u[j0 + j] == thr);
    int s = cnt;
#pragma unroll
    for (int off = 1; off < 64; off <<= 1) {
        int t = __shfl_up(s, off, 64);
        s += (lane >= off) ? t : 0;
    }
    if (lane == 63) wtot[wv] = s;
    __syncthreads();
    int add = 0;
#pragma unroll
    for (int w2 = 0; w2 < 4; ++w2) add += (w2 < wv) ? wtot[w2] : 0;
    int rank = s - cnt + add;

    // keep flags (exact k kept per graph by construction of the select)
    unsigned int keepmask = 0u;
    int myrank = rank;
    int kcnt = 0;
#pragma unroll
    for (int j = 0; j < 8; ++j) {
        unsigned int v = u[j0 + j];
        bool kp;
        if (v > thr) kp = true;
        else if (v == thr) { kp = (myrank < kk); myrank++; }
        else kp = false;
        keepmask |= (kp ? 1u : 0u) << j;
        kcnt += kp ? 1 : 0;
    }
    // block-wide exclusive scan of keep counts -> compact write position
    int s2 = kcnt;
#pragma unroll
    for (int off = 1; off < 64; off <<= 1) {
        int t2 = __shfl_up(s2, off, 64);
        s2 += (lane >= off) ? t2 : 0;
    }
    if (lane == 63) wtot2[wv] = s2;
    __syncthreads();
    int pos = s2 - kcnt;
#pragma unroll
    for (int w2 = 0; w2 < 4; ++w2) pos += (w2 < wv) ? wtot2[w2] : 0;
    int* actg = act + blockIdx.x * k;
#pragma unroll
    for (int j = 0; j < 8; ++j) {
        bool kp = (keepmask >> j) & 1u;
        int n = base + j0 + j;
        nm[n]   = kp ? 1.0f : 0.0f;
        tval[n] = kp ? tanhf(score[n]) : 0.0f;
        if (kp) actg[pos++] = n;
    }
}

// ---------- readout + MLP head + log_softmax, one block per graph ----------
__global__ void k_tail(const float* __restrict__ h, const float* __restrict__ t,
                       const int* __restrict__ act,
                       const float* __restrict__ W5, const float* __restrict__ b5,
                       const float* __restrict__ W6, const float* __restrict__ b6,
                       void* __restrict__ out, const int* __restrict__ flag) {
    __shared__ float gsh[2][HID];
    __shared__ float g5[64];
    __shared__ float ls[2];
    int graph = blockIdx.x, tid = threadIdx.x;
    int f = tid & 127, sub = tid >> 7;
    const int* actg = act + graph * K2;
    float acc = 0.f;
#pragma unroll 8
    for (int i = 0; i < 256; ++i) {
        int gn = actg[sub * 256 + i];
        acc += h[(size_t)gn * HID + f] * t[gn];
    }
    gsh[sub][f] = acc;
    __syncthreads();
    if (tid < 64) {
        const float ic = 1.0f / (float)K2;
        float a5 = b5[tid];
        for (int ff = 0; ff < HID; ++ff)
            a5 += (gsh[0][ff] + gsh[1][ff]) * ic * W5[ff * 64 + tid];
        g5[tid] = fmaxf(a5, 0.f);
    }
    __syncthreads();
    if (tid < 2) {
        float l = b6[tid];
        for (int tt = 0; tt < 64; ++tt) l += g5[tt] * W6[tt * 2 + tid];
        ls[tid] = l;
    }
    __syncthreads();
    if (tid == 0) {
        float a = ls[0], b = ls[1];
        float mx = fmaxf(a, b);
        float lse = mx + logf(expf(a - mx) + expf(b - mx));
        if (*flag) {
            ((unsigned short*)out)[graph * 2 + 0] = f2bf(a - lse);
            ((unsigned short*)out)[graph * 2 + 1] = f2bf(b - lse);
        } else {
            ((float*)out)[graph * 2 + 0] = a - lse;
            ((float*)out)[graph * 2 + 1] = b - lse;
        }
    }
}

extern "C" void kernel_launch(void* const* d_in, const int* in_sizes, int n_in,
                              void* d_out, int out_size, void* d_ws, size_t ws_size,
                              hipStream_t stream) {
    const void* x    = d_in[0];
    const int*  ei   = (const int*)d_in[1];
    const int*  srcE = ei;
    const int*  dstE = ei + NE;

    char* ws = (char*)d_ws;
    float* hA    = (float*)(ws + 0);
    float* hB    = (float*)(ws + 33554432);
    float* tvec  = (float*)(ws + 67108864);
    float* invc  = (float*)(ws + 67371008);
    int*   col2  = (int*)  (ws + 67633152);   // 2 MB (per-graph arenas of EPG)
    int2*  rp2   = (int2*) (ws + 69730304);   // 256 KB
    int*   ghead = (int*)  (ws + 69992448);   // 128 B
    float* q     = (float*)(ws + 100663296);
    float* r     = (float*)(ws + 100925440);
    float* score = (float*)(ws + 101187584);
    float* nm    = (float*)(ws + 101449728);
    int*   rowc  = (int*)  (ws + 101711872);  // reused as act1 (32768 ints) after scan1
    int*   rp    = (int*)  (ws + 101974016);
    int*   bsum  = (int*)  (ws + 102236416);
    int*   fill  = (int*)  (ws + 102238464);  // reused as act2 (16384 ints) after scatter
    int*   col   = (int*)  (ws + 102500608);
    int*   flag  = (int*)  (ws + 104615936);
    float* wts   = (float*)(ws + 104616960);
    unsigned short* Wpack = (unsigned short*)(ws + 105179136);
    int*   act1  = rowc;
    int*   act2  = fill;
    (void)in_sizes; (void)n_in; (void)out_size; (void)ws_size;

    const int O_Wl1 = 0,      O_bl1 = 16384,  O_Wr1 = 16512;
    const int O_Wl2 = 32896,  O_bl2 = 49280,  O_Wr2 = 49408;
    const int O_Wl3 = 65792,  O_bl3 = 82176,  O_Wr3 = 82304;
    const int O_Wl4 = 98688,  O_bl4 = 115072, O_Wr4 = 115200;
    const int O_Pr1 = 131584, O_pb1 = 131712, O_Po1 = 131713;
    const int O_Pr2 = 131841, O_pb2 = 131969, O_Po2 = 131970;
    const int O_W5  = 132098, O_b5  = 140290, O_W6 = 140354, O_b6 = 140482;

    CvtDesc d;
    const int srcIdx[22] = {4,5,6,7,8,9,10,11,12,13,14,15,16,17,18,19,20,21,22,23,24,25};
    const int nelems[22] = {16384,128,16384, 16384,128,16384, 16384,128,16384, 16384,128,16384,
                            128,1,128, 128,1,128, 8192,64,128,2};
    const int offs[22]   = {O_Wl1,O_bl1,O_Wr1, O_Wl2,O_bl2,O_Wr2, O_Wl3,O_bl3,O_Wr3, O_Wl4,O_bl4,O_Wr4,
                            O_Pr1,O_pb1,O_Po1, O_Pr2,O_pb2,O_Po2, O_W5,O_b5,O_W6,O_b6};
    for (int i = 0; i < 22; ++i) { d.src[i] = d_in[srcIdx[i]]; d.n[i] = nelems[i]; d.off[i] = offs[i]; }

    hipMemsetAsync(ghead, 0, NG * 4, stream);

    k_detect <<<1, 256, 0, stream>>>((const unsigned short*)x, flag);
    k_cvt    <<<dim3(64, 22), 256, 0, stream>>>(d, wts, flag);
    k_packW  <<<512, 256, 0, stream>>>(wts, make_int4(O_Wl1, O_Wl2, O_Wl3, O_Wl4),
                                       make_int4(O_Wr1, O_Wr2, O_Wr3, O_Wr4), Wpack, rowc, fill);
    k_hist   <<<2048, 256, 0, stream>>>(dstE, rowc);

    k_scan1  <<<256, 256, 0, stream>>>(rowc, rp, bsum, invc);
    k_scan23 <<<256, 256, 0, stream>>>(rp, bsum);
    k_scatter<<<2048, 256, 0, stream>>>(srcE, dstE, rp, fill, col);

    // layer 1: x -> hB (reads x directly, bf16 or f32)
    k_sage_l1<<<2048, 256, 0, stream>>>(x, flag, invc, rp, col,
                                        Wpack + 0 * 65536, wts + O_bl1, hB);
    // layer 2: hB -> hA  (+ fused pool-1 dots)
    k_sage_dots<false><<<2048, 256, 0, stream>>>(hB, invc, rp, nullptr, col,
                                                 Wpack + 1 * 65536, wts + O_bl2, hA,
                                                 wts + O_Pr1, wts + O_Po1, q, r, nullptr);

    // pool 1 (k = 1024): topk emits act1; parallel filtered-CSR build + invc
    k_score<<<256, 256, 0, stream>>>(q, r, wts + O_pb1, rp, col, score);
    k_topk<false><<<32, 256, 0, stream>>>(score, nm, tvec, K1, act1);
    k_fbuild<<<NG * K1 / 256, 256, 0, stream>>>(act1, nm, rp, col, rp2, col2, invc, ghead);

    // layer 3 (compact, filtered CSR): hA (scaled by tvec) -> hB
    k_sage_plain<<<1024, 256, 0, stream>>>(hA, tvec, invc, rp2, col2,
                                           Wpack + 2 * 65536, wts + O_bl3, hB, act1);
    // layer 4 (compact, filtered CSR => no ts needed): hB -> hA (+ pool-2 dots)
    k_sage_dots<true><<<1024, 256, 0, stream>>>(hB, invc, nullptr, rp2, col2,
                                                Wpack + 3 * 65536, wts + O_bl4, hA,
                                                wts + O_Pr2, wts + O_Po2, q, r, act1);

    // pool 2 (k = 512): score over filtered CSR; emits act2
    k_score2<<<NG * K1 / 256, 256, 0, stream>>>(q, r, wts + O_pb2, rp2, col2, score, act1);
    k_topk<true><<<32, 256, 0, stream>>>(score, nm, tvec, K2, act2);

    // readout + MLP head (one block per graph; count == K2 folded in)
    k_tail<<<32, 256, 0, stream>>>(hA, tvec, act2, wts + O_W5, wts + O_b5,
                                   wts + O_W6, wts + O_b6, d_out, flag);
}

// Round 13
// 355.703 us; speedup vs baseline: 1.1562x; 1.0328x over previous
//
#include <hip/hip_runtime.h>
#include <hip/hip_bf16.h>
#include <math.h>

#define NT   65536      // total nodes (32 graphs * 2048)
#define NPGC 2048       // nodes per graph
#define NG   32         // graphs
#define NE   524288     // edges
#define EPG  16384      // edges per graph (col2 arena stride)
#define HID  128
#define K1   1024       // pool-1 keep per graph
#define K2   512        // pool-2 keep per graph

typedef short short8 __attribute__((ext_vector_type(8)));
typedef float f32x4  __attribute__((ext_vector_type(4)));

__device__ __forceinline__ float bf2f(unsigned short u) {
    union { unsigned int i; float f; } v; v.i = ((unsigned int)u) << 16; return v.f;
}
__device__ __forceinline__ unsigned short f2bf(float f) {   // round-to-nearest (packW only)
    union { float f; unsigned int i; } v; v.f = f;
    unsigned int x = v.i;
    return (unsigned short)((x + 0x7fffu + ((x >> 16) & 1u)) >> 16);
}
// fast truncation split: v ~ hi + lo, |err| <= 2^-16 |v| (4 ops)
__device__ __forceinline__ void split2(float v, unsigned short& hi, unsigned short& lo) {
    unsigned int b = __float_as_uint(v);
    hi = (unsigned short)(b >> 16);
    float rem = v - __uint_as_float(b & 0xFFFF0000u);
    lo = (unsigned short)(__float_as_uint(rem) >> 16);
}

// ---------- dtype detection: bf16 vs fp32 ----------
__global__ void k_detect(const unsigned short* __restrict__ x, int* __restrict__ flag) {
    __shared__ int cnt;
    if (threadIdx.x == 0) cnt = 0;
    __syncthreads();
    int sane = 0;
#pragma unroll
    for (int j = 0; j < 16; ++j) {
        unsigned short u = x[threadIdx.x * 16 + j];
        int e = (u >> 7) & 0xFF;
        if (e > 0x60 && e < 0xA0) sane++;
    }
    atomicAdd(&cnt, sane);
    __syncthreads();
    if (threadIdx.x == 0) *flag = (cnt > 3686) ? 1 : 0;
}

// ---------- weight conversion: (bf16|f32) -> f32 scratch ----------
struct CvtDesc { const void* src[22]; int n[22]; int off[22]; };

__global__ void k_cvt(CvtDesc d, float* __restrict__ wts, const int* __restrict__ flag) {
    int t = blockIdx.y;
    int n = d.n[t];
    bool isbf = (*flag != 0);
    const unsigned short* sb = (const unsigned short*)d.src[t];
    const float* sf = (const float*)d.src[t];
    float* o = wts + d.off[t];
    for (int i = blockIdx.x * blockDim.x + threadIdx.x; i < n; i += gridDim.x * blockDim.x)
        o[i] = isbf ? bf2f(sb[i]) : sf[i];
}

// ---------- pack SAGE weights + edge histogram (rowc pre-zeroed by memset) ----------
__global__ void k_packW(const float* __restrict__ wts, int4 oWl, int4 oWr,
                        unsigned short* __restrict__ Wpack,
                        const int* __restrict__ dstE, int* __restrict__ rowc) {
    int idx = blockIdx.x * 256 + threadIdx.x;   // 0..131071
#pragma unroll
    for (int j = 0; j < 4; ++j) {
        int e = idx * 4 + j;
        atomicAdd(&rowc[dstE[e]], 1);
    }
    if (idx >= 4 * 8 * 8 * 64 * 8) return;
    int L    = idx >> 15;
    int rem  = idx & 32767;
    int ct   = rem >> 12;
    int rem2 = rem & 4095;
    int ks   = rem2 >> 9;
    int rem3 = rem2 & 511;
    int lane = rem3 >> 3;
    int j    = rem3 & 7;
    int k   = ks * 32 + (lane >> 4) * 8 + j;
    int col = ct * 16 + (lane & 15);
    int ol = (L == 0) ? oWl.x : (L == 1) ? oWl.y : (L == 2) ? oWl.z : oWl.w;
    int orr = (L == 0) ? oWr.x : (L == 1) ? oWr.y : (L == 2) ? oWr.z : oWr.w;
    float w = (k < 128) ? wts[ol + k * 128 + col] : wts[orr + (k - 128) * 128 + col];
    unsigned short hi = f2bf(w);
    unsigned short lo = f2bf(w - bf2f(hi));
    int base = L * 65536 + (ct * 8 + ks) * 512 + lane * 8 + j;
    Wpack[base]         = hi;
    Wpack[base + 32768] = lo;
}

// scan1 also emits initial invc (pre-pool: invc = 1/max(deg,1))
__global__ void k_scan1(const int* __restrict__ cnt, int* __restrict__ rp, int* __restrict__ bsum,
                        float* __restrict__ invc) {
    __shared__ int s[256];
    int t = threadIdx.x;
    int i = blockIdx.x * 256 + t;
    int v = cnt[i];
    invc[i] = 1.0f / fmaxf((float)v, 1.0f);
    s[t] = v;
    __syncthreads();
    for (int off = 1; off < 256; off <<= 1) {
        int a = (t >= off) ? s[t - off] : 0;
        __syncthreads();
        s[t] += a;
        __syncthreads();
    }
    rp[i] = s[t] - v;
    if (t == 255) bsum[blockIdx.x] = s[255];
}

// merged scan2+scan3
__global__ void k_scan23(int* __restrict__ rp, const int* __restrict__ bsum) {
    __shared__ int s[256];
    int t = threadIdx.x;
    s[t] = bsum[t];
    __syncthreads();
    for (int off = 1; off < 256; off <<= 1) {
        int a = (t >= off) ? s[t - off] : 0;
        __syncthreads();
        s[t] += a;
        __syncthreads();
    }
    int boffv = s[blockIdx.x] - bsum[blockIdx.x];
    int i = blockIdx.x * 256 + t;
    rp[i] += boffv;
    if (i == 0) rp[NT] = NE;
}

__global__ void k_scatter(const int* __restrict__ src, const int* __restrict__ dst,
                          const int* __restrict__ rp, int* __restrict__ fill, int* __restrict__ col) {
    int e = blockIdx.x * blockDim.x + threadIdx.x;
    if (e < NE) {
        int d = dst[e];
        int p = rp[d] + atomicAdd(&fill[d], 1);
        col[p] = src[e];
    }
}

// ---------- filtered CSR build: 1 thread/active node, block scan, ONE atomic per block ----------
__global__ void __launch_bounds__(256) k_fbuild(const int* __restrict__ act,
                                                const float* __restrict__ nm,
                                                const int* __restrict__ rp,
                                                const int* __restrict__ col,
                                                int2* __restrict__ rp2,
                                                int* __restrict__ col2,
                                                float* __restrict__ invc,
                                                int* __restrict__ ghead) {
    __shared__ int wtot[4];
    __shared__ int s_base;
    int tid = threadIdx.x;
    int lane = tid & 63, wv = tid >> 6;
    int i = blockIdx.x * 256 + tid;           // 0..NG*K1-1
    int g = i >> 10;                          // constant within block
    int n = act[i];
    int bg = rp[n], en = rp[n + 1];
    int cc = 0;
    for (int e = bg; e < en; ++e) cc += (nm[col[e]] > 0.f) ? 1 : 0;
    invc[n] = 1.0f / fmaxf((float)cc, 1.0f);

    // block-wide exclusive scan of cc
    int pre = cc;
#pragma unroll
    for (int off = 1; off < 64; off <<= 1) {
        int v = __shfl_up(pre, off, 64);
        pre += (lane >= off) ? v : 0;
    }
    if (lane == 63) wtot[wv] = pre;
    __syncthreads();
    int woff = 0;
#pragma unroll
    for (int w2 = 0; w2 < 4; ++w2) woff += (w2 < wv) ? wtot[w2] : 0;
    int ex = pre - cc + woff;
    if (tid == 0) s_base = atomicAdd(&ghead[g], wtot[0] + wtot[1] + wtot[2] + wtot[3]);
    __syncthreads();

    int p = g * EPG + s_base + ex;
    rp2[i] = make_int2(p, p + cc);
    for (int e = bg; e < en; ++e) {
        int s = col[e];
        if (nm[s] > 0.f) col2[p++] = s;
    }
}

// ---------- LDS swizzle ----------
__device__ __forceinline__ int lds_sw(int node, int k) {
    int g = k >> 3;
    int go = g ^ (node & 7);
    return node * 128 + go * 8 + (k & 7);
}

// ---------- dtype-generic row chunk load (4 feats) ----------
template<int MODE>
__device__ __forceinline__ float4 ldrow4(const void* __restrict__ h, int node, int f) {
    if constexpr (MODE == 1) {
        ushort4 v = *((const ushort4*)h + (size_t)node * 32 + (f >> 2));
        float4 o; o.x = bf2f(v.x); o.y = bf2f(v.y); o.z = bf2f(v.z); o.w = bf2f(v.w);
        return o;
    } else {
        return *((const float4*)h + (size_t)node * 32 + (f >> 2));
    }
}

// ---------- shared body: two-phase (16 KB LDS), 8-wide gather, CSR prefetched (R7 form) ----------
template<bool HAS_TS, bool COMPACT, int MODE>
__device__ __forceinline__ void sage_body(
    const void* __restrict__ h, const float* __restrict__ ts,
    const float* __restrict__ invc,
    const int* __restrict__ rp, const int2* __restrict__ rp2,
    const int* __restrict__ col,
    const unsigned short* __restrict__ Wp,
    unsigned short* Ahi, unsigned short* Alo,
    int n0, int cb, const int* __restrict__ actb, int tid, f32x4 acc[2][2])
{
    int lane = tid & 63, w = tid >> 6;
    int lrow = lane & 15, quad = lane >> 4;
    int gnode = tid >> 5;          // 0..7 (32 threads per node)
    int f = (tid & 31) * 4;

    // ---- CSR prefetch for this thread's 4 gather nodes ----
    int gns[4], begs[4], ends[4]; float invs[4];
#pragma unroll
    for (int p = 0; p < 4; ++p) gns[p] = COMPACT ? actb[p * 8 + gnode] : n0 + p * 8 + gnode;
#pragma unroll
    for (int p = 0; p < 4; ++p) {
        if (COMPACT) { int2 be = rp2[cb + p * 8 + gnode]; begs[p] = be.x; ends[p] = be.y; }
        else         { begs[p] = rp[gns[p]]; ends[p] = rp[gns[p] + 1]; }
    }
#pragma unroll
    for (int p = 0; p < 4; ++p) invs[p] = invc[gns[p]];

    // ---- phase A: gather mean rows, 8 edges in flight ----
#pragma unroll
    for (int pass = 0; pass < 4; ++pass) {
        int node = pass * 8 + gnode;
        float ax = 0.f, ay = 0.f, az = 0.f, aw = 0.f;
        int beg = begs[pass], end = ends[pass];
        int ecl = end - 1;
        for (int e0 = beg; e0 < end; e0 += 8) {
            int sj[8];
#pragma unroll
            for (int j = 0; j < 8; ++j) {
                int e = (e0 + j < end) ? e0 + j : ecl;
                sj[j] = col[e];
            }
            float4 vj[8];
#pragma unroll
            for (int j = 0; j < 8; ++j)
                vj[j] = ldrow4<MODE>(h, sj[j], f);
#pragma unroll
            for (int j = 0; j < 8; ++j) {
                float cj = (e0 + j < end) ? (HAS_TS ? ts[sj[j]] : 1.0f) : 0.0f;
                ax += vj[j].x * cj;
                ay += vj[j].y * cj;
                az += vj[j].z * cj;
                aw += vj[j].w * cj;
            }
        }
        float inv = invs[pass];
        ushort4 hi4, lo4;
        split2(ax * inv, hi4.x, lo4.x);
        split2(ay * inv, hi4.y, lo4.y);
        split2(az * inv, hi4.z, lo4.z);
        split2(aw * inv, hi4.w, lo4.w);
        int a = lds_sw(node, f);
        *(ushort4*)&Ahi[a] = hi4;
        *(ushort4*)&Alo[a] = lo4;
    }
    __syncthreads();

    // ---- MFMA over Wl half (ks 0..3, from A) ----
#pragma unroll
    for (int ks = 0; ks < 4; ++ks) {
        short8 bh[2], blo[2];
#pragma unroll
        for (int c = 0; c < 2; ++c) {
            int ct = 2 * w + c;
            bh[c]  = *(const short8*)&Wp[(ct * 8 + ks) * 512 + lane * 8];
            blo[c] = *(const short8*)&Wp[32768 + (ct * 8 + ks) * 512 + lane * 8];
        }
        int kb = ks * 32 + quad * 8;
#pragma unroll
        for (int st = 0; st < 2; ++st) {
            int a = lds_sw(st * 16 + lrow, kb);
            short8 ah = *(const short8*)&Ahi[a];
            short8 al = *(const short8*)&Alo[a];
#pragma unroll
            for (int c = 0; c < 2; ++c) {
                acc[st][c] = __builtin_amdgcn_mfma_f32_16x16x32_bf16(ah, bh[c],  acc[st][c], 0, 0, 0);
                acc[st][c] = __builtin_amdgcn_mfma_f32_16x16x32_bf16(al, bh[c],  acc[st][c], 0, 0, 0);
                acc[st][c] = __builtin_amdgcn_mfma_f32_16x16x32_bf16(ah, blo[c], acc[st][c], 0, 0, 0);
            }
        }
    }
    __syncthreads();

    // ---- phase B: stage root rows into the SAME buffer (coalesced) ----
#pragma unroll
    for (int i = 0; i < 4; ++i) {
        int idx = i * 256 + tid;
        int node = idx >> 5;
        int f2 = (idx & 31) * 4;
        int gn = COMPACT ? actb[node] : n0 + node;
        float4 v = ldrow4<MODE>(h, gn, f2);
        float sc = HAS_TS ? ts[gn] : 1.0f;
        ushort4 hi4, lo4;
        split2(v.x * sc, hi4.x, lo4.x);
        split2(v.y * sc, hi4.y, lo4.y);
        split2(v.z * sc, hi4.z, lo4.z);
        split2(v.w * sc, hi4.w, lo4.w);
        int a = lds_sw(node, f2);
        *(ushort4*)&Ahi[a] = hi4;
        *(ushort4*)&Alo[a] = lo4;
    }
    __syncthreads();

    // ---- MFMA over Wr half (ks 4..7, from A again) ----
#pragma unroll
    for (int ks = 4; ks < 8; ++ks) {
        short8 bh[2], blo[2];
#pragma unroll
        for (int c = 0; c < 2; ++c) {
            int ct = 2 * w + c;
            bh[c]  = *(const short8*)&Wp[(ct * 8 + ks) * 512 + lane * 8];
            blo[c] = *(const short8*)&Wp[32768 + (ct * 8 + ks) * 512 + lane * 8];
        }
        int kb = (ks - 4) * 32 + quad * 8;
#pragma unroll
        for (int st = 0; st < 2; ++st) {
            int a = lds_sw(st * 16 + lrow, kb);
            short8 ah = *(const short8*)&Ahi[a];
            short8 al = *(const short8*)&Alo[a];
#pragma unroll
            for (int c = 0; c < 2; ++c) {
                acc[st][c] = __builtin_amdgcn_mfma_f32_16x16x32_bf16(ah, bh[c],  acc[st][c], 0, 0, 0);
                acc[st][c] = __builtin_amdgcn_mfma_f32_16x16x32_bf16(al, bh[c],  acc[st][c], 0, 0, 0);
                acc[st][c] = __builtin_amdgcn_mfma_f32_16x16x32_bf16(ah, blo[c], acc[st][c], 0, 0, 0);
            }
        }
    }
}

// ---------- block -> (graph, tile) with XCD-affinity swizzle ----------
template<bool COMPACT>
__device__ __forceinline__ void map_block(int b, int& graph, int& tile) {
    if (COMPACT) { graph = (b & 7) * 4 + (b >> 8); tile = (b >> 3) & 31; }   // 1024 blocks
    else         { graph = (b & 7) * 4 + (b >> 9); tile = (b >> 3) & 63; }   // 2048 blocks
}

// ---------- layer 1: reads x directly (bf16 or f32) ----------
__global__ void __launch_bounds__(256, 6) k_sage_l1(
    const void* __restrict__ x, const int* __restrict__ flag,
    const float* __restrict__ invc,
    const int* __restrict__ rp, const int* __restrict__ col,
    const unsigned short* __restrict__ Wp, const float* __restrict__ bl,
    float* __restrict__ out)
{
    __shared__ unsigned short Ahi[32 * 128];
    __shared__ unsigned short Alo[32 * 128];
    int tid = threadIdx.x;
    int graph, tile;
    map_block<false>(blockIdx.x, graph, tile);
    int n0 = graph * NPGC + tile * 32;
    int lane = tid & 63, w = tid >> 6;
    int lrow = lane & 15, quad = lane >> 4;
    f32x4 acc[2][2] = {};

    if (*flag)
        sage_body<false, false, 1>(x, nullptr, invc, rp, nullptr, col, Wp, Ahi, Alo, n0, 0, nullptr, tid, acc);
    else
        sage_body<false, false, 0>(x, nullptr, invc, rp, nullptr, col, Wp, Ahi, Alo, n0, 0, nullptr, tid, acc);

#pragma unroll
    for (int c = 0; c < 2; ++c) {
        int colg = (2 * w + c) * 16 + lrow;
        float bias = bl[colg];
#pragma unroll
        for (int st = 0; st < 2; ++st) {
#pragma unroll
            for (int rr = 0; rr < 4; ++rr) {
                int node = n0 + st * 16 + quad * 4 + rr;
                out[(size_t)node * HID + colg] = fmaxf(acc[st][c][rr] + bias, 0.f);
            }
        }
    }
}

// ---------- layer 3: compact plain (filtered CSR) ----------
__global__ void __launch_bounds__(256, 6) k_sage_plain(
    const float* __restrict__ h, const float* __restrict__ ts,
    const float* __restrict__ invc,
    const int2* __restrict__ rp2, const int* __restrict__ col2,
    const unsigned short* __restrict__ Wp, const float* __restrict__ bl,
    float* __restrict__ out, const int* __restrict__ act)
{
    __shared__ unsigned short Ahi[32 * 128];
    __shared__ unsigned short Alo[32 * 128];
    int tid = threadIdx.x;
    int graph, tile;
    map_block<true>(blockIdx.x, graph, tile);
    int n0 = graph * NPGC + tile * 32;
    int cb = graph * K1 + tile * 32;
    const int* actb = act + cb;
    int lane = tid & 63, w = tid >> 6;
    int lrow = lane & 15, quad = lane >> 4;
    f32x4 acc[2][2] = {};

    sage_body<true, true, 0>(h, ts, invc, nullptr, rp2, col2, Wp, Ahi, Alo, n0, cb, actb, tid, acc);

#pragma unroll
    for (int c = 0; c < 2; ++c) {
        int colg = (2 * w + c) * 16 + lrow;
        float bias = bl[colg];
#pragma unroll
        for (int st = 0; st < 2; ++st) {
#pragma unroll
            for (int rr = 0; rr < 4; ++rr) {
                int node = actb[st * 16 + quad * 4 + rr];
                out[(size_t)node * HID + colg] = fmaxf(acc[st][c][rr] + bias, 0.f);
            }
        }
    }
}

// ---------- layers 2 & 4: SAGE + pool dots ----------
template<bool COMPACT>
__global__ void __launch_bounds__(256, 6) k_sage_dots(
    const float* __restrict__ h,
    const float* __restrict__ invc,
    const int* __restrict__ rp, const int2* __restrict__ rp2,
    const int* __restrict__ col,
    const unsigned short* __restrict__ Wp, const float* __restrict__ bl,
    float* __restrict__ out,
    const float* __restrict__ Prel, const float* __restrict__ Proot,
    float* __restrict__ q, float* __restrict__ r, const int* __restrict__ act)
{
    __shared__ unsigned short Ahi[32 * 128];
    __shared__ unsigned short Alo[32 * 128];
    int tid = threadIdx.x;
    int graph, tile;
    map_block<COMPACT>(blockIdx.x, graph, tile);
    int n0 = graph * NPGC + tile * 32;
    int cb = COMPACT ? (graph * K1 + tile * 32) : 0;
    const int* actb = COMPACT ? (act + cb) : nullptr;
    int lane = tid & 63, w = tid >> 6;
    int lrow = lane & 15, quad = lane >> 4;
    f32x4 acc[2][2] = {};

    // layer 4 (COMPACT): filtered CSR => all sources active => no ts needed
    sage_body<false, COMPACT, 0>(h, nullptr, invc, rp, rp2, col, Wp, Ahi, Alo, n0, cb, actb, tid, acc);

    float qp[2][4] = {}, rp_[2][4] = {};
#pragma unroll
    for (int c = 0; c < 2; ++c) {
        int colg = (2 * w + c) * 16 + lrow;
        float bias = bl[colg];
        float pq = Prel[colg], pr = Proot[colg];
#pragma unroll
        for (int st = 0; st < 2; ++st) {
#pragma unroll
            for (int rr = 0; rr < 4; ++rr) {
                int nl = st * 16 + quad * 4 + rr;
                int node = COMPACT ? actb[nl] : n0 + nl;
                float val = fmaxf(acc[st][c][rr] + bias, 0.f);
                out[(size_t)node * HID + colg] = val;
                qp[st][rr] += val * pq;
                rp_[st][rr] += val * pr;
            }
        }
    }
#pragma unroll
    for (int st = 0; st < 2; ++st)
#pragma unroll
        for (int rr = 0; rr < 4; ++rr) {
#pragma unroll
            for (int m = 1; m < 16; m <<= 1) {
                qp[st][rr]  += __shfl_xor(qp[st][rr],  m, 64);
                rp_[st][rr] += __shfl_xor(rp_[st][rr], m, 64);
            }
        }
    __syncthreads();
    float* qa = (float*)Ahi;
    if (tid < 64) qa[tid] = 0.f;
    __syncthreads();
    if (lrow == 0) {
#pragma unroll
        for (int st = 0; st < 2; ++st)
#pragma unroll
            for (int rr = 0; rr < 4; ++rr) {
                int nl = st * 16 + quad * 4 + rr;
                atomicAdd(&qa[nl], qp[st][rr]);
                atomicAdd(&qa[32 + nl], rp_[st][rr]);
            }
    }
    __syncthreads();
    if (tid < 32) {
        int node = COMPACT ? actb[tid] : n0 + tid;
        q[node] = qa[tid];
        r[node] = qa[32 + tid];
    }
}

// ---------- score = segsum(q[src]) + r + prb (full, pool 1) ----------
__global__ void k_score(const float* __restrict__ q, const float* __restrict__ r,
                        const float* __restrict__ prb,
                        const int* __restrict__ rp, const int* __restrict__ col,
                        float* __restrict__ score) {
    int n = blockIdx.x * 256 + threadIdx.x;
    int beg = rp[n], end = rp[n + 1];
    float s = 0.f;
    for (int e = beg; e < end; ++e) s += q[col[e]];
    score[n] = s + r[n] + prb[0];
}

// ---------- score over active nodes via filtered CSR (pool 2) ----------
__global__ void k_score2(const float* __restrict__ q, const float* __restrict__ r,
                         const float* __restrict__ prb,
                         const int2* __restrict__ rp2, const int* __restrict__ col2,
                         float* __restrict__ score, const int* __restrict__ act) {
    int i = blockIdx.x * 256 + threadIdx.x;
    int n = act[i];
    int2 be = rp2[i];
    float s = 0.f;
    for (int e = be.x; e < be.y; ++e) s += q[col2[e]];
    score[n] = s + r[n] + prb[0];
}

// ---------- per-graph top-k via radix select; emits compact active list ----------
template<bool NMIN>
__global__ void __launch_bounds__(256) k_topk(const float* __restrict__ score,
                                              float* __restrict__ nm,
                                              float* __restrict__ tval, int k,
                                              int* __restrict__ act) {
    __shared__ unsigned int u[NPGC];
    __shared__ int hist[256];
    __shared__ int scanb[257];
    __shared__ int wtot[4];
    __shared__ int wtot2[4];
    __shared__ unsigned int s_byte;
    __shared__ int s_kk;
    int tid = threadIdx.x;
    int lane = tid & 63, wv = tid >> 6;
    int base = blockIdx.x * NPGC;

    for (int j = tid; j < NPGC; j += 256) {
        float sc = NMIN ? ((nm[base + j] > 0.f) ? score[base + j] : -1e30f) : score[base + j];
        unsigned int v = __float_as_uint(sc);
        v = (v & 0x80000000u) ? ~v : (v | 0x80000000u);
        u[j] = v;
    }
    hist[tid] = 0;
    if (tid == 0) scanb[256] = 0;
    __syncthreads();

    unsigned int prefix = 0;
    int kk = k;
#pragma unroll
    for (int round = 0; round < 4; ++round) {
        int shift = 24 - 8 * round;
        unsigned int pmask = (round == 0) ? 0u : (0xFFFFFFFFu << (32 - 8 * round));
        for (int j = tid; j < NPGC; j += 256) {
            unsigned int v = u[j];
            if ((v & pmask) == prefix) atomicAdd(&hist[(v >> shift) & 0xFF], 1);
        }
        __syncthreads();
        int s = hist[tid];
#pragma unroll
        for (int off = 1; off < 64; off <<= 1) {
            int t = __shfl_down(s, off, 64);
            s += (lane + off < 64) ? t : 0;
        }
        if (lane == 0) wtot[wv] = s;
        __syncthreads();
        int add = 0;
#pragma unroll
        for (int w2 = 1; w2 < 4; ++w2) add += (wv + w2 < 4) ? wtot[wv + w2] : 0;
        s += add;
        scanb[tid] = s;
        __syncthreads();
        int above = scanb[tid + 1];
        if (s >= kk && above < kk) { s_byte = (unsigned int)tid; s_kk = kk - above; }
        hist[tid] = 0;
        __syncthreads();
        prefix |= (s_byte << shift);
        kk = s_kk;
    }
    unsigned int thr = prefix;

    int j0 = tid * 8;
    int cnt = 0;
#pragma unroll
    for (int j = 0; j < 8; ++j) cnt += (u[j0 + j] == thr);
    int s = cnt;
#pragma unroll
    for (int off = 1; off < 64; off <<= 1) {
        int t = __shfl_up(s, off, 64);
        s += (lane >= off) ? t : 0;
    }
    if (lane == 63) wtot[wv] = s;
    __syncthreads();
    int add = 0;
#pragma unroll
    for (int w2 = 0; w2 < 4; ++w2) add += (w2 < wv) ? wtot[w2] : 0;
    int rank = s - cnt + add;

    // keep flags (exact k kept per graph by construction of the select)
    unsigned int keepmask = 0u;
    int myrank = rank;
    int kcnt = 0;
#pragma unroll
    for (int j = 0; j < 8; ++j) {
        unsigned int v = u[j0 + j];
        bool kp;
        if (v > thr) kp = true;
        else if (v == thr) { kp = (myrank < kk); myrank++; }
        else kp = false;
        keepmask |= (kp ? 1u : 0u) << j;
        kcnt += kp ? 1 : 0;
    }
    // block-wide exclusive scan of keep counts -> compact write position
    int s2 = kcnt;
#pragma unroll
    for (int off = 1; off < 64; off <<= 1) {
        int t2 = __shfl_up(s2, off, 64);
        s2 += (lane >= off) ? t2 : 0;
    }
    if (lane == 63) wtot2[wv] = s2;
    __syncthreads();
    int pos = s2 - kcnt;
#pragma unroll
    for (int w2 = 0; w2 < 4; ++w2) pos += (w2 < wv) ? wtot2[w2] : 0;
    int* actg = act + blockIdx.x * k;
#pragma unroll
    for (int j = 0; j < 8; ++j) {
        bool kp = (keepmask >> j) & 1u;
        int n = base + j0 + j;
        nm[n]   = kp ? 1.0f : 0.0f;
        tval[n] = kp ? tanhf(score[n]) : 0.0f;
        if (kp) actg[pos++] = n;
    }
}

// ---------- readout + MLP head + log_softmax, one block per graph ----------
__global__ void k_tail(const float* __restrict__ h, const float* __restrict__ t,
                       const int* __restrict__ act,
                       const float* __restrict__ W5, const float* __restrict__ b5,
                       const float* __restrict__ W6, const float* __restrict__ b6,
                       void* __restrict__ out, const int* __restrict__ flag) {
    __shared__ float gsh[2][HID];
    __shared__ float g5[64];
    __shared__ float ls[2];
    int graph = blockIdx.x, tid = threadIdx.x;
    int f = tid & 127, sub = tid >> 7;
    const int* actg = act + graph * K2;
    float acc = 0.f;
#pragma unroll 8
    for (int i = 0; i < 256; ++i) {
        int gn = actg[sub * 256 + i];
        acc += h[(size_t)gn * HID + f] * t[gn];
    }
    gsh[sub][f] = acc;
    __syncthreads();
    if (tid < 64) {
        const float ic = 1.0f / (float)K2;
        float a5 = b5[tid];
        for (int ff = 0; ff < HID; ++ff)
            a5 += (gsh[0][ff] + gsh[1][ff]) * ic * W5[ff * 64 + tid];
        g5[tid] = fmaxf(a5, 0.f);
    }
    __syncthreads();
    if (tid < 2) {
        float l = b6[tid];
        for (int tt = 0; tt < 64; ++tt) l += g5[tt] * W6[tt * 2 + tid];
        ls[tid] = l;
    }
    __syncthreads();
    if (tid == 0) {
        float a = ls[0], b = ls[1];
        float mx = fmaxf(a, b);
        float lse = mx + logf(expf(a - mx) + expf(b - mx));
        if (*flag) {
            ((unsigned short*)out)[graph * 2 + 0] = f2bf(a - lse);
            ((unsigned short*)out)[graph * 2 + 1] = f2bf(b - lse);
        } else {
            ((float*)out)[graph * 2 + 0] = a - lse;
            ((float*)out)[graph * 2 + 1] = b - lse;
        }
    }
}

extern "C" void kernel_launch(void* const* d_in, const int* in_sizes, int n_in,
                              void* d_out, int out_size, void* d_ws, size_t ws_size,
                              hipStream_t stream) {
    const void* x    = d_in[0];
    const int*  ei   = (const int*)d_in[1];
    const int*  srcE = ei;
    const int*  dstE = ei + NE;

    char* ws = (char*)d_ws;
    float* hA    = (float*)(ws + 0);
    float* hB    = (float*)(ws + 33554432);
    float* tvec  = (float*)(ws + 67108864);
    float* invc  = (float*)(ws + 67371008);
    int*   col2  = (int*)  (ws + 67633152);   // 2 MB (per-graph arenas of EPG)
    int2*  rp2   = (int2*) (ws + 69730304);   // 256 KB
    int*   ghead = (int*)  (ws + 69992448);   // 128 B
    float* q     = (float*)(ws + 100663296);
    float* r     = (float*)(ws + 100925440);
    float* score = (float*)(ws + 101187584);
    float* nm    = (float*)(ws + 101449728);
    int*   rowc  = (int*)  (ws + 101711872);  // reused as act1 (32768 ints) after scan1
    int*   rp    = (int*)  (ws + 101974016);
    int*   bsum  = (int*)  (ws + 102236416);
    int*   fill  = (int*)  (ws + 102238464);  // reused as act2 (16384 ints) after scatter
    int*   col   = (int*)  (ws + 102500608);
    int*   flag  = (int*)  (ws + 104615936);
    float* wts   = (float*)(ws + 104616960);
    unsigned short* Wpack = (unsigned short*)(ws + 105179136);
    int*   act1  = rowc;
    int*   act2  = fill;
    (void)in_sizes; (void)n_in; (void)out_size; (void)ws_size;

    const int O_Wl1 = 0,      O_bl1 = 16384,  O_Wr1 = 16512;
    const int O_Wl2 = 32896,  O_bl2 = 49280,  O_Wr2 = 49408;
    const int O_Wl3 = 65792,  O_bl3 = 82176,  O_Wr3 = 82304;
    const int O_Wl4 = 98688,  O_bl4 = 115072, O_Wr4 = 115200;
    const int O_Pr1 = 131584, O_pb1 = 131712, O_Po1 = 131713;
    const int O_Pr2 = 131841, O_pb2 = 131969, O_Po2 = 131970;
    const int O_W5  = 132098, O_b5  = 140290, O_W6 = 140354, O_b6 = 140482;

    CvtDesc d;
    const int srcIdx[22] = {4,5,6,7,8,9,10,11,12,13,14,15,16,17,18,19,20,21,22,23,24,25};
    const int nelems[22] = {16384,128,16384, 16384,128,16384, 16384,128,16384, 16384,128,16384,
                            128,1,128, 128,1,128, 8192,64,128,2};
    const int offs[22]   = {O_Wl1,O_bl1,O_Wr1, O_Wl2,O_bl2,O_Wr2, O_Wl3,O_bl3,O_Wr3, O_Wl4,O_bl4,O_Wr4,
                            O_Pr1,O_pb1,O_Po1, O_Pr2,O_pb2,O_Po2, O_W5,O_b5,O_W6,O_b6};
    for (int i = 0; i < 22; ++i) { d.src[i] = d_in[srcIdx[i]]; d.n[i] = nelems[i]; d.off[i] = offs[i]; }

    // zero rowc..fill span (covers rowc, rp, bsum, fill; rp/bsum rewritten by scans) + ghead
    hipMemsetAsync(rowc, 0, 102500608 - 101711872, stream);
    hipMemsetAsync(ghead, 0, NG * 4, stream);

    k_detect <<<1, 256, 0, stream>>>((const unsigned short*)x, flag);
    k_cvt    <<<dim3(64, 22), 256, 0, stream>>>(d, wts, flag);
    // packW + fused edge histogram (rowc pre-zeroed)
    k_packW  <<<512, 256, 0, stream>>>(wts, make_int4(O_Wl1, O_Wl2, O_Wl3, O_Wl4),
                                       make_int4(O_Wr1, O_Wr2, O_Wr3, O_Wr4), Wpack, dstE, rowc);

    k_scan1  <<<256, 256, 0, stream>>>(rowc, rp, bsum, invc);
    k_scan23 <<<256, 256, 0, stream>>>(rp, bsum);
    k_scatter<<<2048, 256, 0, stream>>>(srcE, dstE, rp, fill, col);

    // layer 1: x -> hB (reads x directly, bf16 or f32)
    k_sage_l1<<<2048, 256, 0, stream>>>(x, flag, invc, rp, col,
                                        Wpack + 0 * 65536, wts + O_bl1, hB);
    // layer 2: hB -> hA  (+ fused pool-1 dots)
    k_sage_dots<false><<<2048, 256, 0, stream>>>(hB, invc, rp, nullptr, col,
                                                 Wpack + 1 * 65536, wts + O_bl2, hA,
                                                 wts + O_Pr1, wts + O_Po1, q, r, nullptr);

    // pool 1 (k = 1024): topk emits act1; parallel filtered-CSR build + invc
    k_score<<<256, 256, 0, stream>>>(q, r, wts + O_pb1, rp, col, score);
    k_topk<false><<<32, 256, 0, stream>>>(score, nm, tvec, K1, act1);
    k_fbuild<<<NG * K1 / 256, 256, 0, stream>>>(act1, nm, rp, col, rp2, col2, invc, ghead);

    // layer 3 (compact, filtered CSR): hA (scaled by tvec) -> hB
    k_sage_plain<<<1024, 256, 0, stream>>>(hA, tvec, invc, rp2, col2,
                                           Wpack + 2 * 65536, wts + O_bl3, hB, act1);
    // layer 4 (compact, filtered CSR => no ts needed): hB -> hA (+ pool-2 dots)
    k_sage_dots<true><<<1024, 256, 0, stream>>>(hB, invc, nullptr, rp2, col2,
                                                Wpack + 3 * 65536, wts + O_bl4, hA,
                                                wts + O_Pr2, wts + O_Po2, q, r, act1);

    // pool 2 (k = 512): score over filtered CSR; emits act2
    k_score2<<<NG * K1 / 256, 256, 0, stream>>>(q, r, wts + O_pb2, rp2, col2, score, act1);
    k_topk<true><<<32, 256, 0, stream>>>(score, nm, tvec, K2, act2);

    // readout + MLP head (one block per graph; count == K2 folded in)
    k_tail<<<32, 256, 0, stream>>>(hA, tvec, act2, wts + O_W5, wts + O_b5,
                                   wts + O_W6, wts + O_b6, d_out, flag);
}